// Round 13
// baseline (1059.422 us; speedup 1.0000x reference)
//
#include <hip/hip_runtime.h>
#include <hip/hip_bf16.h>

typedef __attribute__((ext_vector_type(8))) short sv8_t;   // 8 bf16 (4 VGPR)
typedef __attribute__((ext_vector_type(4))) float fv4_t;   // MFMA accumulator
typedef __attribute__((ext_vector_type(4))) float f4ld_t;  // global float4 load

#define BB 8
#define TT 8
#define HH 56
#define WW2 56
#define NTOK 98
#define BNW 2048
#define PSPAT 25088
#define TOK_TOTAL 200704
#define ACT_ELEMS 25690112
#define VT_WSTRIDE 14336   // 128 * 112

#define SWZB(row, cb) ((cb) ^ ((((unsigned)(row)) & 7u) << 4))

__device__ __forceinline__ unsigned short f2bf(float f) {
    union { float f; unsigned u; } x; x.f = f;
    unsigned r = x.u + 0x7fffu + ((x.u >> 16) & 1u);
    return (unsigned short)(r >> 16);
}
// packed pair via v_cvt_pk_bf16_f32 (RNE, bit-identical to f2bf pair, 1 inst)
__device__ __forceinline__ unsigned packbf(float lo, float hi) {
    __hip_bfloat162 h = __float22bfloat162_rn(make_float2(lo, hi));
    union { __hip_bfloat162 h; unsigned u; } cv; cv.h = h; return cv.u;
}
__device__ __forceinline__ sv8_t lds_ld8(const unsigned short* p, int byteoff) {
    return *(const sv8_t*)((const char*)p + byteoff);
}
__device__ __forceinline__ void lds_st8(unsigned short* p, int byteoff, sv8_t v) {
    *(sv8_t*)((char*)p + byteoff) = v;
}
__device__ __forceinline__ void lds_st1(unsigned short* p, int byteoff, unsigned short v) {
    *(unsigned short*)((char*)p + byteoff) = v;
}
// GELU, tanh form via hardware exp (~10 VALU ops vs erff's ~30)
__device__ __forceinline__ float gelu_f(float v) {
    float u = v * (0.7978845608028654f + 0.035677408136300125f * v * v);
    float e = __expf(2.f * u);
    float th = 1.f - 2.f / (e + 1.f);
    return 0.5f * v * (1.f + th);
}

// ---------------- transpose in: (B,C,P) -> (B,P,C) f32 ----------------
__global__ __launch_bounds__(256) void k_transpose_in(const float* __restrict__ in,
                                                      float* __restrict__ xbuf) {
    __shared__ float tile[32][33];
    int p0 = blockIdx.x * 32, c0 = blockIdx.y * 32, b = blockIdx.z;
    int pi = threadIdx.x, ci = threadIdx.y;
    const float* src = in + ((size_t)b * 128 + c0) * PSPAT + p0;
    for (int r = 0; r < 32; r += 8)
        tile[ci + r][pi] = src[(size_t)(ci + r) * PSPAT + pi];
    __syncthreads();
    float* dst = xbuf + ((size_t)b * PSPAT + p0) * 128 + c0;
    for (int r = 0; r < 32; r += 8)
        dst[(size_t)(ci + r) * 128 + pi] = tile[pi][ci + r];
}

// ---------------- weight prep: in f32 [K][N] -> out bf16 [N][K] ----------------
__global__ __launch_bounds__(256) void k_prep_w(const float* __restrict__ in,
                                                unsigned short* __restrict__ out,
                                                int K, int N) {
    __shared__ float tile[32][33];
    int n0 = blockIdx.x * 32, k0 = blockIdx.y * 32;
    int x = threadIdx.x, y = threadIdx.y;
    for (int r = 0; r < 32; r += 8)
        tile[y + r][x] = in[(size_t)(k0 + y + r) * N + n0 + x];
    __syncthreads();
    for (int r = 0; r < 32; r += 8)
        out[(size_t)(n0 + y + r) * K + k0 + x] = f2bf(tile[x][y + r]);
}

// ---------------- bias prep: biasb[layer][head][q row][k col] ----------------
__global__ void k_prep_bias(const float* __restrict__ rpb, float* __restrict__ biasb) {
    int col = threadIdx.x;   // 0..111 (k index)
    int row = blockIdx.x;    // 0..111 (q index)
    int head = blockIdx.y;   // 0..3
    int layer = blockIdx.z;
    int tn = min(row, 97), tm = min(col, 97);
    int itn = tn / 49, rn = tn - itn * 49, ihn = rn / 7, iwn = rn - ihn * 7;
    int itm = tm / 49, rm = tm - itm * 49, ihm = rm / 7, iwm = rm - ihm * 7;
    int dt = itn - itm + 1, dh = ihn - ihm + 6, dw = iwn - iwm + 6;
    float v = rpb[((size_t)layer * 507 + dt * 169 + dh * 13 + dw) * 4 + head];
    biasb[(((size_t)layer * 4 + head) * 112 + row) * 112 + col] = v;
}

// ---------------- fused LN1 + gather + qkv GEMM ----------------
// ALL waves use swapped-operand MFMA (C: lane=token, reg=4 consecutive cols)
// -> packed 8B stores. Waves 0/1: Q,K -> qkbuf[tok][256]; waves 2/3: V -> vT.
__global__ __launch_bounds__(256) void k_qkv(const float* __restrict__ xbuf,
                                             const float* __restrict__ g,
                                             const float* __restrict__ be,
                                             const unsigned short* __restrict__ wT,  // [384][128]
                                             const float* __restrict__ bias,         // [384]
                                             unsigned short* __restrict__ qkbuf,
                                             unsigned short* __restrict__ vT,
                                             int shifted) {
    __shared__ unsigned short xt[64 * 128];
    int tid = threadIdx.x;
    int row0 = blockIdx.x * 64;
    {
        int r = tid >> 2, q = tid & 3;
        int wt = row0 + r;
        int win = wt / 98, n = wt - win * 98;
        int b_ = win >> 8, wrem = win & 255;
        int tw = wrem >> 6, hw = (wrem >> 3) & 7, ww = wrem & 7;
        int it = n / 49, r2 = n - it * 49, ih = r2 / 7, iw = r2 - ih * 7;
        int t = tw * 2 + it, h = hw * 7 + ih, w = ww * 7 + iw;
        if (shifted) {
            t += 1; if (t >= TT) t -= TT;
            h += 3; if (h >= HH) h -= HH;
            w += 3; if (w >= WW2) w -= WW2;
        }
        const float* src = xbuf + ((size_t)b_ * PSPAT + t * (HH * WW2) + h * WW2 + w) * 128 + q * 32;
        float v[32];
        float s = 0.f, sq = 0.f;
        for (int i = 0; i < 8; i++) {
            f4ld_t f = *(const f4ld_t*)(src + i * 4);
            v[i * 4 + 0] = f.x; v[i * 4 + 1] = f.y; v[i * 4 + 2] = f.z; v[i * 4 + 3] = f.w;
            s += f.x + f.y + f.z + f.w;
            sq += f.x * f.x + f.y * f.y + f.z * f.z + f.w * f.w;
        }
        s += __shfl_xor(s, 1); sq += __shfl_xor(sq, 1);
        s += __shfl_xor(s, 2); sq += __shfl_xor(sq, 2);
        float mu = s * (1.f / 128.f);
        float var = sq * (1.f / 128.f) - mu * mu;
        float rs = rsqrtf(var + 1e-5f);
        for (int c0 = 0; c0 < 32; c0 += 8) {
            float y[8];
            #pragma unroll
            for (int i = 0; i < 8; i++) {
                int c = q * 32 + c0 + i;
                y[i] = (v[c0 + i] - mu) * rs * g[c] + be[c];
            }
            union { unsigned u[4]; sv8_t s8; } pk;
            pk.u[0] = packbf(y[0], y[1]); pk.u[1] = packbf(y[2], y[3]);
            pk.u[2] = packbf(y[4], y[5]); pk.u[3] = packbf(y[6], y[7]);
            lds_st8(xt, r * 256 + SWZB(r, (q * 32 + c0) * 2), pk.s8);
        }
    }
    __syncthreads();
    int wv = tid >> 6, lane = tid & 63, l15 = lane & 15, lhi = lane >> 4;

    if (wv < 2) {
        // Q (wv0) or K (wv1), swapped: C[d][tok]; 8 d16-frags, packed 8B stores
        int nb = wv * 128;
        fv4_t acc[4][8];
        for (int m = 0; m < 4; m++) for (int f = 0; f < 8; f++) acc[m][f] = (fv4_t){0.f, 0.f, 0.f, 0.f};
        for (int kk = 0; kk < 4; kk++) {
            sv8_t x4[4];
            #pragma unroll
            for (int m = 0; m < 4; m++) {
                int ar = 16 * m + l15;
                x4[m] = lds_ld8(xt, ar * 256 + SWZB(ar, (kk * 32 + 8 * lhi) * 2));
            }
            #pragma unroll
            for (int f = 0; f < 8; f++) {
                sv8_t wf = *(const sv8_t*)(wT + (size_t)(nb + 16 * f + l15) * 128 + kk * 32 + 8 * lhi);
                #pragma unroll
                for (int m = 0; m < 4; m++)
                    acc[m][f] = __builtin_amdgcn_mfma_f32_16x16x32_bf16(wf, x4[m], acc[m][f], 0, 0, 0);
            }
        }
        float sc_ = (wv == 0) ? 0.17677669529663687f : 1.f;
        #pragma unroll
        for (int f = 0; f < 8; f++) {
            f4ld_t b4 = *(const f4ld_t*)(bias + nb + 16 * f + 4 * lhi);
            #pragma unroll
            for (int m = 0; m < 4; m++) {
                int row = row0 + 16 * m + l15;
                union { unsigned u[2]; uint2 u2; } pk;
                pk.u[0] = packbf((acc[m][f][0] + b4.x) * sc_, (acc[m][f][1] + b4.y) * sc_);
                pk.u[1] = packbf((acc[m][f][2] + b4.z) * sc_, (acc[m][f][3] + b4.w) * sc_);
                *(uint2*)(qkbuf + (size_t)row * 256 + nb + 16 * f + 4 * lhi) = pk.u2;
            }
        }
    } else {
        int d16base = (wv - 2) * 4;
        fv4_t acc[4][4];   // [m][f]
        for (int m = 0; m < 4; m++) for (int f = 0; f < 4; f++) acc[m][f] = (fv4_t){0.f, 0.f, 0.f, 0.f};
        for (int kk = 0; kk < 4; kk++) {
            sv8_t x4[4];
            #pragma unroll
            for (int m = 0; m < 4; m++) {
                int ar = 16 * m + l15;
                x4[m] = lds_ld8(xt, ar * 256 + SWZB(ar, (kk * 32 + 8 * lhi) * 2));
            }
            #pragma unroll
            for (int f = 0; f < 4; f++) {
                sv8_t wf = *(const sv8_t*)(wT + (size_t)(256 + (d16base + f) * 16 + l15) * 128 + kk * 32 + 8 * lhi);
                #pragma unroll
                for (int m = 0; m < 4; m++)
                    acc[m][f] = __builtin_amdgcn_mfma_f32_16x16x32_bf16(wf, x4[m], acc[m][f], 0, 0, 0);
            }
        }
        #pragma unroll
        for (int f = 0; f < 4; f++) {
            f4ld_t b4 = *(const f4ld_t*)(bias + 256 + (d16base + f) * 16 + 4 * lhi);
            #pragma unroll
            for (int r = 0; r < 4; r++) {
                int d = (d16base + f) * 16 + 4 * lhi + r;
                #pragma unroll
                for (int m = 0; m < 4; m++) {
                    int row = row0 + 16 * m + l15;
                    int win = row / 98, tok = row - win * 98;
                    vT[(size_t)win * VT_WSTRIDE + d * 112 + tok] = f2bf(acc[m][f][r] + b4[r]);
                }
            }
        }
    }
}

// ---------------- attention core + proj, one block per window ----------------
// Swapped QK^T, in-lane softmax; all 7 Q fragments hoisted (ms loop unrolled).
__global__ __launch_bounds__(256) void k_attn_proj(const unsigned short* __restrict__ qk,
                                                   const unsigned short* __restrict__ vT,
                                                   const float* __restrict__ biasb,  // [4][q 112][k 112]
                                                   const unsigned short* __restrict__ pwT, // [128][128]
                                                   const float* __restrict__ pb,
                                                   float* __restrict__ xbuf,
                                                   int shifted) {
    __shared__ unsigned short pt[4 * 16 * 128];
    __shared__ unsigned short ot[112 * 128];
    __shared__ int lablut[112];
    int win = blockIdx.x;
    int tid = threadIdx.x;
    int wv = tid >> 6, lane = tid & 63;
    int head = wv;
    int l15 = lane & 15, lhi = lane >> 4;
    int wrem = win & 255;
    int tw = wrem >> 6, hw = (wrem >> 3) & 7, ww = wrem & 7;

    for (int m = tid; m < 112; m += 256) {
        int t0 = min(m, 97);
        int it = t0 / 49, r2 = t0 - it * 49, ih = r2 / 7, iw = r2 - ih * 7;
        int lab = 0;
        if (shifted) {
            int t = tw * 2 + it, h = hw * 7 + ih, w = ww * 7 + iw;
            int ct = (t < TT - 2) ? 0 : ((t < TT - 1) ? 1 : 2);
            int ch = (h < HH - 7) ? 0 : ((h < HH - 3) ? 1 : 2);
            int cw = (w < WW2 - 7) ? 0 : ((w < WW2 - 3) ? 1 : 2);
            lab = ct * 9 + ch * 3 + cw;
        }
        lablut[m] = lab;
    }
    {
        unsigned short* myp = pt + wv * 16 * 128;
        for (int idx = lane; idx < 256; idx += 64) {
            int r = idx >> 4, c = 112 + (idx & 15);
            lds_st1(myp, r * 256 + SWZB(r, c * 2), 0);
        }
    }
    __syncthreads();

    size_t rowbase = (size_t)win * 98;
    sv8_t kf[7], qaf[7];
    #pragma unroll
    for (int j = 0; j < 7; j++) {
        int tok = min(16 * j + l15, 97);
        kf[j]  = *(const sv8_t*)(qk + (rowbase + tok) * 256 + 128 + head * 32 + 8 * lhi);
        qaf[j] = *(const sv8_t*)(qk + (rowbase + tok) * 256 + head * 32 + 8 * lhi);
    }
    const unsigned short* vbase = vT + (size_t)win * VT_WSTRIDE + (head * 32) * 112;
    sv8_t vf[4][2];
    #pragma unroll
    for (int kk = 0; kk < 4; kk++)
        #pragma unroll
        for (int j = 0; j < 2; j++)
            vf[kk][j] = *(const sv8_t*)(vbase + (16 * j + l15) * 112 + kk * 32 + 8 * lhi);

    int klab[7];
    if (shifted) {
        #pragma unroll
        for (int j = 0; j < 7; j++) {
            int kb = 16 * j + 4 * lhi;
            klab[j] = lablut[kb] | (lablut[kb + 1] << 8) | (lablut[kb + 2] << 16) | (lablut[kb + 3] << 24);
        }
    }

    unsigned short* myp = pt + wv * 16 * 128;

    #pragma unroll
    for (int ms = 0; ms < 7; ms++) {
        int ql = min(16 * ms + l15, 97);
        int labq = shifted ? lablut[ql] : 0;
        const float* bq = biasb + ((size_t)head * 112 + ql) * 112;
        f4ld_t bv[7];
        #pragma unroll
        for (int j = 0; j < 7; j++)
            bv[j] = *(const f4ld_t*)(bq + 16 * j + 4 * lhi);
        fv4_t sc[7];
        __builtin_amdgcn_s_setprio(1);
        #pragma unroll
        for (int j = 0; j < 7; j++) {
            fv4_t z = {0.f, 0.f, 0.f, 0.f};
            sc[j] = __builtin_amdgcn_mfma_f32_16x16x32_bf16(kf[j], qaf[ms], z, 0, 0, 0);
        }
        __builtin_amdgcn_s_setprio(0);
        float mx = -1e30f;
        #pragma unroll
        for (int j = 0; j < 7; j++) {
            #pragma unroll
            for (int r = 0; r < 4; r++) {
                float s = sc[j][r] + bv[j][r];
                if (shifted && (((klab[j] >> (8 * r)) & 255) != labq)) s -= 100.f;
                if (16 * j + 4 * lhi + r >= 98) s = -1e30f;
                sc[j][r] = s;
                mx = fmaxf(mx, s);
            }
        }
        mx = fmaxf(mx, __shfl_xor(mx, 16));
        mx = fmaxf(mx, __shfl_xor(mx, 32));
        float sm = 0.f;
        #pragma unroll
        for (int j = 0; j < 7; j++)
            #pragma unroll
            for (int r = 0; r < 4; r++) {
                float p = __expf(sc[j][r] - mx);
                sc[j][r] = p;
                sm += p;
            }
        sm += __shfl_xor(sm, 16);
        sm += __shfl_xor(sm, 32);
        float inv = 1.f / sm;
        #pragma unroll
        for (int j = 0; j < 7; j++) {
            union { unsigned u[2]; uint2 u2; } pk;
            pk.u[0] = packbf(sc[j][0] * inv, sc[j][1] * inv);
            pk.u[1] = packbf(sc[j][2] * inv, sc[j][3] * inv);
            *(uint2*)((char*)myp + l15 * 256 + SWZB(l15, (16 * j + 4 * lhi) * 2)) = pk.u2;
        }
        fv4_t oacc[2] = {{0.f, 0.f, 0.f, 0.f}, {0.f, 0.f, 0.f, 0.f}};
        __builtin_amdgcn_s_setprio(1);
        for (int kk = 0; kk < 4; kk++) {
            sv8_t pa = lds_ld8(myp, l15 * 256 + SWZB(l15, (kk * 32 + 8 * lhi) * 2));
            #pragma unroll
            for (int j = 0; j < 2; j++)
                oacc[j] = __builtin_amdgcn_mfma_f32_16x16x32_bf16(pa, vf[kk][j], oacc[j], 0, 0, 0);
        }
        __builtin_amdgcn_s_setprio(0);
        #pragma unroll
        for (int r = 0; r < 4; r++) {
            int orow = 16 * ms + 4 * lhi + r;
            #pragma unroll
            for (int j = 0; j < 2; j++) {
                int ocol = head * 32 + 16 * j + l15;
                float v = (orow < 98) ? oacc[j][r] : 0.f;
                lds_st1(ot, orow * 256 + SWZB(orow, ocol * 2), f2bf(v));
            }
        }
    }
    __syncthreads();

    {
        int nb = wv * 32;
        fv4_t acc[7][2];
        for (int m = 0; m < 7; m++) for (int j = 0; j < 2; j++) acc[m][j] = (fv4_t){0.f, 0.f, 0.f, 0.f};
        for (int kk = 0; kk < 4; kk++) {
            sv8_t b[2];
            #pragma unroll
            for (int j = 0; j < 2; j++)
                b[j] = *(const sv8_t*)(pwT + (size_t)(nb + 16 * j + l15) * 128 + kk * 32 + 8 * lhi);
            __builtin_amdgcn_s_setprio(1);
            #pragma unroll
            for (int m = 0; m < 7; m++) {
                int ar = 16 * m + l15;
                sv8_t a = lds_ld8(ot, ar * 256 + SWZB(ar, (kk * 32 + 8 * lhi) * 2));
                #pragma unroll
                for (int j = 0; j < 2; j++)
                    acc[m][j] = __builtin_amdgcn_mfma_f32_16x16x32_bf16(a, b[j], acc[m][j], 0, 0, 0);
            }
            __builtin_amdgcn_s_setprio(0);
        }
        int b_ = win >> 8;
        for (int m = 0; m < 7; m++)
            #pragma unroll
            for (int r = 0; r < 4; r++) {
                int row = 16 * m + lhi * 4 + r;
                if (row < 98) {
                    int it = row / 49, r2 = row - it * 49, ih = r2 / 7, iw = r2 - ih * 7;
                    int t = tw * 2 + it, h = hw * 7 + ih, w = ww * 7 + iw;
                    if (shifted) {
                        t += 1; if (t >= TT) t -= TT;
                        h += 3; if (h >= HH) h -= HH;
                        w += 3; if (w >= WW2) w -= WW2;
                    }
                    float* xp = xbuf + ((size_t)b_ * PSPAT + t * (HH * WW2) + h * WW2 + w) * 128 + nb;
                    #pragma unroll
                    for (int j = 0; j < 2; j++) {
                        int c = 16 * j + l15;
                        xp[c] += acc[m][j][r] + pb[nb + c];
                    }
                }
            }
    }
}

// ---------------- fused LN2 + fc1 + GELU + fc2 + residual (+final transpose) ----
// [REVERTED to round-11 best: reg-staged ping-pong, loads 2 phases ahead]
#define LOAD_CHUNK(c, R)                                                                   \
    if ((c) < 16) {                                                                        \
        if (((c) & 2) == 0) {                                                              \
            _Pragma("unroll")                                                              \
            for (int i_ = 0; i_ < 4; i_++)                                                 \
                R[i_] = *(const sv8_t*)(w1T + (size_t)(((c) >> 2) * 128 + ((c)&1) * 64 + i_ * 16 + r1) * 128 + (c1 >> 1)); \
        } else {                                                                           \
            _Pragma("unroll")                                                              \
            for (int i_ = 0; i_ < 4; i_++)                                                 \
                R[i_] = *(const sv8_t*)(w2T + (size_t)(i_ * 32 + r2) * 512 + ((c) >> 2) * 128 + ((c)&1) * 64 + (c2 >> 1)); \
        }                                                                                  \
    }
#define WRITE_CHUNK(c, R)                                                                  \
    if ((c) < 16) {                                                                        \
        unsigned short* bst_ = Bst[(c)&1];                                                 \
        if (((c) & 2) == 0) {                                                              \
            _Pragma("unroll")                                                              \
            for (int i_ = 0; i_ < 4; i_++)                                                 \
                lds_st8(bst_, (i_ * 16 + r1) * 256 + SWZB(i_ * 16 + r1, c1), R[i_]);       \
        } else {                                                                           \
            _Pragma("unroll")                                                              \
            for (int i_ = 0; i_ < 4; i_++)                                                 \
                lds_st8(bst_, (i_ * 32 + r2) * 128 + SWZB(i_ * 32 + r2, c2), R[i_]);       \
        }                                                                                  \
    }

__global__ __launch_bounds__(256, 2) void k_mlp(const float* __restrict__ xin,
                                                const float* __restrict__ g,
                                                const float* __restrict__ be,
                                                const unsigned short* __restrict__ w1T,  // [512][128]
                                                const float* __restrict__ b1p,
                                                const unsigned short* __restrict__ w2T,  // [128][512]
                                                const float* __restrict__ b2p,
                                                float* __restrict__ xbuf,
                                                float* __restrict__ outp,
                                                int final_layer) {
    __shared__ unsigned short A[4][32 * 128];   // 32 KB: per-wave xt then U slice
    __shared__ unsigned short Bst[2][8192];     // 2 x 16 KB ping-pong chunks
    int tid = threadIdx.x;
    int wv = tid >> 6, lane = tid & 63, l15 = lane & 15, lhi = lane >> 4;
    unsigned short* bw = A[wv];
    int tok0 = blockIdx.x * 128 + wv * 32;

    int r1 = tid >> 4, c1 = (tid & 15) * 16;   // w1 chunk coords (64x128)
    int r2 = tid >> 3, c2 = (tid & 7) * 16;    // w2 chunk coords (128x64)

    sv8_t wA[4], wB[4];
    LOAD_CHUNK(0, wA)                          // hidden under LN

    // ---- LN (wave-private xt in A[wv])
    #pragma unroll
    for (int tf = 0; tf < 2; tf++) {
        int lrow = 16 * tf + l15;
        const float* src = xin + (size_t)(tok0 + lrow) * 128 + lhi * 32;
        float v[32];
        float s = 0.f, sq = 0.f;
        #pragma unroll
        for (int i = 0; i < 8; i++) {
            f4ld_t f = *(const f4ld_t*)(src + i * 4);
            v[i * 4 + 0] = f.x; v[i * 4 + 1] = f.y; v[i * 4 + 2] = f.z; v[i * 4 + 3] = f.w;
            s += f.x + f.y + f.z + f.w;
            sq += f.x * f.x + f.y * f.y + f.z * f.z + f.w * f.w;
        }
        s += __shfl_xor(s, 16); sq += __shfl_xor(sq, 16);
        s += __shfl_xor(s, 32); sq += __shfl_xor(sq, 32);
        float mu = s * (1.f / 128.f);
        float var = sq * (1.f / 128.f) - mu * mu;
        float rs = rsqrtf(var + 1e-5f);
        #pragma unroll
        for (int j = 0; j < 4; j++) {
            int c0 = lhi * 32 + 8 * j;
            f4ld_t g0 = *(const f4ld_t*)(g + c0);
            f4ld_t g1 = *(const f4ld_t*)(g + c0 + 4);
            f4ld_t b0 = *(const f4ld_t*)(be + c0);
            f4ld_t b1 = *(const f4ld_t*)(be + c0 + 4);
            float y0 = (v[8 * j + 0] - mu) * rs * g0.x + b0.x;
            float y1 = (v[8 * j + 1] - mu) * rs * g0.y + b0.y;
            float y2 = (v[8 * j + 2] - mu) * rs * g0.z + b0.z;
            float y3 = (v[8 * j + 3] - mu) * rs * g0.w + b0.w;
            float y4 = (v[8 * j + 4] - mu) * rs * g1.x + b1.x;
            float y5 = (v[8 * j + 5] - mu) * rs * g1.y + b1.y;
            float y6 = (v[8 * j + 6] - mu) * rs * g1.z + b1.z;
            float y7 = (v[8 * j + 7] - mu) * rs * g1.w + b1.w;
            union { unsigned u[4]; sv8_t s8; } pk;
            pk.u[0] = packbf(y0, y1); pk.u[1] = packbf(y2, y3);
            pk.u[2] = packbf(y4, y5); pk.u[3] = packbf(y6, y7);
            lds_st8(bw, lrow * 256 + SWZB(lrow, 64 * lhi + 16 * j), pk.s8);
        }
    }
    sv8_t xf[2][4];
    #pragma unroll
    for (int tf = 0; tf < 2; tf++)
        #pragma unroll
        for (int kk = 0; kk < 4; kk++) {
            int lrow = 16 * tf + l15;
            xf[tf][kk] = lds_ld8(bw, lrow * 256 + SWZB(lrow, 64 * kk + 16 * lhi));
        }

    fv4_t acc2[8][2];
    #pragma unroll
    for (int cg = 0; cg < 8; cg++)
        #pragma unroll
        for (int tf = 0; tf < 2; tf++) acc2[cg][tf] = (fv4_t){0.f, 0.f, 0.f, 0.f};

    // prologue: stage chunk0, issue chunk1
    WRITE_CHUNK(0, wA)
    LOAD_CHUNK(1, wB)
    __syncthreads();

    #pragma unroll
    for (int q = 0; q < 4; q++) {
        // ---- phase s=0: fc1 fg 0..3 from Bst[0]
        {
            const int c = 4 * q;
            WRITE_CHUNK(c + 1, wB)
            LOAD_CHUNK(c + 2, wA)
            #pragma unroll
            for (int f = 0; f < 4; f++) {
                int fg = f;
                sv8_t wf[4];
                #pragma unroll
                for (int kk = 0; kk < 4; kk++) {
                    int wrow = 16 * f + l15;
                    wf[kk] = lds_ld8(Bst[0], wrow * 256 + SWZB(wrow, kk * 64 + 16 * lhi));
                }
                fv4_t a1[2] = {{0.f, 0.f, 0.f, 0.f}, {0.f, 0.f, 0.f, 0.f}};
                __builtin_amdgcn_s_setprio(1);
                #pragma unroll
                for (int kk = 0; kk < 4; kk++) {
                    a1[0] = __builtin_amdgcn_mfma_f32_16x16x32_bf16(wf[kk], xf[0][kk], a1[0], 0, 0, 0);
                    a1[1] = __builtin_amdgcn_mfma_f32_16x16x32_bf16(wf[kk], xf[1][kk], a1[1], 0, 0, 0);
                }
                __builtin_amdgcn_s_setprio(0);
                f4ld_t b4 = *(const f4ld_t*)(b1p + q * 128 + 16 * fg + 4 * lhi);
                #pragma unroll
                for (int tf = 0; tf < 2; tf++) {
                    float g0 = gelu_f(a1[tf][0] + b4.x);
                    float g1 = gelu_f(a1[tf][1] + b4.y);
                    float g2 = gelu_f(a1[tf][2] + b4.z);
                    float g3 = gelu_f(a1[tf][3] + b4.w);
                    union { unsigned u[2]; uint2 u2; } pk;
                    pk.u[0] = packbf(g0, g1); pk.u[1] = packbf(g2, g3);
                    int lrow = 16 * tf + l15;
                    *(uint2*)((char*)bw + lrow * 256 + SWZB(lrow, 32 * fg + 8 * lhi)) = pk.u2;
                }
            }
            __syncthreads();
        }
        // ---- phase s=1: fc1 fg 4..7 from Bst[1]
        {
            const int c = 4 * q + 1;
            WRITE_CHUNK(c + 1, wA)
            LOAD_CHUNK(c + 2, wB)
            #pragma unroll
            for (int f = 0; f < 4; f++) {
                int fg = 4 + f;
                sv8_t wf[4];
                #pragma unroll
                for (int kk = 0; kk < 4; kk++) {
                    int wrow = 16 * f + l15;
                    wf[kk] = lds_ld8(Bst[1], wrow * 256 + SWZB(wrow, kk * 64 + 16 * lhi));
                }
                fv4_t a1[2] = {{0.f, 0.f, 0.f, 0.f}, {0.f, 0.f, 0.f, 0.f}};
                __builtin_amdgcn_s_setprio(1);
                #pragma unroll
                for (int kk = 0; kk < 4; kk++) {
                    a1[0] = __builtin_amdgcn_mfma_f32_16x16x32_bf16(wf[kk], xf[0][kk], a1[0], 0, 0, 0);
                    a1[1] = __builtin_amdgcn_mfma_f32_16x16x32_bf16(wf[kk], xf[1][kk], a1[1], 0, 0, 0);
                }
                __builtin_amdgcn_s_setprio(0);
                f4ld_t b4 = *(const f4ld_t*)(b1p + q * 128 + 16 * fg + 4 * lhi);
                #pragma unroll
                for (int tf = 0; tf < 2; tf++) {
                    float g0 = gelu_f(a1[tf][0] + b4.x);
                    float g1 = gelu_f(a1[tf][1] + b4.y);
                    float g2 = gelu_f(a1[tf][2] + b4.z);
                    float g3 = gelu_f(a1[tf][3] + b4.w);
                    union { unsigned u[2]; uint2 u2; } pk;
                    pk.u[0] = packbf(g0, g1); pk.u[1] = packbf(g2, g3);
                    int lrow = 16 * tf + l15;
                    *(uint2*)((char*)bw + lrow * 256 + SWZB(lrow, 32 * fg + 8 * lhi)) = pk.u2;
                }
            }
            __syncthreads();
        }
        // ---- phase s=2: fc2 kq 0,1 from Bst[0]
        {
            const int c = 4 * q + 2;
            WRITE_CHUNK(c + 1, wB)
            LOAD_CHUNK(c + 2, wA)
            #pragma unroll
            for (int kq = 0; kq < 2; kq++) {
                sv8_t uf[2];
                #pragma unroll
                for (int tf = 0; tf < 2; tf++) {
                    int lrow = 16 * tf + l15;
                    uf[tf] = lds_ld8(bw, lrow * 256 + SWZB(lrow, 64 * kq + 16 * lhi));
                }
                #pragma unroll
                for (int cb = 0; cb < 2; cb++) {
                    sv8_t w2f[4];
                    #pragma unroll
                    for (int cc = 0; cc < 4; cc++) {
                        int wrow = 16 * (4 * cb + cc) + l15;
                        w2f[cc] = lds_ld8(Bst[0], wrow * 128 + SWZB(wrow, kq * 64 + 16 * lhi));
                    }
                    __builtin_amdgcn_s_setprio(1);
                    #pragma unroll
                    for (int cc = 0; cc < 4; cc++) {
                        int cg = 4 * cb + cc;
                        acc2[cg][0] = __builtin_amdgcn_mfma_f32_16x16x32_bf16(w2f[cc], uf[0], acc2[cg][0], 0, 0, 0);
                        acc2[cg][1] = __builtin_amdgcn_mfma_f32_16x16x32_bf16(w2f[cc], uf[1], acc2[cg][1], 0, 0, 0);
                    }
                    __builtin_amdgcn_s_setprio(0);
                }
            }
            __syncthreads();
        }
        // ---- phase s=3: fc2 kq 2,3 from Bst[1]
        {
            const int c = 4 * q + 3;
            WRITE_CHUNK(c + 1, wA)
            LOAD_CHUNK(c + 2, wB)
            #pragma unroll
            for (int kq = 2; kq < 4; kq++) {
                sv8_t uf[2];
                #pragma unroll
                for (int tf = 0; tf < 2; tf++) {
                    int lrow = 16 * tf + l15;
                    uf[tf] = lds_ld8(bw, lrow * 256 + SWZB(lrow, 64 * kq + 16 * lhi));
                }
                #pragma unroll
                for (int cb = 0; cb < 2; cb++) {
                    sv8_t w2f[4];
                    #pragma unroll
                    for (int cc = 0; cc < 4; cc++) {
                        int wrow = 16 * (4 * cb + cc) + l15;
                        w2f[cc] = lds_ld8(Bst[1], wrow * 128 + SWZB(wrow, (kq - 2) * 64 + 16 * lhi));
                    }
                    __builtin_amdgcn_s_setprio(1);
                    #pragma unroll
                    for (int cc = 0; cc < 4; cc++) {
                        int cg = 4 * cb + cc;
                        acc2[cg][0] = __builtin_amdgcn_mfma_f32_16x16x32_bf16(w2f[cc], uf[0], acc2[cg][0], 0, 0, 0);
                        acc2[cg][1] = __builtin_amdgcn_mfma_f32_16x16x32_bf16(w2f[cc], uf[1], acc2[cg][1], 0, 0, 0);
                    }
                    __builtin_amdgcn_s_setprio(0);
                }
            }
            __syncthreads();
        }
    }
    // ---- epilogue
    if (!final_layer) {
        #pragma unroll
        for (int tf = 0; tf < 2; tf++) {
            int row = tok0 + 16 * tf + l15;
            #pragma unroll
            for (int cg = 0; cg < 8; cg++) {
                int c0 = 16 * cg + 4 * lhi;
                f4ld_t b4 = *(const f4ld_t*)(b2p + c0);
                float* xp = xbuf + (size_t)row * 128 + c0;
                f4ld_t o = *(f4ld_t*)xp;
                o.x += acc2[cg][tf][0] + b4.x;
                o.y += acc2[cg][tf][1] + b4.y;
                o.z += acc2[cg][tf][2] + b4.z;
                o.w += acc2[cg][tf][3] + b4.w;
                *(f4ld_t*)xp = o;
            }
        }
    } else {
        // final layer: write transposed out[b][c][p] = xbuf + mlp (fuses transpose_out)
        #pragma unroll
        for (int tf = 0; tf < 2; tf++) {
            int row = tok0 + 16 * tf + l15;
            int b_ = row / PSPAT, p = row - b_ * PSPAT;
            float* ob = outp + (size_t)b_ * 128 * PSPAT + p;
            #pragma unroll
            for (int cg = 0; cg < 8; cg++) {
                int c0 = 16 * cg + 4 * lhi;
                f4ld_t b4 = *(const f4ld_t*)(b2p + c0);
                const float* xp = xbuf + (size_t)row * 128 + c0;
                f4ld_t o = *(const f4ld_t*)xp;
                o.x += acc2[cg][tf][0] + b4.x;
                o.y += acc2[cg][tf][1] + b4.y;
                o.z += acc2[cg][tf][2] + b4.z;
                o.w += acc2[cg][tf][3] + b4.w;
                ob[(size_t)(c0 + 0) * PSPAT] = o.x;
                ob[(size_t)(c0 + 1) * PSPAT] = o.y;
                ob[(size_t)(c0 + 2) * PSPAT] = o.z;
                ob[(size_t)(c0 + 3) * PSPAT] = o.w;
            }
        }
    }
}

extern "C" void kernel_launch(void* const* d_in, const int* in_sizes, int n_in,
                              void* d_out, int out_size, void* d_ws, size_t ws_size,
                              hipStream_t stream) {
    const float* x_in   = (const float*)d_in[0];
    const float* ln1_g  = (const float*)d_in[1];
    const float* ln1_b  = (const float*)d_in[2];
    const float* qkv_w  = (const float*)d_in[3];
    const float* qkv_b  = (const float*)d_in[4];
    const float* rpb    = (const float*)d_in[5];
    const float* proj_w = (const float*)d_in[6];
    const float* proj_b = (const float*)d_in[7];
    const float* ln2_g  = (const float*)d_in[8];
    const float* ln2_b  = (const float*)d_in[9];
    const float* fc1_w  = (const float*)d_in[10];
    const float* fc1_b  = (const float*)d_in[11];
    const float* fc2_w  = (const float*)d_in[12];
    const float* fc2_b  = (const float*)d_in[13];
    float* out = (float*)d_out;

    char* ws = (char*)d_ws;
    float* xbuf = (float*)ws;                                        // 102,760,448 B
    unsigned short* qkbuf = (unsigned short*)(ws + 102760448);       // 102,760,448 B
    unsigned short* vTbuf = (unsigned short*)(ws + 205520896);       //  58,720,256 B
    unsigned short* wbase = (unsigned short*)(ws + 264241408);       //     786,432 B
    float* biasb = (float*)(ws + 264241408 + 786432);                //     401,408 B

    k_transpose_in<<<dim3(PSPAT / 32, 4, BB), dim3(32, 8), 0, stream>>>(x_in, xbuf);

    for (int l = 0; l < 2; l++) {
        unsigned short* wqT = wbase + (size_t)l * 196608;
        unsigned short* wpT = wqT + 49152;
        unsigned short* w1T = wpT + 16384;
        unsigned short* w2T = w1T + 65536;
        k_prep_w<<<dim3(12, 4), dim3(32, 8), 0, stream>>>(qkv_w + (size_t)l * 49152, wqT, 128, 384);
        k_prep_w<<<dim3(4, 4),  dim3(32, 8), 0, stream>>>(proj_w + (size_t)l * 16384, wpT, 128, 128);
        k_prep_w<<<dim3(16, 4), dim3(32, 8), 0, stream>>>(fc1_w + (size_t)l * 65536, w1T, 128, 512);
        k_prep_w<<<dim3(4, 16), dim3(32, 8), 0, stream>>>(fc2_w + (size_t)l * 65536, w2T, 512, 128);
    }
    k_prep_bias<<<dim3(112, 4, 2), 112, 0, stream>>>(rpb, biasb);

    for (int layer = 0; layer < 2; layer++) {
        unsigned short* wqT = wbase + (size_t)layer * 196608;
        unsigned short* wpT = wqT + 49152;
        unsigned short* w1T = wpT + 16384;
        unsigned short* w2T = w1T + 65536;
        int shifted = layer & 1;

        k_qkv<<<TOK_TOTAL / 64, 256, 0, stream>>>(xbuf, ln1_g + layer * 128, ln1_b + layer * 128,
                                                  wqT, qkv_b + layer * 384, qkbuf, vTbuf, shifted);
        k_attn_proj<<<BNW, 256, 0, stream>>>(qkbuf, vTbuf, biasb + (size_t)layer * 4 * 112 * 112,
                                             wpT, proj_b + layer * 128, xbuf, shifted);
        k_mlp<<<TOK_TOTAL / 128, 256, 0, stream>>>(xbuf, ln2_g + layer * 128, ln2_b + layer * 128,
                                                   w1T, fc1_b + layer * 512, w2T, fc2_b + layer * 128,
                                                   xbuf, out, layer == 1);
    }
}

// Round 14
// 892.496 us; speedup vs baseline: 1.1870x; 1.1870x over previous
//
#include <hip/hip_runtime.h>
#include <hip/hip_bf16.h>

typedef __attribute__((ext_vector_type(8))) short sv8_t;   // 8 bf16 (4 VGPR)
typedef __attribute__((ext_vector_type(4))) float fv4_t;   // MFMA accumulator
typedef __attribute__((ext_vector_type(4))) float f4ld_t;  // global float4 load

#define BB 8
#define TT 8
#define HH 56
#define WW2 56
#define NTOK 98
#define BNW 2048
#define PSPAT 25088
#define TOK_TOTAL 200704
#define ACT_ELEMS 25690112
#define VT_WSTRIDE 14336   // 128 * 112

#define SWZB(row, cb) ((cb) ^ ((((unsigned)(row)) & 7u) << 4))

__device__ __forceinline__ unsigned short f2bf(float f) {
    union { float f; unsigned u; } x; x.f = f;
    unsigned r = x.u + 0x7fffu + ((x.u >> 16) & 1u);
    return (unsigned short)(r >> 16);
}
// packed pair via v_cvt_pk_bf16_f32 (RNE, bit-identical to f2bf pair, 1 inst)
__device__ __forceinline__ unsigned packbf(float lo, float hi) {
    __hip_bfloat162 h = __float22bfloat162_rn(make_float2(lo, hi));
    union { __hip_bfloat162 h; unsigned u; } cv; cv.h = h; return cv.u;
}
__device__ __forceinline__ sv8_t lds_ld8(const unsigned short* p, int byteoff) {
    return *(const sv8_t*)((const char*)p + byteoff);
}
__device__ __forceinline__ void lds_st8(unsigned short* p, int byteoff, sv8_t v) {
    *(sv8_t*)((char*)p + byteoff) = v;
}
__device__ __forceinline__ void lds_st1(unsigned short* p, int byteoff, unsigned short v) {
    *(unsigned short*)((char*)p + byteoff) = v;
}
// GELU, tanh form via hardware exp (~10 VALU ops vs erff's ~30)
__device__ __forceinline__ float gelu_f(float v) {
    float u = v * (0.7978845608028654f + 0.035677408136300125f * v * v);
    float e = __expf(2.f * u);
    float th = 1.f - 2.f / (e + 1.f);
    return 0.5f * v * (1.f + th);
}

// ---------------- transpose in: (B,C,P) -> (B,P,C) f32 ----------------
__global__ __launch_bounds__(256) void k_transpose_in(const float* __restrict__ in,
                                                      float* __restrict__ xbuf) {
    __shared__ float tile[32][33];
    int p0 = blockIdx.x * 32, c0 = blockIdx.y * 32, b = blockIdx.z;
    int pi = threadIdx.x, ci = threadIdx.y;
    const float* src = in + ((size_t)b * 128 + c0) * PSPAT + p0;
    for (int r = 0; r < 32; r += 8)
        tile[ci + r][pi] = src[(size_t)(ci + r) * PSPAT + pi];
    __syncthreads();
    float* dst = xbuf + ((size_t)b * PSPAT + p0) * 128 + c0;
    for (int r = 0; r < 32; r += 8)
        dst[(size_t)(ci + r) * 128 + pi] = tile[pi][ci + r];
}

// ---------------- weight prep: in f32 [K][N] -> out bf16 [N][K] ----------------
__global__ __launch_bounds__(256) void k_prep_w(const float* __restrict__ in,
                                                unsigned short* __restrict__ out,
                                                int K, int N) {
    __shared__ float tile[32][33];
    int n0 = blockIdx.x * 32, k0 = blockIdx.y * 32;
    int x = threadIdx.x, y = threadIdx.y;
    for (int r = 0; r < 32; r += 8)
        tile[y + r][x] = in[(size_t)(k0 + y + r) * N + n0 + x];
    __syncthreads();
    for (int r = 0; r < 32; r += 8)
        out[(size_t)(n0 + y + r) * K + k0 + x] = f2bf(tile[x][y + r]);
}

// ---------------- bias prep: biasb[layer][head][q row][k col] ----------------
__global__ void k_prep_bias(const float* __restrict__ rpb, float* __restrict__ biasb) {
    int col = threadIdx.x;   // 0..111 (k index)
    int row = blockIdx.x;    // 0..111 (q index)
    int head = blockIdx.y;   // 0..3
    int layer = blockIdx.z;
    int tn = min(row, 97), tm = min(col, 97);
    int itn = tn / 49, rn = tn - itn * 49, ihn = rn / 7, iwn = rn - ihn * 7;
    int itm = tm / 49, rm = tm - itm * 49, ihm = rm / 7, iwm = rm - ihm * 7;
    int dt = itn - itm + 1, dh = ihn - ihm + 6, dw = iwn - iwm + 6;
    float v = rpb[((size_t)layer * 507 + dt * 169 + dh * 13 + dw) * 4 + head];
    biasb[(((size_t)layer * 4 + head) * 112 + row) * 112 + col] = v;
}

// ---------------- fused LN1 + gather + qkv GEMM ----------------
// ALL waves use swapped-operand MFMA (C: lane=token, reg=4 consecutive cols)
// -> packed 8B stores. Waves 0/1: Q,K -> qkbuf[tok][256]; waves 2/3: V -> vT.
__global__ __launch_bounds__(256) void k_qkv(const float* __restrict__ xbuf,
                                             const float* __restrict__ g,
                                             const float* __restrict__ be,
                                             const unsigned short* __restrict__ wT,  // [384][128]
                                             const float* __restrict__ bias,         // [384]
                                             unsigned short* __restrict__ qkbuf,
                                             unsigned short* __restrict__ vT,
                                             int shifted) {
    __shared__ unsigned short xt[64 * 128];
    int tid = threadIdx.x;
    int row0 = blockIdx.x * 64;
    {
        int r = tid >> 2, q = tid & 3;
        int wt = row0 + r;
        int win = wt / 98, n = wt - win * 98;
        int b_ = win >> 8, wrem = win & 255;
        int tw = wrem >> 6, hw = (wrem >> 3) & 7, ww = wrem & 7;
        int it = n / 49, r2 = n - it * 49, ih = r2 / 7, iw = r2 - ih * 7;
        int t = tw * 2 + it, h = hw * 7 + ih, w = ww * 7 + iw;
        if (shifted) {
            t += 1; if (t >= TT) t -= TT;
            h += 3; if (h >= HH) h -= HH;
            w += 3; if (w >= WW2) w -= WW2;
        }
        const float* src = xbuf + ((size_t)b_ * PSPAT + t * (HH * WW2) + h * WW2 + w) * 128 + q * 32;
        float v[32];
        float s = 0.f, sq = 0.f;
        for (int i = 0; i < 8; i++) {
            f4ld_t f = *(const f4ld_t*)(src + i * 4);
            v[i * 4 + 0] = f.x; v[i * 4 + 1] = f.y; v[i * 4 + 2] = f.z; v[i * 4 + 3] = f.w;
            s += f.x + f.y + f.z + f.w;
            sq += f.x * f.x + f.y * f.y + f.z * f.z + f.w * f.w;
        }
        s += __shfl_xor(s, 1); sq += __shfl_xor(sq, 1);
        s += __shfl_xor(s, 2); sq += __shfl_xor(sq, 2);
        float mu = s * (1.f / 128.f);
        float var = sq * (1.f / 128.f) - mu * mu;
        float rs = rsqrtf(var + 1e-5f);
        for (int c0 = 0; c0 < 32; c0 += 8) {
            float y[8];
            #pragma unroll
            for (int i = 0; i < 8; i++) {
                int c = q * 32 + c0 + i;
                y[i] = (v[c0 + i] - mu) * rs * g[c] + be[c];
            }
            union { unsigned u[4]; sv8_t s8; } pk;
            pk.u[0] = packbf(y[0], y[1]); pk.u[1] = packbf(y[2], y[3]);
            pk.u[2] = packbf(y[4], y[5]); pk.u[3] = packbf(y[6], y[7]);
            lds_st8(xt, r * 256 + SWZB(r, (q * 32 + c0) * 2), pk.s8);
        }
    }
    __syncthreads();
    int wv = tid >> 6, lane = tid & 63, l15 = lane & 15, lhi = lane >> 4;

    if (wv < 2) {
        // Q (wv0) or K (wv1), swapped: C[d][tok]; 8 d16-frags, packed 8B stores
        int nb = wv * 128;
        fv4_t acc[4][8];
        for (int m = 0; m < 4; m++) for (int f = 0; f < 8; f++) acc[m][f] = (fv4_t){0.f, 0.f, 0.f, 0.f};
        for (int kk = 0; kk < 4; kk++) {
            sv8_t x4[4];
            #pragma unroll
            for (int m = 0; m < 4; m++) {
                int ar = 16 * m + l15;
                x4[m] = lds_ld8(xt, ar * 256 + SWZB(ar, (kk * 32 + 8 * lhi) * 2));
            }
            #pragma unroll
            for (int f = 0; f < 8; f++) {
                sv8_t wf = *(const sv8_t*)(wT + (size_t)(nb + 16 * f + l15) * 128 + kk * 32 + 8 * lhi);
                #pragma unroll
                for (int m = 0; m < 4; m++)
                    acc[m][f] = __builtin_amdgcn_mfma_f32_16x16x32_bf16(wf, x4[m], acc[m][f], 0, 0, 0);
            }
        }
        float sc_ = (wv == 0) ? 0.17677669529663687f : 1.f;
        #pragma unroll
        for (int f = 0; f < 8; f++) {
            f4ld_t b4 = *(const f4ld_t*)(bias + nb + 16 * f + 4 * lhi);
            #pragma unroll
            for (int m = 0; m < 4; m++) {
                int row = row0 + 16 * m + l15;
                union { unsigned u[2]; uint2 u2; } pk;
                pk.u[0] = packbf((acc[m][f][0] + b4.x) * sc_, (acc[m][f][1] + b4.y) * sc_);
                pk.u[1] = packbf((acc[m][f][2] + b4.z) * sc_, (acc[m][f][3] + b4.w) * sc_);
                *(uint2*)(qkbuf + (size_t)row * 256 + nb + 16 * f + 4 * lhi) = pk.u2;
            }
        }
    } else {
        int d16base = (wv - 2) * 4;
        fv4_t acc[4][4];   // [m][f]
        for (int m = 0; m < 4; m++) for (int f = 0; f < 4; f++) acc[m][f] = (fv4_t){0.f, 0.f, 0.f, 0.f};
        for (int kk = 0; kk < 4; kk++) {
            sv8_t x4[4];
            #pragma unroll
            for (int m = 0; m < 4; m++) {
                int ar = 16 * m + l15;
                x4[m] = lds_ld8(xt, ar * 256 + SWZB(ar, (kk * 32 + 8 * lhi) * 2));
            }
            #pragma unroll
            for (int f = 0; f < 4; f++) {
                sv8_t wf = *(const sv8_t*)(wT + (size_t)(256 + (d16base + f) * 16 + l15) * 128 + kk * 32 + 8 * lhi);
                #pragma unroll
                for (int m = 0; m < 4; m++)
                    acc[m][f] = __builtin_amdgcn_mfma_f32_16x16x32_bf16(wf, x4[m], acc[m][f], 0, 0, 0);
            }
        }
        #pragma unroll
        for (int f = 0; f < 4; f++) {
            f4ld_t b4 = *(const f4ld_t*)(bias + 256 + (d16base + f) * 16 + 4 * lhi);
            #pragma unroll
            for (int r = 0; r < 4; r++) {
                int d = (d16base + f) * 16 + 4 * lhi + r;
                #pragma unroll
                for (int m = 0; m < 4; m++) {
                    int row = row0 + 16 * m + l15;
                    int win = row / 98, tok = row - win * 98;
                    vT[(size_t)win * VT_WSTRIDE + d * 112 + tok] = f2bf(acc[m][f][r] + b4[r]);
                }
            }
        }
    }
}

// ---------------- attention core + proj, one block per window ----------------
// [REVERTED to round-12: rolled ms loop + 1-deep qa pipeline (occupancy!)]
__global__ __launch_bounds__(256) void k_attn_proj(const unsigned short* __restrict__ qk,
                                                   const unsigned short* __restrict__ vT,
                                                   const float* __restrict__ biasb,  // [4][q 112][k 112]
                                                   const unsigned short* __restrict__ pwT, // [128][128]
                                                   const float* __restrict__ pb,
                                                   float* __restrict__ xbuf,
                                                   int shifted) {
    __shared__ unsigned short pt[4 * 16 * 128];
    __shared__ unsigned short ot[112 * 128];
    __shared__ int lablut[112];
    int win = blockIdx.x;
    int tid = threadIdx.x;
    int wv = tid >> 6, lane = tid & 63;
    int head = wv;
    int l15 = lane & 15, lhi = lane >> 4;
    int wrem = win & 255;
    int tw = wrem >> 6, hw = (wrem >> 3) & 7, ww = wrem & 7;

    for (int m = tid; m < 112; m += 256) {
        int t0 = min(m, 97);
        int it = t0 / 49, r2 = t0 - it * 49, ih = r2 / 7, iw = r2 - ih * 7;
        int lab = 0;
        if (shifted) {
            int t = tw * 2 + it, h = hw * 7 + ih, w = ww * 7 + iw;
            int ct = (t < TT - 2) ? 0 : ((t < TT - 1) ? 1 : 2);
            int ch = (h < HH - 7) ? 0 : ((h < HH - 3) ? 1 : 2);
            int cw = (w < WW2 - 7) ? 0 : ((w < WW2 - 3) ? 1 : 2);
            lab = ct * 9 + ch * 3 + cw;
        }
        lablut[m] = lab;
    }
    {
        unsigned short* myp = pt + wv * 16 * 128;
        for (int idx = lane; idx < 256; idx += 64) {
            int r = idx >> 4, c = 112 + (idx & 15);
            lds_st1(myp, r * 256 + SWZB(r, c * 2), 0);
        }
    }
    __syncthreads();

    size_t rowbase = (size_t)win * 98;
    sv8_t kf[7];
    #pragma unroll
    for (int j = 0; j < 7; j++) {
        int tok = min(16 * j + l15, 97);
        kf[j] = *(const sv8_t*)(qk + (rowbase + tok) * 256 + 128 + head * 32 + 8 * lhi);
    }
    const unsigned short* vbase = vT + (size_t)win * VT_WSTRIDE + (head * 32) * 112;
    sv8_t vf[4][2];
    #pragma unroll
    for (int kk = 0; kk < 4; kk++)
        #pragma unroll
        for (int j = 0; j < 2; j++)
            vf[kk][j] = *(const sv8_t*)(vbase + (16 * j + l15) * 112 + kk * 32 + 8 * lhi);

    int klab[7];
    if (shifted) {
        #pragma unroll
        for (int j = 0; j < 7; j++) {
            int kb = 16 * j + 4 * lhi;
            klab[j] = lablut[kb] | (lablut[kb + 1] << 8) | (lablut[kb + 2] << 16) | (lablut[kb + 3] << 24);
        }
    }

    unsigned short* myp = pt + wv * 16 * 128;

    sv8_t qa_c = *(const sv8_t*)(qk + (rowbase + l15) * 256 + head * 32 + 8 * lhi);

    for (int ms = 0; ms < 7; ms++) {
        sv8_t qa_n = qa_c;
        if (ms < 6) {
            int qtok = min(16 * (ms + 1) + l15, 97);
            qa_n = *(const sv8_t*)(qk + (rowbase + qtok) * 256 + head * 32 + 8 * lhi);
        }
        int ql = min(16 * ms + l15, 97);
        int labq = shifted ? lablut[ql] : 0;
        const float* bq = biasb + ((size_t)head * 112 + ql) * 112;
        f4ld_t bv[7];
        #pragma unroll
        for (int j = 0; j < 7; j++)
            bv[j] = *(const f4ld_t*)(bq + 16 * j + 4 * lhi);
        fv4_t sc[7];
        __builtin_amdgcn_s_setprio(1);
        #pragma unroll
        for (int j = 0; j < 7; j++) {
            fv4_t z = {0.f, 0.f, 0.f, 0.f};
            sc[j] = __builtin_amdgcn_mfma_f32_16x16x32_bf16(kf[j], qa_c, z, 0, 0, 0);
        }
        __builtin_amdgcn_s_setprio(0);
        float mx = -1e30f;
        #pragma unroll
        for (int j = 0; j < 7; j++) {
            #pragma unroll
            for (int r = 0; r < 4; r++) {
                float s = sc[j][r] + bv[j][r];
                if (shifted && (((klab[j] >> (8 * r)) & 255) != labq)) s -= 100.f;
                if (16 * j + 4 * lhi + r >= 98) s = -1e30f;
                sc[j][r] = s;
                mx = fmaxf(mx, s);
            }
        }
        mx = fmaxf(mx, __shfl_xor(mx, 16));
        mx = fmaxf(mx, __shfl_xor(mx, 32));
        float sm = 0.f;
        #pragma unroll
        for (int j = 0; j < 7; j++)
            #pragma unroll
            for (int r = 0; r < 4; r++) {
                float p = __expf(sc[j][r] - mx);
                sc[j][r] = p;
                sm += p;
            }
        sm += __shfl_xor(sm, 16);
        sm += __shfl_xor(sm, 32);
        float inv = 1.f / sm;
        #pragma unroll
        for (int j = 0; j < 7; j++) {
            union { unsigned u[2]; uint2 u2; } pk;
            pk.u[0] = packbf(sc[j][0] * inv, sc[j][1] * inv);
            pk.u[1] = packbf(sc[j][2] * inv, sc[j][3] * inv);
            *(uint2*)((char*)myp + l15 * 256 + SWZB(l15, (16 * j + 4 * lhi) * 2)) = pk.u2;
        }
        fv4_t oacc[2] = {{0.f, 0.f, 0.f, 0.f}, {0.f, 0.f, 0.f, 0.f}};
        __builtin_amdgcn_s_setprio(1);
        for (int kk = 0; kk < 4; kk++) {
            sv8_t pa = lds_ld8(myp, l15 * 256 + SWZB(l15, (kk * 32 + 8 * lhi) * 2));
            #pragma unroll
            for (int j = 0; j < 2; j++)
                oacc[j] = __builtin_amdgcn_mfma_f32_16x16x32_bf16(pa, vf[kk][j], oacc[j], 0, 0, 0);
        }
        __builtin_amdgcn_s_setprio(0);
        #pragma unroll
        for (int r = 0; r < 4; r++) {
            int orow = 16 * ms + 4 * lhi + r;
            #pragma unroll
            for (int j = 0; j < 2; j++) {
                int ocol = head * 32 + 16 * j + l15;
                float v = (orow < 98) ? oacc[j][r] : 0.f;
                lds_st1(ot, orow * 256 + SWZB(orow, ocol * 2), f2bf(v));
            }
        }
        qa_c = qa_n;
    }
    __syncthreads();

    {
        int nb = wv * 32;
        fv4_t acc[7][2];
        for (int m = 0; m < 7; m++) for (int j = 0; j < 2; j++) acc[m][j] = (fv4_t){0.f, 0.f, 0.f, 0.f};
        for (int kk = 0; kk < 4; kk++) {
            sv8_t b[2];
            #pragma unroll
            for (int j = 0; j < 2; j++)
                b[j] = *(const sv8_t*)(pwT + (size_t)(nb + 16 * j + l15) * 128 + kk * 32 + 8 * lhi);
            __builtin_amdgcn_s_setprio(1);
            #pragma unroll
            for (int m = 0; m < 7; m++) {
                int ar = 16 * m + l15;
                sv8_t a = lds_ld8(ot, ar * 256 + SWZB(ar, (kk * 32 + 8 * lhi) * 2));
                #pragma unroll
                for (int j = 0; j < 2; j++)
                    acc[m][j] = __builtin_amdgcn_mfma_f32_16x16x32_bf16(a, b[j], acc[m][j], 0, 0, 0);
            }
            __builtin_amdgcn_s_setprio(0);
        }
        int b_ = win >> 8;
        for (int m = 0; m < 7; m++)
            #pragma unroll
            for (int r = 0; r < 4; r++) {
                int row = 16 * m + lhi * 4 + r;
                if (row < 98) {
                    int it = row / 49, r2 = row - it * 49, ih = r2 / 7, iw = r2 - ih * 7;
                    int t = tw * 2 + it, h = hw * 7 + ih, w = ww * 7 + iw;
                    if (shifted) {
                        t += 1; if (t >= TT) t -= TT;
                        h += 3; if (h >= HH) h -= HH;
                        w += 3; if (w >= WW2) w -= WW2;
                    }
                    float* xp = xbuf + ((size_t)b_ * PSPAT + t * (HH * WW2) + h * WW2 + w) * 128 + nb;
                    #pragma unroll
                    for (int j = 0; j < 2; j++) {
                        int c = 16 * j + l15;
                        xp[c] += acc[m][j][r] + pb[nb + c];
                    }
                }
            }
    }
}

// ---------------- fused LN2 + fc1 + GELU + fc2 + residual (+final transpose) ----
// [round-11 best: reg-staged ping-pong, loads 2 phases ahead]
#define LOAD_CHUNK(c, R)                                                                   \
    if ((c) < 16) {                                                                        \
        if (((c) & 2) == 0) {                                                              \
            _Pragma("unroll")                                                              \
            for (int i_ = 0; i_ < 4; i_++)                                                 \
                R[i_] = *(const sv8_t*)(w1T + (size_t)(((c) >> 2) * 128 + ((c)&1) * 64 + i_ * 16 + r1) * 128 + (c1 >> 1)); \
        } else {                                                                           \
            _Pragma("unroll")                                                              \
            for (int i_ = 0; i_ < 4; i_++)                                                 \
                R[i_] = *(const sv8_t*)(w2T + (size_t)(i_ * 32 + r2) * 512 + ((c) >> 2) * 128 + ((c)&1) * 64 + (c2 >> 1)); \
        }                                                                                  \
    }
#define WRITE_CHUNK(c, R)                                                                  \
    if ((c) < 16) {                                                                        \
        unsigned short* bst_ = Bst[(c)&1];                                                 \
        if (((c) & 2) == 0) {                                                              \
            _Pragma("unroll")                                                              \
            for (int i_ = 0; i_ < 4; i_++)                                                 \
                lds_st8(bst_, (i_ * 16 + r1) * 256 + SWZB(i_ * 16 + r1, c1), R[i_]);       \
        } else {                                                                           \
            _Pragma("unroll")                                                              \
            for (int i_ = 0; i_ < 4; i_++)                                                 \
                lds_st8(bst_, (i_ * 32 + r2) * 128 + SWZB(i_ * 32 + r2, c2), R[i_]);       \
        }                                                                                  \
    }

__global__ __launch_bounds__(256, 2) void k_mlp(const float* __restrict__ xin,
                                                const float* __restrict__ g,
                                                const float* __restrict__ be,
                                                const unsigned short* __restrict__ w1T,  // [512][128]
                                                const float* __restrict__ b1p,
                                                const unsigned short* __restrict__ w2T,  // [128][512]
                                                const float* __restrict__ b2p,
                                                float* __restrict__ xbuf,
                                                float* __restrict__ outp,
                                                int final_layer) {
    __shared__ unsigned short A[4][32 * 128];   // 32 KB: per-wave xt then U slice
    __shared__ unsigned short Bst[2][8192];     // 2 x 16 KB ping-pong chunks
    int tid = threadIdx.x;
    int wv = tid >> 6, lane = tid & 63, l15 = lane & 15, lhi = lane >> 4;
    unsigned short* bw = A[wv];
    int tok0 = blockIdx.x * 128 + wv * 32;

    int r1 = tid >> 4, c1 = (tid & 15) * 16;   // w1 chunk coords (64x128)
    int r2 = tid >> 3, c2 = (tid & 7) * 16;    // w2 chunk coords (128x64)

    sv8_t wA[4], wB[4];
    LOAD_CHUNK(0, wA)                          // hidden under LN

    // ---- LN (wave-private xt in A[wv])
    #pragma unroll
    for (int tf = 0; tf < 2; tf++) {
        int lrow = 16 * tf + l15;
        const float* src = xin + (size_t)(tok0 + lrow) * 128 + lhi * 32;
        float v[32];
        float s = 0.f, sq = 0.f;
        #pragma unroll
        for (int i = 0; i < 8; i++) {
            f4ld_t f = *(const f4ld_t*)(src + i * 4);
            v[i * 4 + 0] = f.x; v[i * 4 + 1] = f.y; v[i * 4 + 2] = f.z; v[i * 4 + 3] = f.w;
            s += f.x + f.y + f.z + f.w;
            sq += f.x * f.x + f.y * f.y + f.z * f.z + f.w * f.w;
        }
        s += __shfl_xor(s, 16); sq += __shfl_xor(sq, 16);
        s += __shfl_xor(s, 32); sq += __shfl_xor(sq, 32);
        float mu = s * (1.f / 128.f);
        float var = sq * (1.f / 128.f) - mu * mu;
        float rs = rsqrtf(var + 1e-5f);
        #pragma unroll
        for (int j = 0; j < 4; j++) {
            int c0 = lhi * 32 + 8 * j;
            f4ld_t g0 = *(const f4ld_t*)(g + c0);
            f4ld_t g1 = *(const f4ld_t*)(g + c0 + 4);
            f4ld_t b0 = *(const f4ld_t*)(be + c0);
            f4ld_t b1 = *(const f4ld_t*)(be + c0 + 4);
            float y0 = (v[8 * j + 0] - mu) * rs * g0.x + b0.x;
            float y1 = (v[8 * j + 1] - mu) * rs * g0.y + b0.y;
            float y2 = (v[8 * j + 2] - mu) * rs * g0.z + b0.z;
            float y3 = (v[8 * j + 3] - mu) * rs * g0.w + b0.w;
            float y4 = (v[8 * j + 4] - mu) * rs * g1.x + b1.x;
            float y5 = (v[8 * j + 5] - mu) * rs * g1.y + b1.y;
            float y6 = (v[8 * j + 6] - mu) * rs * g1.z + b1.z;
            float y7 = (v[8 * j + 7] - mu) * rs * g1.w + b1.w;
            union { unsigned u[4]; sv8_t s8; } pk;
            pk.u[0] = packbf(y0, y1); pk.u[1] = packbf(y2, y3);
            pk.u[2] = packbf(y4, y5); pk.u[3] = packbf(y6, y7);
            lds_st8(bw, lrow * 256 + SWZB(lrow, 64 * lhi + 16 * j), pk.s8);
        }
    }
    sv8_t xf[2][4];
    #pragma unroll
    for (int tf = 0; tf < 2; tf++)
        #pragma unroll
        for (int kk = 0; kk < 4; kk++) {
            int lrow = 16 * tf + l15;
            xf[tf][kk] = lds_ld8(bw, lrow * 256 + SWZB(lrow, 64 * kk + 16 * lhi));
        }

    fv4_t acc2[8][2];
    #pragma unroll
    for (int cg = 0; cg < 8; cg++)
        #pragma unroll
        for (int tf = 0; tf < 2; tf++) acc2[cg][tf] = (fv4_t){0.f, 0.f, 0.f, 0.f};

    // prologue: stage chunk0, issue chunk1
    WRITE_CHUNK(0, wA)
    LOAD_CHUNK(1, wB)
    __syncthreads();

    #pragma unroll
    for (int q = 0; q < 4; q++) {
        // ---- phase s=0: fc1 fg 0..3 from Bst[0]
        {
            const int c = 4 * q;
            WRITE_CHUNK(c + 1, wB)
            LOAD_CHUNK(c + 2, wA)
            #pragma unroll
            for (int f = 0; f < 4; f++) {
                int fg = f;
                sv8_t wf[4];
                #pragma unroll
                for (int kk = 0; kk < 4; kk++) {
                    int wrow = 16 * f + l15;
                    wf[kk] = lds_ld8(Bst[0], wrow * 256 + SWZB(wrow, kk * 64 + 16 * lhi));
                }
                fv4_t a1[2] = {{0.f, 0.f, 0.f, 0.f}, {0.f, 0.f, 0.f, 0.f}};
                __builtin_amdgcn_s_setprio(1);
                #pragma unroll
                for (int kk = 0; kk < 4; kk++) {
                    a1[0] = __builtin_amdgcn_mfma_f32_16x16x32_bf16(wf[kk], xf[0][kk], a1[0], 0, 0, 0);
                    a1[1] = __builtin_amdgcn_mfma_f32_16x16x32_bf16(wf[kk], xf[1][kk], a1[1], 0, 0, 0);
                }
                __builtin_amdgcn_s_setprio(0);
                f4ld_t b4 = *(const f4ld_t*)(b1p + q * 128 + 16 * fg + 4 * lhi);
                #pragma unroll
                for (int tf = 0; tf < 2; tf++) {
                    float g0 = gelu_f(a1[tf][0] + b4.x);
                    float g1 = gelu_f(a1[tf][1] + b4.y);
                    float g2 = gelu_f(a1[tf][2] + b4.z);
                    float g3 = gelu_f(a1[tf][3] + b4.w);
                    union { unsigned u[2]; uint2 u2; } pk;
                    pk.u[0] = packbf(g0, g1); pk.u[1] = packbf(g2, g3);
                    int lrow = 16 * tf + l15;
                    *(uint2*)((char*)bw + lrow * 256 + SWZB(lrow, 32 * fg + 8 * lhi)) = pk.u2;
                }
            }
            __syncthreads();
        }
        // ---- phase s=1: fc1 fg 4..7 from Bst[1]
        {
            const int c = 4 * q + 1;
            WRITE_CHUNK(c + 1, wA)
            LOAD_CHUNK(c + 2, wB)
            #pragma unroll
            for (int f = 0; f < 4; f++) {
                int fg = 4 + f;
                sv8_t wf[4];
                #pragma unroll
                for (int kk = 0; kk < 4; kk++) {
                    int wrow = 16 * f + l15;
                    wf[kk] = lds_ld8(Bst[1], wrow * 256 + SWZB(wrow, kk * 64 + 16 * lhi));
                }
                fv4_t a1[2] = {{0.f, 0.f, 0.f, 0.f}, {0.f, 0.f, 0.f, 0.f}};
                __builtin_amdgcn_s_setprio(1);
                #pragma unroll
                for (int kk = 0; kk < 4; kk++) {
                    a1[0] = __builtin_amdgcn_mfma_f32_16x16x32_bf16(wf[kk], xf[0][kk], a1[0], 0, 0, 0);
                    a1[1] = __builtin_amdgcn_mfma_f32_16x16x32_bf16(wf[kk], xf[1][kk], a1[1], 0, 0, 0);
                }
                __builtin_amdgcn_s_setprio(0);
                f4ld_t b4 = *(const f4ld_t*)(b1p + q * 128 + 16 * fg + 4 * lhi);
                #pragma unroll
                for (int tf = 0; tf < 2; tf++) {
                    float g0 = gelu_f(a1[tf][0] + b4.x);
                    float g1 = gelu_f(a1[tf][1] + b4.y);
                    float g2 = gelu_f(a1[tf][2] + b4.z);
                    float g3 = gelu_f(a1[tf][3] + b4.w);
                    union { unsigned u[2]; uint2 u2; } pk;
                    pk.u[0] = packbf(g0, g1); pk.u[1] = packbf(g2, g3);
                    int lrow = 16 * tf + l15;
                    *(uint2*)((char*)bw + lrow * 256 + SWZB(lrow, 32 * fg + 8 * lhi)) = pk.u2;
                }
            }
            __syncthreads();
        }
        // ---- phase s=2: fc2 kq 0,1 from Bst[0]
        {
            const int c = 4 * q + 2;
            WRITE_CHUNK(c + 1, wB)
            LOAD_CHUNK(c + 2, wA)
            #pragma unroll
            for (int kq = 0; kq < 2; kq++) {
                sv8_t uf[2];
                #pragma unroll
                for (int tf = 0; tf < 2; tf++) {
                    int lrow = 16 * tf + l15;
                    uf[tf] = lds_ld8(bw, lrow * 256 + SWZB(lrow, 64 * kq + 16 * lhi));
                }
                #pragma unroll
                for (int cb = 0; cb < 2; cb++) {
                    sv8_t w2f[4];
                    #pragma unroll
                    for (int cc = 0; cc < 4; cc++) {
                        int wrow = 16 * (4 * cb + cc) + l15;
                        w2f[cc] = lds_ld8(Bst[0], wrow * 128 + SWZB(wrow, kq * 64 + 16 * lhi));
                    }
                    __builtin_amdgcn_s_setprio(1);
                    #pragma unroll
                    for (int cc = 0; cc < 4; cc++) {
                        int cg = 4 * cb + cc;
                        acc2[cg][0] = __builtin_amdgcn_mfma_f32_16x16x32_bf16(w2f[cc], uf[0], acc2[cg][0], 0, 0, 0);
                        acc2[cg][1] = __builtin_amdgcn_mfma_f32_16x16x32_bf16(w2f[cc], uf[1], acc2[cg][1], 0, 0, 0);
                    }
                    __builtin_amdgcn_s_setprio(0);
                }
            }
            __syncthreads();
        }
        // ---- phase s=3: fc2 kq 2,3 from Bst[1]
        {
            const int c = 4 * q + 3;
            WRITE_CHUNK(c + 1, wA)
            LOAD_CHUNK(c + 2, wB)
            #pragma unroll
            for (int kq = 2; kq < 4; kq++) {
                sv8_t uf[2];
                #pragma unroll
                for (int tf = 0; tf < 2; tf++) {
                    int lrow = 16 * tf + l15;
                    uf[tf] = lds_ld8(bw, lrow * 256 + SWZB(lrow, 64 * kq + 16 * lhi));
                }
                #pragma unroll
                for (int cb = 0; cb < 2; cb++) {
                    sv8_t w2f[4];
                    #pragma unroll
                    for (int cc = 0; cc < 4; cc++) {
                        int wrow = 16 * (4 * cb + cc) + l15;
                        w2f[cc] = lds_ld8(Bst[1], wrow * 128 + SWZB(wrow, (kq - 2) * 64 + 16 * lhi));
                    }
                    __builtin_amdgcn_s_setprio(1);
                    #pragma unroll
                    for (int cc = 0; cc < 4; cc++) {
                        int cg = 4 * cb + cc;
                        acc2[cg][0] = __builtin_amdgcn_mfma_f32_16x16x32_bf16(w2f[cc], uf[0], acc2[cg][0], 0, 0, 0);
                        acc2[cg][1] = __builtin_amdgcn_mfma_f32_16x16x32_bf16(w2f[cc], uf[1], acc2[cg][1], 0, 0, 0);
                    }
                    __builtin_amdgcn_s_setprio(0);
                }
            }
            __syncthreads();
        }
    }
    // ---- epilogue
    if (!final_layer) {
        #pragma unroll
        for (int tf = 0; tf < 2; tf++) {
            int row = tok0 + 16 * tf + l15;
            #pragma unroll
            for (int cg = 0; cg < 8; cg++) {
                int c0 = 16 * cg + 4 * lhi;
                f4ld_t b4 = *(const f4ld_t*)(b2p + c0);
                float* xp = xbuf + (size_t)row * 128 + c0;
                f4ld_t o = *(f4ld_t*)xp;
                o.x += acc2[cg][tf][0] + b4.x;
                o.y += acc2[cg][tf][1] + b4.y;
                o.z += acc2[cg][tf][2] + b4.z;
                o.w += acc2[cg][tf][3] + b4.w;
                *(f4ld_t*)xp = o;
            }
        }
    } else {
        // final layer: write transposed out[b][c][p] = xbuf + mlp (fuses transpose_out)
        #pragma unroll
        for (int tf = 0; tf < 2; tf++) {
            int row = tok0 + 16 * tf + l15;
            int b_ = row / PSPAT, p = row - b_ * PSPAT;
            float* ob = outp + (size_t)b_ * 128 * PSPAT + p;
            #pragma unroll
            for (int cg = 0; cg < 8; cg++) {
                int c0 = 16 * cg + 4 * lhi;
                f4ld_t b4 = *(const f4ld_t*)(b2p + c0);
                const float* xp = xbuf + (size_t)row * 128 + c0;
                f4ld_t o = *(const f4ld_t*)xp;
                o.x += acc2[cg][tf][0] + b4.x;
                o.y += acc2[cg][tf][1] + b4.y;
                o.z += acc2[cg][tf][2] + b4.z;
                o.w += acc2[cg][tf][3] + b4.w;
                ob[(size_t)(c0 + 0) * PSPAT] = o.x;
                ob[(size_t)(c0 + 1) * PSPAT] = o.y;
                ob[(size_t)(c0 + 2) * PSPAT] = o.z;
                ob[(size_t)(c0 + 3) * PSPAT] = o.w;
            }
        }
    }
}

extern "C" void kernel_launch(void* const* d_in, const int* in_sizes, int n_in,
                              void* d_out, int out_size, void* d_ws, size_t ws_size,
                              hipStream_t stream) {
    const float* x_in   = (const float*)d_in[0];
    const float* ln1_g  = (const float*)d_in[1];
    const float* ln1_b  = (const float*)d_in[2];
    const float* qkv_w  = (const float*)d_in[3];
    const float* qkv_b  = (const float*)d_in[4];
    const float* rpb    = (const float*)d_in[5];
    const float* proj_w = (const float*)d_in[6];
    const float* proj_b = (const float*)d_in[7];
    const float* ln2_g  = (const float*)d_in[8];
    const float* ln2_b  = (const float*)d_in[9];
    const float* fc1_w  = (const float*)d_in[10];
    const float* fc1_b  = (const float*)d_in[11];
    const float* fc2_w  = (const float*)d_in[12];
    const float* fc2_b  = (const float*)d_in[13];
    float* out = (float*)d_out;

    char* ws = (char*)d_ws;
    float* xbuf = (float*)ws;                                        // 102,760,448 B
    unsigned short* qkbuf = (unsigned short*)(ws + 102760448);       // 102,760,448 B
    unsigned short* vTbuf = (unsigned short*)(ws + 205520896);       //  58,720,256 B
    unsigned short* wbase = (unsigned short*)(ws + 264241408);       //     786,432 B
    float* biasb = (float*)(ws + 264241408 + 786432);                //     401,408 B

    k_transpose_in<<<dim3(PSPAT / 32, 4, BB), dim3(32, 8), 0, stream>>>(x_in, xbuf);

    for (int l = 0; l < 2; l++) {
        unsigned short* wqT = wbase + (size_t)l * 196608;
        unsigned short* wpT = wqT + 49152;
        unsigned short* w1T = wpT + 16384;
        unsigned short* w2T = w1T + 65536;
        k_prep_w<<<dim3(12, 4), dim3(32, 8), 0, stream>>>(qkv_w + (size_t)l * 49152, wqT, 128, 384);
        k_prep_w<<<dim3(4, 4),  dim3(32, 8), 0, stream>>>(proj_w + (size_t)l * 16384, wpT, 128, 128);
        k_prep_w<<<dim3(16, 4), dim3(32, 8), 0, stream>>>(fc1_w + (size_t)l * 65536, w1T, 128, 512);
        k_prep_w<<<dim3(4, 16), dim3(32, 8), 0, stream>>>(fc2_w + (size_t)l * 65536, w2T, 512, 128);
    }
    k_prep_bias<<<dim3(112, 4, 2), 112, 0, stream>>>(rpb, biasb);

    for (int layer = 0; layer < 2; layer++) {
        unsigned short* wqT = wbase + (size_t)layer * 196608;
        unsigned short* wpT = wqT + 49152;
        unsigned short* w1T = wpT + 16384;
        unsigned short* w2T = w1T + 65536;
        int shifted = layer & 1;

        k_qkv<<<TOK_TOTAL / 64, 256, 0, stream>>>(xbuf, ln1_g + layer * 128, ln1_b + layer * 128,
                                                  wqT, qkv_b + layer * 384, qkbuf, vTbuf, shifted);
        k_attn_proj<<<BNW, 256, 0, stream>>>(qkbuf, vTbuf, biasb + (size_t)layer * 4 * 112 * 112,
                                             wpT, proj_b + layer * 128, xbuf, shifted);
        k_mlp<<<TOK_TOTAL / 128, 256, 0, stream>>>(xbuf, ln2_g + layer * 128, ln2_b + layer * 128,
                                                   w1T, fc1_b + layer * 512, w2T, fc2_b + layer * 128,
                                                   xbuf, out, layer == 1);
    }
}

// Round 15
// 822.300 us; speedup vs baseline: 1.2884x; 1.0854x over previous
//
#include <hip/hip_runtime.h>
#include <hip/hip_bf16.h>

typedef __attribute__((ext_vector_type(8))) short sv8_t;   // 8 bf16 (4 VGPR)
typedef __attribute__((ext_vector_type(4))) float fv4_t;   // MFMA accumulator
typedef __attribute__((ext_vector_type(4))) float f4ld_t;  // global float4 load

#define BB 8
#define TT 8
#define HH 56
#define WW2 56
#define NTOK 98
#define BNW 2048
#define PSPAT 25088
#define TOK_TOTAL 200704
#define ACT_ELEMS 25690112
#define VT_WSTRIDE 14336   // 128 * 112

#define SWZB(row, cb) ((cb) ^ ((((unsigned)(row)) & 7u) << 4))

__device__ __forceinline__ unsigned short f2bf(float f) {
    union { float f; unsigned u; } x; x.f = f;
    unsigned r = x.u + 0x7fffu + ((x.u >> 16) & 1u);
    return (unsigned short)(r >> 16);
}
// packed pair via v_cvt_pk_bf16_f32 (RNE, bit-identical to f2bf pair, 1 inst)
__device__ __forceinline__ unsigned packbf(float lo, float hi) {
    __hip_bfloat162 h = __float22bfloat162_rn(make_float2(lo, hi));
    union { __hip_bfloat162 h; unsigned u; } cv; cv.h = h; return cv.u;
}
__device__ __forceinline__ sv8_t lds_ld8(const unsigned short* p, int byteoff) {
    return *(const sv8_t*)((const char*)p + byteoff);
}
__device__ __forceinline__ void lds_st8(unsigned short* p, int byteoff, sv8_t v) {
    *(sv8_t*)((char*)p + byteoff) = v;
}
__device__ __forceinline__ void lds_st1(unsigned short* p, int byteoff, unsigned short v) {
    *(unsigned short*)((char*)p + byteoff) = v;
}
// GELU, sigmoid form: x*sigmoid(1.702x) — ~5 ops (2 on trans pipe) vs tanh form's ~10.
// |err vs tanh-form| < 0.005 for |x|<1 (U has sigma~0.23); propagated through fc2 ~2e-3.
__device__ __forceinline__ float gelu_f(float v) {
    float e = __expf(-1.702f * v);
    return v * __builtin_amdgcn_rcpf(1.f + e);
}

// ---------------- transpose in: (B,C,P) -> (B,P,C) f32 ----------------
__global__ __launch_bounds__(256) void k_transpose_in(const float* __restrict__ in,
                                                      float* __restrict__ xbuf) {
    __shared__ float tile[32][33];
    int p0 = blockIdx.x * 32, c0 = blockIdx.y * 32, b = blockIdx.z;
    int pi = threadIdx.x, ci = threadIdx.y;
    const float* src = in + ((size_t)b * 128 + c0) * PSPAT + p0;
    for (int r = 0; r < 32; r += 8)
        tile[ci + r][pi] = src[(size_t)(ci + r) * PSPAT + pi];
    __syncthreads();
    float* dst = xbuf + ((size_t)b * PSPAT + p0) * 128 + c0;
    for (int r = 0; r < 32; r += 8)
        dst[(size_t)(ci + r) * 128 + pi] = tile[pi][ci + r];
}

// ---------------- weight prep: in f32 [K][N] -> out bf16 [N][K] ----------------
__global__ __launch_bounds__(256) void k_prep_w(const float* __restrict__ in,
                                                unsigned short* __restrict__ out,
                                                int K, int N) {
    __shared__ float tile[32][33];
    int n0 = blockIdx.x * 32, k0 = blockIdx.y * 32;
    int x = threadIdx.x, y = threadIdx.y;
    for (int r = 0; r < 32; r += 8)
        tile[y + r][x] = in[(size_t)(k0 + y + r) * N + n0 + x];
    __syncthreads();
    for (int r = 0; r < 32; r += 8)
        out[(size_t)(n0 + y + r) * K + k0 + x] = f2bf(tile[x][y + r]);
}

// ---------------- bias prep: biasb[layer][head][q row][k col] ----------------
__global__ void k_prep_bias(const float* __restrict__ rpb, float* __restrict__ biasb) {
    int col = threadIdx.x;   // 0..111 (k index)
    int row = blockIdx.x;    // 0..111 (q index)
    int head = blockIdx.y;   // 0..3
    int layer = blockIdx.z;
    int tn = min(row, 97), tm = min(col, 97);
    int itn = tn / 49, rn = tn - itn * 49, ihn = rn / 7, iwn = rn - ihn * 7;
    int itm = tm / 49, rm = tm - itm * 49, ihm = rm / 7, iwm = rm - ihm * 7;
    int dt = itn - itm + 1, dh = ihn - ihm + 6, dw = iwn - iwm + 6;
    float v = rpb[((size_t)layer * 507 + dt * 169 + dh * 13 + dw) * 4 + head];
    biasb[(((size_t)layer * 4 + head) * 112 + row) * 112 + col] = v;
}

// ---------------- fused LN1 + gather + qkv GEMM ----------------
// ALL waves use swapped-operand MFMA (C: lane=token, reg=4 consecutive cols)
// -> packed 8B stores. Waves 0/1: Q,K -> qkbuf[tok][256]; waves 2/3: V -> vT.
__global__ __launch_bounds__(256) void k_qkv(const float* __restrict__ xbuf,
                                             const float* __restrict__ g,
                                             const float* __restrict__ be,
                                             const unsigned short* __restrict__ wT,  // [384][128]
                                             const float* __restrict__ bias,         // [384]
                                             unsigned short* __restrict__ qkbuf,
                                             unsigned short* __restrict__ vT,
                                             int shifted) {
    __shared__ unsigned short xt[64 * 128];
    int tid = threadIdx.x;
    int row0 = blockIdx.x * 64;
    {
        int r = tid >> 2, q = tid & 3;
        int wt = row0 + r;
        int win = wt / 98, n = wt - win * 98;
        int b_ = win >> 8, wrem = win & 255;
        int tw = wrem >> 6, hw = (wrem >> 3) & 7, ww = wrem & 7;
        int it = n / 49, r2 = n - it * 49, ih = r2 / 7, iw = r2 - ih * 7;
        int t = tw * 2 + it, h = hw * 7 + ih, w = ww * 7 + iw;
        if (shifted) {
            t += 1; if (t >= TT) t -= TT;
            h += 3; if (h >= HH) h -= HH;
            w += 3; if (w >= WW2) w -= WW2;
        }
        const float* src = xbuf + ((size_t)b_ * PSPAT + t * (HH * WW2) + h * WW2 + w) * 128 + q * 32;
        float v[32];
        float s = 0.f, sq = 0.f;
        for (int i = 0; i < 8; i++) {
            f4ld_t f = *(const f4ld_t*)(src + i * 4);
            v[i * 4 + 0] = f.x; v[i * 4 + 1] = f.y; v[i * 4 + 2] = f.z; v[i * 4 + 3] = f.w;
            s += f.x + f.y + f.z + f.w;
            sq += f.x * f.x + f.y * f.y + f.z * f.z + f.w * f.w;
        }
        s += __shfl_xor(s, 1); sq += __shfl_xor(sq, 1);
        s += __shfl_xor(s, 2); sq += __shfl_xor(sq, 2);
        float mu = s * (1.f / 128.f);
        float var = sq * (1.f / 128.f) - mu * mu;
        float rs = rsqrtf(var + 1e-5f);
        for (int c0 = 0; c0 < 32; c0 += 8) {
            float y[8];
            #pragma unroll
            for (int i = 0; i < 8; i++) {
                int c = q * 32 + c0 + i;
                y[i] = (v[c0 + i] - mu) * rs * g[c] + be[c];
            }
            union { unsigned u[4]; sv8_t s8; } pk;
            pk.u[0] = packbf(y[0], y[1]); pk.u[1] = packbf(y[2], y[3]);
            pk.u[2] = packbf(y[4], y[5]); pk.u[3] = packbf(y[6], y[7]);
            lds_st8(xt, r * 256 + SWZB(r, (q * 32 + c0) * 2), pk.s8);
        }
    }
    __syncthreads();
    int wv = tid >> 6, lane = tid & 63, l15 = lane & 15, lhi = lane >> 4;

    if (wv < 2) {
        // Q (wv0) or K (wv1), swapped: C[d][tok]; 8 d16-frags, packed 8B stores
        int nb = wv * 128;
        fv4_t acc[4][8];
        for (int m = 0; m < 4; m++) for (int f = 0; f < 8; f++) acc[m][f] = (fv4_t){0.f, 0.f, 0.f, 0.f};
        for (int kk = 0; kk < 4; kk++) {
            sv8_t x4[4];
            #pragma unroll
            for (int m = 0; m < 4; m++) {
                int ar = 16 * m + l15;
                x4[m] = lds_ld8(xt, ar * 256 + SWZB(ar, (kk * 32 + 8 * lhi) * 2));
            }
            #pragma unroll
            for (int f = 0; f < 8; f++) {
                sv8_t wf = *(const sv8_t*)(wT + (size_t)(nb + 16 * f + l15) * 128 + kk * 32 + 8 * lhi);
                #pragma unroll
                for (int m = 0; m < 4; m++)
                    acc[m][f] = __builtin_amdgcn_mfma_f32_16x16x32_bf16(wf, x4[m], acc[m][f], 0, 0, 0);
            }
        }
        float sc_ = (wv == 0) ? 0.17677669529663687f : 1.f;
        #pragma unroll
        for (int f = 0; f < 8; f++) {
            f4ld_t b4 = *(const f4ld_t*)(bias + nb + 16 * f + 4 * lhi);
            #pragma unroll
            for (int m = 0; m < 4; m++) {
                int row = row0 + 16 * m + l15;
                union { unsigned u[2]; uint2 u2; } pk;
                pk.u[0] = packbf((acc[m][f][0] + b4.x) * sc_, (acc[m][f][1] + b4.y) * sc_);
                pk.u[1] = packbf((acc[m][f][2] + b4.z) * sc_, (acc[m][f][3] + b4.w) * sc_);
                *(uint2*)(qkbuf + (size_t)row * 256 + nb + 16 * f + 4 * lhi) = pk.u2;
            }
        }
    } else {
        int d16base = (wv - 2) * 4;
        fv4_t acc[4][4];   // [m][f]
        for (int m = 0; m < 4; m++) for (int f = 0; f < 4; f++) acc[m][f] = (fv4_t){0.f, 0.f, 0.f, 0.f};
        for (int kk = 0; kk < 4; kk++) {
            sv8_t x4[4];
            #pragma unroll
            for (int m = 0; m < 4; m++) {
                int ar = 16 * m + l15;
                x4[m] = lds_ld8(xt, ar * 256 + SWZB(ar, (kk * 32 + 8 * lhi) * 2));
            }
            #pragma unroll
            for (int f = 0; f < 4; f++) {
                sv8_t wf = *(const sv8_t*)(wT + (size_t)(256 + (d16base + f) * 16 + l15) * 128 + kk * 32 + 8 * lhi);
                #pragma unroll
                for (int m = 0; m < 4; m++)
                    acc[m][f] = __builtin_amdgcn_mfma_f32_16x16x32_bf16(wf, x4[m], acc[m][f], 0, 0, 0);
            }
        }
        #pragma unroll
        for (int f = 0; f < 4; f++) {
            f4ld_t b4 = *(const f4ld_t*)(bias + 256 + (d16base + f) * 16 + 4 * lhi);
            #pragma unroll
            for (int r = 0; r < 4; r++) {
                int d = (d16base + f) * 16 + 4 * lhi + r;
                #pragma unroll
                for (int m = 0; m < 4; m++) {
                    int row = row0 + 16 * m + l15;
                    int win = row / 98, tok = row - win * 98;
                    vT[(size_t)win * VT_WSTRIDE + d * 112 + tok] = f2bf(acc[m][f][r] + b4[r]);
                }
            }
        }
    }
}

// ---------------- attention core + proj, one block per window ----------------
// Swapped QK^T, in-lane softmax, rolled ms loop + 1-deep qa pipeline.
__global__ __launch_bounds__(256) void k_attn_proj(const unsigned short* __restrict__ qk,
                                                   const unsigned short* __restrict__ vT,
                                                   const float* __restrict__ biasb,  // [4][q 112][k 112]
                                                   const unsigned short* __restrict__ pwT, // [128][128]
                                                   const float* __restrict__ pb,
                                                   float* __restrict__ xbuf,
                                                   int shifted) {
    __shared__ unsigned short pt[4 * 16 * 128];
    __shared__ unsigned short ot[112 * 128];
    __shared__ int lablut[112];
    int win = blockIdx.x;
    int tid = threadIdx.x;
    int wv = tid >> 6, lane = tid & 63;
    int head = wv;
    int l15 = lane & 15, lhi = lane >> 4;
    int wrem = win & 255;
    int tw = wrem >> 6, hw = (wrem >> 3) & 7, ww = wrem & 7;

    for (int m = tid; m < 112; m += 256) {
        int t0 = min(m, 97);
        int it = t0 / 49, r2 = t0 - it * 49, ih = r2 / 7, iw = r2 - ih * 7;
        int lab = 0;
        if (shifted) {
            int t = tw * 2 + it, h = hw * 7 + ih, w = ww * 7 + iw;
            int ct = (t < TT - 2) ? 0 : ((t < TT - 1) ? 1 : 2);
            int ch = (h < HH - 7) ? 0 : ((h < HH - 3) ? 1 : 2);
            int cw = (w < WW2 - 7) ? 0 : ((w < WW2 - 3) ? 1 : 2);
            lab = ct * 9 + ch * 3 + cw;
        }
        lablut[m] = lab;
    }
    {
        unsigned short* myp = pt + wv * 16 * 128;
        for (int idx = lane; idx < 256; idx += 64) {
            int r = idx >> 4, c = 112 + (idx & 15);
            lds_st1(myp, r * 256 + SWZB(r, c * 2), 0);
        }
    }
    __syncthreads();

    size_t rowbase = (size_t)win * 98;
    sv8_t kf[7];
    #pragma unroll
    for (int j = 0; j < 7; j++) {
        int tok = min(16 * j + l15, 97);
        kf[j] = *(const sv8_t*)(qk + (rowbase + tok) * 256 + 128 + head * 32 + 8 * lhi);
    }
    const unsigned short* vbase = vT + (size_t)win * VT_WSTRIDE + (head * 32) * 112;
    sv8_t vf[4][2];
    #pragma unroll
    for (int kk = 0; kk < 4; kk++)
        #pragma unroll
        for (int j = 0; j < 2; j++)
            vf[kk][j] = *(const sv8_t*)(vbase + (16 * j + l15) * 112 + kk * 32 + 8 * lhi);

    int klab[7];
    if (shifted) {
        #pragma unroll
        for (int j = 0; j < 7; j++) {
            int kb = 16 * j + 4 * lhi;
            klab[j] = lablut[kb] | (lablut[kb + 1] << 8) | (lablut[kb + 2] << 16) | (lablut[kb + 3] << 24);
        }
    }

    unsigned short* myp = pt + wv * 16 * 128;

    sv8_t qa_c = *(const sv8_t*)(qk + (rowbase + l15) * 256 + head * 32 + 8 * lhi);

    for (int ms = 0; ms < 7; ms++) {
        sv8_t qa_n = qa_c;
        if (ms < 6) {
            int qtok = min(16 * (ms + 1) + l15, 97);
            qa_n = *(const sv8_t*)(qk + (rowbase + qtok) * 256 + head * 32 + 8 * lhi);
        }
        int ql = min(16 * ms + l15, 97);
        int labq = shifted ? lablut[ql] : 0;
        const float* bq = biasb + ((size_t)head * 112 + ql) * 112;
        f4ld_t bv[7];
        #pragma unroll
        for (int j = 0; j < 7; j++)
            bv[j] = *(const f4ld_t*)(bq + 16 * j + 4 * lhi);
        fv4_t sc[7];
        __builtin_amdgcn_s_setprio(1);
        #pragma unroll
        for (int j = 0; j < 7; j++) {
            fv4_t z = {0.f, 0.f, 0.f, 0.f};
            sc[j] = __builtin_amdgcn_mfma_f32_16x16x32_bf16(kf[j], qa_c, z, 0, 0, 0);
        }
        __builtin_amdgcn_s_setprio(0);
        float mx = -1e30f;
        #pragma unroll
        for (int j = 0; j < 7; j++) {
            #pragma unroll
            for (int r = 0; r < 4; r++) {
                float s = sc[j][r] + bv[j][r];
                if (shifted && (((klab[j] >> (8 * r)) & 255) != labq)) s -= 100.f;
                if (16 * j + 4 * lhi + r >= 98) s = -1e30f;
                sc[j][r] = s;
                mx = fmaxf(mx, s);
            }
        }
        mx = fmaxf(mx, __shfl_xor(mx, 16));
        mx = fmaxf(mx, __shfl_xor(mx, 32));
        float sm = 0.f;
        #pragma unroll
        for (int j = 0; j < 7; j++)
            #pragma unroll
            for (int r = 0; r < 4; r++) {
                float p = __expf(sc[j][r] - mx);
                sc[j][r] = p;
                sm += p;
            }
        sm += __shfl_xor(sm, 16);
        sm += __shfl_xor(sm, 32);
        float inv = __builtin_amdgcn_rcpf(sm);
        #pragma unroll
        for (int j = 0; j < 7; j++) {
            union { unsigned u[2]; uint2 u2; } pk;
            pk.u[0] = packbf(sc[j][0] * inv, sc[j][1] * inv);
            pk.u[1] = packbf(sc[j][2] * inv, sc[j][3] * inv);
            *(uint2*)((char*)myp + l15 * 256 + SWZB(l15, (16 * j + 4 * lhi) * 2)) = pk.u2;
        }
        fv4_t oacc[2] = {{0.f, 0.f, 0.f, 0.f}, {0.f, 0.f, 0.f, 0.f}};
        __builtin_amdgcn_s_setprio(1);
        for (int kk = 0; kk < 4; kk++) {
            sv8_t pa = lds_ld8(myp, l15 * 256 + SWZB(l15, (kk * 32 + 8 * lhi) * 2));
            #pragma unroll
            for (int j = 0; j < 2; j++)
                oacc[j] = __builtin_amdgcn_mfma_f32_16x16x32_bf16(pa, vf[kk][j], oacc[j], 0, 0, 0);
        }
        __builtin_amdgcn_s_setprio(0);
        #pragma unroll
        for (int r = 0; r < 4; r++) {
            int orow = 16 * ms + 4 * lhi + r;
            #pragma unroll
            for (int j = 0; j < 2; j++) {
                int ocol = head * 32 + 16 * j + l15;
                float v = (orow < 98) ? oacc[j][r] : 0.f;
                lds_st1(ot, orow * 256 + SWZB(orow, ocol * 2), f2bf(v));
            }
        }
        qa_c = qa_n;
    }
    __syncthreads();

    {
        int nb = wv * 32;
        fv4_t acc[7][2];
        for (int m = 0; m < 7; m++) for (int j = 0; j < 2; j++) acc[m][j] = (fv4_t){0.f, 0.f, 0.f, 0.f};
        for (int kk = 0; kk < 4; kk++) {
            sv8_t b[2];
            #pragma unroll
            for (int j = 0; j < 2; j++)
                b[j] = *(const sv8_t*)(pwT + (size_t)(nb + 16 * j + l15) * 128 + kk * 32 + 8 * lhi);
            __builtin_amdgcn_s_setprio(1);
            #pragma unroll
            for (int m = 0; m < 7; m++) {
                int ar = 16 * m + l15;
                sv8_t a = lds_ld8(ot, ar * 256 + SWZB(ar, (kk * 32 + 8 * lhi) * 2));
                #pragma unroll
                for (int j = 0; j < 2; j++)
                    acc[m][j] = __builtin_amdgcn_mfma_f32_16x16x32_bf16(a, b[j], acc[m][j], 0, 0, 0);
            }
            __builtin_amdgcn_s_setprio(0);
        }
        int b_ = win >> 8;
        for (int m = 0; m < 7; m++)
            #pragma unroll
            for (int r = 0; r < 4; r++) {
                int row = 16 * m + lhi * 4 + r;
                if (row < 98) {
                    int it = row / 49, r2 = row - it * 49, ih = r2 / 7, iw = r2 - ih * 7;
                    int t = tw * 2 + it, h = hw * 7 + ih, w = ww * 7 + iw;
                    if (shifted) {
                        t += 1; if (t >= TT) t -= TT;
                        h += 3; if (h >= HH) h -= HH;
                        w += 3; if (w >= WW2) w -= WW2;
                    }
                    float* xp = xbuf + ((size_t)b_ * PSPAT + t * (HH * WW2) + h * WW2 + w) * 128 + nb;
                    #pragma unroll
                    for (int j = 0; j < 2; j++) {
                        int c = 16 * j + l15;
                        xp[c] += acc[m][j][r] + pb[nb + c];
                    }
                }
            }
    }
}

// ---------------- fused LN2 + fc1 + GELU + fc2 + residual (+final transpose) ----
// [round-11 best: reg-staged ping-pong, loads 2 phases ahead]
#define LOAD_CHUNK(c, R)                                                                   \
    if ((c) < 16) {                                                                        \
        if (((c) & 2) == 0) {                                                              \
            _Pragma("unroll")                                                              \
            for (int i_ = 0; i_ < 4; i_++)                                                 \
                R[i_] = *(const sv8_t*)(w1T + (size_t)(((c) >> 2) * 128 + ((c)&1) * 64 + i_ * 16 + r1) * 128 + (c1 >> 1)); \
        } else {                                                                           \
            _Pragma("unroll")                                                              \
            for (int i_ = 0; i_ < 4; i_++)                                                 \
                R[i_] = *(const sv8_t*)(w2T + (size_t)(i_ * 32 + r2) * 512 + ((c) >> 2) * 128 + ((c)&1) * 64 + (c2 >> 1)); \
        }                                                                                  \
    }
#define WRITE_CHUNK(c, R)                                                                  \
    if ((c) < 16) {                                                                        \
        unsigned short* bst_ = Bst[(c)&1];                                                 \
        if (((c) & 2) == 0) {                                                              \
            _Pragma("unroll")                                                              \
            for (int i_ = 0; i_ < 4; i_++)                                                 \
                lds_st8(bst_, (i_ * 16 + r1) * 256 + SWZB(i_ * 16 + r1, c1), R[i_]);       \
        } else {                                                                           \
            _Pragma("unroll")                                                              \
            for (int i_ = 0; i_ < 4; i_++)                                                 \
                lds_st8(bst_, (i_ * 32 + r2) * 128 + SWZB(i_ * 32 + r2, c2), R[i_]);       \
        }                                                                                  \
    }

__global__ __launch_bounds__(256, 2) void k_mlp(const float* __restrict__ xin,
                                                const float* __restrict__ g,
                                                const float* __restrict__ be,
                                                const unsigned short* __restrict__ w1T,  // [512][128]
                                                const float* __restrict__ b1p,
                                                const unsigned short* __restrict__ w2T,  // [128][512]
                                                const float* __restrict__ b2p,
                                                float* __restrict__ xbuf,
                                                float* __restrict__ outp,
                                                int final_layer) {
    __shared__ unsigned short A[4][32 * 128];   // 32 KB: per-wave xt then U slice
    __shared__ unsigned short Bst[2][8192];     // 2 x 16 KB ping-pong chunks
    int tid = threadIdx.x;
    int wv = tid >> 6, lane = tid & 63, l15 = lane & 15, lhi = lane >> 4;
    unsigned short* bw = A[wv];
    int tok0 = blockIdx.x * 128 + wv * 32;

    int r1 = tid >> 4, c1 = (tid & 15) * 16;   // w1 chunk coords (64x128)
    int r2 = tid >> 3, c2 = (tid & 7) * 16;    // w2 chunk coords (128x64)

    sv8_t wA[4], wB[4];
    LOAD_CHUNK(0, wA)                          // hidden under LN

    // ---- LN (wave-private xt in A[wv])
    #pragma unroll
    for (int tf = 0; tf < 2; tf++) {
        int lrow = 16 * tf + l15;
        const float* src = xin + (size_t)(tok0 + lrow) * 128 + lhi * 32;
        float v[32];
        float s = 0.f, sq = 0.f;
        #pragma unroll
        for (int i = 0; i < 8; i++) {
            f4ld_t f = *(const f4ld_t*)(src + i * 4);
            v[i * 4 + 0] = f.x; v[i * 4 + 1] = f.y; v[i * 4 + 2] = f.z; v[i * 4 + 3] = f.w;
            s += f.x + f.y + f.z + f.w;
            sq += f.x * f.x + f.y * f.y + f.z * f.z + f.w * f.w;
        }
        s += __shfl_xor(s, 16); sq += __shfl_xor(sq, 16);
        s += __shfl_xor(s, 32); sq += __shfl_xor(sq, 32);
        float mu = s * (1.f / 128.f);
        float var = sq * (1.f / 128.f) - mu * mu;
        float rs = rsqrtf(var + 1e-5f);
        #pragma unroll
        for (int j = 0; j < 4; j++) {
            int c0 = lhi * 32 + 8 * j;
            f4ld_t g0 = *(const f4ld_t*)(g + c0);
            f4ld_t g1 = *(const f4ld_t*)(g + c0 + 4);
            f4ld_t b0 = *(const f4ld_t*)(be + c0);
            f4ld_t b1 = *(const f4ld_t*)(be + c0 + 4);
            float y0 = (v[8 * j + 0] - mu) * rs * g0.x + b0.x;
            float y1 = (v[8 * j + 1] - mu) * rs * g0.y + b0.y;
            float y2 = (v[8 * j + 2] - mu) * rs * g0.z + b0.z;
            float y3 = (v[8 * j + 3] - mu) * rs * g0.w + b0.w;
            float y4 = (v[8 * j + 4] - mu) * rs * g1.x + b1.x;
            float y5 = (v[8 * j + 5] - mu) * rs * g1.y + b1.y;
            float y6 = (v[8 * j + 6] - mu) * rs * g1.z + b1.z;
            float y7 = (v[8 * j + 7] - mu) * rs * g1.w + b1.w;
            union { unsigned u[4]; sv8_t s8; } pk;
            pk.u[0] = packbf(y0, y1); pk.u[1] = packbf(y2, y3);
            pk.u[2] = packbf(y4, y5); pk.u[3] = packbf(y6, y7);
            lds_st8(bw, lrow * 256 + SWZB(lrow, 64 * lhi + 16 * j), pk.s8);
        }
    }
    sv8_t xf[2][4];
    #pragma unroll
    for (int tf = 0; tf < 2; tf++)
        #pragma unroll
        for (int kk = 0; kk < 4; kk++) {
            int lrow = 16 * tf + l15;
            xf[tf][kk] = lds_ld8(bw, lrow * 256 + SWZB(lrow, 64 * kk + 16 * lhi));
        }

    fv4_t acc2[8][2];
    #pragma unroll
    for (int cg = 0; cg < 8; cg++)
        #pragma unroll
        for (int tf = 0; tf < 2; tf++) acc2[cg][tf] = (fv4_t){0.f, 0.f, 0.f, 0.f};

    // prologue: stage chunk0, issue chunk1
    WRITE_CHUNK(0, wA)
    LOAD_CHUNK(1, wB)
    __syncthreads();

    #pragma unroll
    for (int q = 0; q < 4; q++) {
        // ---- phase s=0: fc1 fg 0..3 from Bst[0]
        {
            const int c = 4 * q;
            WRITE_CHUNK(c + 1, wB)
            LOAD_CHUNK(c + 2, wA)
            #pragma unroll
            for (int f = 0; f < 4; f++) {
                int fg = f;
                sv8_t wf[4];
                #pragma unroll
                for (int kk = 0; kk < 4; kk++) {
                    int wrow = 16 * f + l15;
                    wf[kk] = lds_ld8(Bst[0], wrow * 256 + SWZB(wrow, kk * 64 + 16 * lhi));
                }
                fv4_t a1[2] = {{0.f, 0.f, 0.f, 0.f}, {0.f, 0.f, 0.f, 0.f}};
                __builtin_amdgcn_s_setprio(1);
                #pragma unroll
                for (int kk = 0; kk < 4; kk++) {
                    a1[0] = __builtin_amdgcn_mfma_f32_16x16x32_bf16(wf[kk], xf[0][kk], a1[0], 0, 0, 0);
                    a1[1] = __builtin_amdgcn_mfma_f32_16x16x32_bf16(wf[kk], xf[1][kk], a1[1], 0, 0, 0);
                }
                __builtin_amdgcn_s_setprio(0);
                f4ld_t b4 = *(const f4ld_t*)(b1p + q * 128 + 16 * fg + 4 * lhi);
                #pragma unroll
                for (int tf = 0; tf < 2; tf++) {
                    float g0 = gelu_f(a1[tf][0] + b4.x);
                    float g1 = gelu_f(a1[tf][1] + b4.y);
                    float g2 = gelu_f(a1[tf][2] + b4.z);
                    float g3 = gelu_f(a1[tf][3] + b4.w);
                    union { unsigned u[2]; uint2 u2; } pk;
                    pk.u[0] = packbf(g0, g1); pk.u[1] = packbf(g2, g3);
                    int lrow = 16 * tf + l15;
                    *(uint2*)((char*)bw + lrow * 256 + SWZB(lrow, 32 * fg + 8 * lhi)) = pk.u2;
                }
            }
            __syncthreads();
        }
        // ---- phase s=1: fc1 fg 4..7 from Bst[1]
        {
            const int c = 4 * q + 1;
            WRITE_CHUNK(c + 1, wA)
            LOAD_CHUNK(c + 2, wB)
            #pragma unroll
            for (int f = 0; f < 4; f++) {
                int fg = 4 + f;
                sv8_t wf[4];
                #pragma unroll
                for (int kk = 0; kk < 4; kk++) {
                    int wrow = 16 * f + l15;
                    wf[kk] = lds_ld8(Bst[1], wrow * 256 + SWZB(wrow, kk * 64 + 16 * lhi));
                }
                fv4_t a1[2] = {{0.f, 0.f, 0.f, 0.f}, {0.f, 0.f, 0.f, 0.f}};
                __builtin_amdgcn_s_setprio(1);
                #pragma unroll
                for (int kk = 0; kk < 4; kk++) {
                    a1[0] = __builtin_amdgcn_mfma_f32_16x16x32_bf16(wf[kk], xf[0][kk], a1[0], 0, 0, 0);
                    a1[1] = __builtin_amdgcn_mfma_f32_16x16x32_bf16(wf[kk], xf[1][kk], a1[1], 0, 0, 0);
                }
                __builtin_amdgcn_s_setprio(0);
                f4ld_t b4 = *(const f4ld_t*)(b1p + q * 128 + 16 * fg + 4 * lhi);
                #pragma unroll
                for (int tf = 0; tf < 2; tf++) {
                    float g0 = gelu_f(a1[tf][0] + b4.x);
                    float g1 = gelu_f(a1[tf][1] + b4.y);
                    float g2 = gelu_f(a1[tf][2] + b4.z);
                    float g3 = gelu_f(a1[tf][3] + b4.w);
                    union { unsigned u[2]; uint2 u2; } pk;
                    pk.u[0] = packbf(g0, g1); pk.u[1] = packbf(g2, g3);
                    int lrow = 16 * tf + l15;
                    *(uint2*)((char*)bw + lrow * 256 + SWZB(lrow, 32 * fg + 8 * lhi)) = pk.u2;
                }
            }
            __syncthreads();
        }
        // ---- phase s=2: fc2 kq 0,1 from Bst[0]
        {
            const int c = 4 * q + 2;
            WRITE_CHUNK(c + 1, wB)
            LOAD_CHUNK(c + 2, wA)
            #pragma unroll
            for (int kq = 0; kq < 2; kq++) {
                sv8_t uf[2];
                #pragma unroll
                for (int tf = 0; tf < 2; tf++) {
                    int lrow = 16 * tf + l15;
                    uf[tf] = lds_ld8(bw, lrow * 256 + SWZB(lrow, 64 * kq + 16 * lhi));
                }
                #pragma unroll
                for (int cb = 0; cb < 2; cb++) {
                    sv8_t w2f[4];
                    #pragma unroll
                    for (int cc = 0; cc < 4; cc++) {
                        int wrow = 16 * (4 * cb + cc) + l15;
                        w2f[cc] = lds_ld8(Bst[0], wrow * 128 + SWZB(wrow, kq * 64 + 16 * lhi));
                    }
                    __builtin_amdgcn_s_setprio(1);
                    #pragma unroll
                    for (int cc = 0; cc < 4; cc++) {
                        int cg = 4 * cb + cc;
                        acc2[cg][0] = __builtin_amdgcn_mfma_f32_16x16x32_bf16(w2f[cc], uf[0], acc2[cg][0], 0, 0, 0);
                        acc2[cg][1] = __builtin_amdgcn_mfma_f32_16x16x32_bf16(w2f[cc], uf[1], acc2[cg][1], 0, 0, 0);
                    }
                    __builtin_amdgcn_s_setprio(0);
                }
            }
            __syncthreads();
        }
        // ---- phase s=3: fc2 kq 2,3 from Bst[1]
        {
            const int c = 4 * q + 3;
            WRITE_CHUNK(c + 1, wA)
            LOAD_CHUNK(c + 2, wB)
            #pragma unroll
            for (int kq = 2; kq < 4; kq++) {
                sv8_t uf[2];
                #pragma unroll
                for (int tf = 0; tf < 2; tf++) {
                    int lrow = 16 * tf + l15;
                    uf[tf] = lds_ld8(bw, lrow * 256 + SWZB(lrow, 64 * kq + 16 * lhi));
                }
                #pragma unroll
                for (int cb = 0; cb < 2; cb++) {
                    sv8_t w2f[4];
                    #pragma unroll
                    for (int cc = 0; cc < 4; cc++) {
                        int wrow = 16 * (4 * cb + cc) + l15;
                        w2f[cc] = lds_ld8(Bst[1], wrow * 128 + SWZB(wrow, (kq - 2) * 64 + 16 * lhi));
                    }
                    __builtin_amdgcn_s_setprio(1);
                    #pragma unroll
                    for (int cc = 0; cc < 4; cc++) {
                        int cg = 4 * cb + cc;
                        acc2[cg][0] = __builtin_amdgcn_mfma_f32_16x16x32_bf16(w2f[cc], uf[0], acc2[cg][0], 0, 0, 0);
                        acc2[cg][1] = __builtin_amdgcn_mfma_f32_16x16x32_bf16(w2f[cc], uf[1], acc2[cg][1], 0, 0, 0);
                    }
                    __builtin_amdgcn_s_setprio(0);
                }
            }
            __syncthreads();
        }
    }
    // ---- epilogue
    if (!final_layer) {
        #pragma unroll
        for (int tf = 0; tf < 2; tf++) {
            int row = tok0 + 16 * tf + l15;
            #pragma unroll
            for (int cg = 0; cg < 8; cg++) {
                int c0 = 16 * cg + 4 * lhi;
                f4ld_t b4 = *(const f4ld_t*)(b2p + c0);
                float* xp = xbuf + (size_t)row * 128 + c0;
                f4ld_t o = *(f4ld_t*)xp;
                o.x += acc2[cg][tf][0] + b4.x;
                o.y += acc2[cg][tf][1] + b4.y;
                o.z += acc2[cg][tf][2] + b4.z;
                o.w += acc2[cg][tf][3] + b4.w;
                *(f4ld_t*)xp = o;
            }
        }
    } else {
        // final layer: write transposed out[b][c][p] = xbuf + mlp (fuses transpose_out)
        #pragma unroll
        for (int tf = 0; tf < 2; tf++) {
            int row = tok0 + 16 * tf + l15;
            int b_ = row / PSPAT, p = row - b_ * PSPAT;
            float* ob = outp + (size_t)b_ * 128 * PSPAT + p;
            #pragma unroll
            for (int cg = 0; cg < 8; cg++) {
                int c0 = 16 * cg + 4 * lhi;
                f4ld_t b4 = *(const f4ld_t*)(b2p + c0);
                const float* xp = xbuf + (size_t)row * 128 + c0;
                f4ld_t o = *(const f4ld_t*)xp;
                o.x += acc2[cg][tf][0] + b4.x;
                o.y += acc2[cg][tf][1] + b4.y;
                o.z += acc2[cg][tf][2] + b4.z;
                o.w += acc2[cg][tf][3] + b4.w;
                ob[(size_t)(c0 + 0) * PSPAT] = o.x;
                ob[(size_t)(c0 + 1) * PSPAT] = o.y;
                ob[(size_t)(c0 + 2) * PSPAT] = o.z;
                ob[(size_t)(c0 + 3) * PSPAT] = o.w;
            }
        }
    }
}

extern "C" void kernel_launch(void* const* d_in, const int* in_sizes, int n_in,
                              void* d_out, int out_size, void* d_ws, size_t ws_size,
                              hipStream_t stream) {
    const float* x_in   = (const float*)d_in[0];
    const float* ln1_g  = (const float*)d_in[1];
    const float* ln1_b  = (const float*)d_in[2];
    const float* qkv_w  = (const float*)d_in[3];
    const float* qkv_b  = (const float*)d_in[4];
    const float* rpb    = (const float*)d_in[5];
    const float* proj_w = (const float*)d_in[6];
    const float* proj_b = (const float*)d_in[7];
    const float* ln2_g  = (const float*)d_in[8];
    const float* ln2_b  = (const float*)d_in[9];
    const float* fc1_w  = (const float*)d_in[10];
    const float* fc1_b  = (const float*)d_in[11];
    const float* fc2_w  = (const float*)d_in[12];
    const float* fc2_b  = (const float*)d_in[13];
    float* out = (float*)d_out;

    char* ws = (char*)d_ws;
    float* xbuf = (float*)ws;                                        // 102,760,448 B
    unsigned short* qkbuf = (unsigned short*)(ws + 102760448);       // 102,760,448 B
    unsigned short* vTbuf = (unsigned short*)(ws + 205520896);       //  58,720,256 B
    unsigned short* wbase = (unsigned short*)(ws + 264241408);       //     786,432 B
    float* biasb = (float*)(ws + 264241408 + 786432);                //     401,408 B

    k_transpose_in<<<dim3(PSPAT / 32, 4, BB), dim3(32, 8), 0, stream>>>(x_in, xbuf);

    for (int l = 0; l < 2; l++) {
        unsigned short* wqT = wbase + (size_t)l * 196608;
        unsigned short* wpT = wqT + 49152;
        unsigned short* w1T = wpT + 16384;
        unsigned short* w2T = w1T + 65536;
        k_prep_w<<<dim3(12, 4), dim3(32, 8), 0, stream>>>(qkv_w + (size_t)l * 49152, wqT, 128, 384);
        k_prep_w<<<dim3(4, 4),  dim3(32, 8), 0, stream>>>(proj_w + (size_t)l * 16384, wpT, 128, 128);
        k_prep_w<<<dim3(16, 4), dim3(32, 8), 0, stream>>>(fc1_w + (size_t)l * 65536, w1T, 128, 512);
        k_prep_w<<<dim3(4, 16), dim3(32, 8), 0, stream>>>(fc2_w + (size_t)l * 65536, w2T, 512, 128);
    }
    k_prep_bias<<<dim3(112, 4, 2), 112, 0, stream>>>(rpb, biasb);

    for (int layer = 0; layer < 2; layer++) {
        unsigned short* wqT = wbase + (size_t)layer * 196608;
        unsigned short* wpT = wqT + 49152;
        unsigned short* w1T = wpT + 16384;
        unsigned short* w2T = w1T + 65536;
        int shifted = layer & 1;

        k_qkv<<<TOK_TOTAL / 64, 256, 0, stream>>>(xbuf, ln1_g + layer * 128, ln1_b + layer * 128,
                                                  wqT, qkv_b + layer * 384, qkbuf, vTbuf, shifted);
        k_attn_proj<<<BNW, 256, 0, stream>>>(qkbuf, vTbuf, biasb + (size_t)layer * 4 * 112 * 112,
                                             wpT, proj_b + layer * 128, xbuf, shifted);
        k_mlp<<<TOK_TOTAL / 128, 256, 0, stream>>>(xbuf, ln2_g + layer * 128, ln2_b + layer * 128,
                                                   w1T, fc1_b + layer * 512, w2T, fc2_b + layer * 128,
                                                   xbuf, out, layer == 1);
    }
}

// Round 16
// 779.047 us; speedup vs baseline: 1.3599x; 1.0555x over previous
//
#include <hip/hip_runtime.h>
#include <hip/hip_bf16.h>

typedef __attribute__((ext_vector_type(8))) short sv8_t;   // 8 bf16 (4 VGPR)
typedef __attribute__((ext_vector_type(4))) float fv4_t;   // MFMA accumulator
typedef __attribute__((ext_vector_type(4))) float f4ld_t;  // global float4 load

#define BB 8
#define TT 8
#define HH 56
#define WW2 56
#define NTOK 98
#define BNW 2048
#define PSPAT 25088
#define TOK_TOTAL 200704
#define ACT_ELEMS 25690112
#define VT_WSTRIDE 14336   // 128 * 112

#define SWZB(row, cb) ((cb) ^ ((((unsigned)(row)) & 7u) << 4))

__device__ __forceinline__ unsigned short f2bf(float f) {
    union { float f; unsigned u; } x; x.f = f;
    unsigned r = x.u + 0x7fffu + ((x.u >> 16) & 1u);
    return (unsigned short)(r >> 16);
}
// packed pair via v_cvt_pk_bf16_f32 (RNE, bit-identical to f2bf pair, 1 inst)
__device__ __forceinline__ unsigned packbf(float lo, float hi) {
    __hip_bfloat162 h = __float22bfloat162_rn(make_float2(lo, hi));
    union { __hip_bfloat162 h; unsigned u; } cv; cv.h = h; return cv.u;
}
__device__ __forceinline__ sv8_t lds_ld8(const unsigned short* p, int byteoff) {
    return *(const sv8_t*)((const char*)p + byteoff);
}
__device__ __forceinline__ void lds_st8(unsigned short* p, int byteoff, sv8_t v) {
    *(sv8_t*)((char*)p + byteoff) = v;
}
__device__ __forceinline__ void lds_st1(unsigned short* p, int byteoff, unsigned short v) {
    *(unsigned short*)((char*)p + byteoff) = v;
}
// GELU, sigmoid form: x*sigmoid(1.702x)
__device__ __forceinline__ float gelu_f(float v) {
    float e = __expf(-1.702f * v);
    return v * __builtin_amdgcn_rcpf(1.f + e);
}

// ---------------- transpose in: (B,C,P) -> (B,P,C) f32 ----------------
__global__ __launch_bounds__(256) void k_transpose_in(const float* __restrict__ in,
                                                      float* __restrict__ xbuf) {
    __shared__ float tile[32][33];
    int p0 = blockIdx.x * 32, c0 = blockIdx.y * 32, b = blockIdx.z;
    int pi = threadIdx.x, ci = threadIdx.y;
    const float* src = in + ((size_t)b * 128 + c0) * PSPAT + p0;
    for (int r = 0; r < 32; r += 8)
        tile[ci + r][pi] = src[(size_t)(ci + r) * PSPAT + pi];
    __syncthreads();
    float* dst = xbuf + ((size_t)b * PSPAT + p0) * 128 + c0;
    for (int r = 0; r < 32; r += 8)
        dst[(size_t)(ci + r) * 128 + pi] = tile[pi][ci + r];
}

// ---------------- weight prep: in f32 [K][N] -> out bf16 [N][K] ----------------
__global__ __launch_bounds__(256) void k_prep_w(const float* __restrict__ in,
                                                unsigned short* __restrict__ out,
                                                int K, int N) {
    __shared__ float tile[32][33];
    int n0 = blockIdx.x * 32, k0 = blockIdx.y * 32;
    int x = threadIdx.x, y = threadIdx.y;
    for (int r = 0; r < 32; r += 8)
        tile[y + r][x] = in[(size_t)(k0 + y + r) * N + n0 + x];
    __syncthreads();
    for (int r = 0; r < 32; r += 8)
        out[(size_t)(n0 + y + r) * K + k0 + x] = f2bf(tile[x][y + r]);
}

// ---------------- bias prep: biasb[layer][head][q row][k col] ----------------
__global__ void k_prep_bias(const float* __restrict__ rpb, float* __restrict__ biasb) {
    int col = threadIdx.x;   // 0..111 (k index)
    int row = blockIdx.x;    // 0..111 (q index)
    int head = blockIdx.y;   // 0..3
    int layer = blockIdx.z;
    int tn = min(row, 97), tm = min(col, 97);
    int itn = tn / 49, rn = tn - itn * 49, ihn = rn / 7, iwn = rn - ihn * 7;
    int itm = tm / 49, rm = tm - itm * 49, ihm = rm / 7, iwm = rm - ihm * 7;
    int dt = itn - itm + 1, dh = ihn - ihm + 6, dw = iwn - iwm + 6;
    float v = rpb[((size_t)layer * 507 + dt * 169 + dh * 13 + dw) * 4 + head];
    biasb[(((size_t)layer * 4 + head) * 112 + row) * 112 + col] = v;
}

// ---------------- fused LN1 + gather + qkv GEMM ----------------
__global__ __launch_bounds__(256) void k_qkv(const float* __restrict__ xbuf,
                                             const float* __restrict__ g,
                                             const float* __restrict__ be,
                                             const unsigned short* __restrict__ wT,  // [384][128]
                                             const float* __restrict__ bias,         // [384]
                                             unsigned short* __restrict__ qkbuf,
                                             unsigned short* __restrict__ vT,
                                             int shifted) {
    __shared__ unsigned short xt[64 * 128];
    int tid = threadIdx.x;
    int row0 = blockIdx.x * 64;
    {
        int r = tid >> 2, q = tid & 3;
        int wt = row0 + r;
        int win = wt / 98, n = wt - win * 98;
        int b_ = win >> 8, wrem = win & 255;
        int tw = wrem >> 6, hw = (wrem >> 3) & 7, ww = wrem & 7;
        int it = n / 49, r2 = n - it * 49, ih = r2 / 7, iw = r2 - ih * 7;
        int t = tw * 2 + it, h = hw * 7 + ih, w = ww * 7 + iw;
        if (shifted) {
            t += 1; if (t >= TT) t -= TT;
            h += 3; if (h >= HH) h -= HH;
            w += 3; if (w >= WW2) w -= WW2;
        }
        const float* src = xbuf + ((size_t)b_ * PSPAT + t * (HH * WW2) + h * WW2 + w) * 128 + q * 32;
        float v[32];
        float s = 0.f, sq = 0.f;
        for (int i = 0; i < 8; i++) {
            f4ld_t f = *(const f4ld_t*)(src + i * 4);
            v[i * 4 + 0] = f.x; v[i * 4 + 1] = f.y; v[i * 4 + 2] = f.z; v[i * 4 + 3] = f.w;
            s += f.x + f.y + f.z + f.w;
            sq += f.x * f.x + f.y * f.y + f.z * f.z + f.w * f.w;
        }
        s += __shfl_xor(s, 1); sq += __shfl_xor(sq, 1);
        s += __shfl_xor(s, 2); sq += __shfl_xor(sq, 2);
        float mu = s * (1.f / 128.f);
        float var = sq * (1.f / 128.f) - mu * mu;
        float rs = rsqrtf(var + 1e-5f);
        for (int c0 = 0; c0 < 32; c0 += 8) {
            float y[8];
            #pragma unroll
            for (int i = 0; i < 8; i++) {
                int c = q * 32 + c0 + i;
                y[i] = (v[c0 + i] - mu) * rs * g[c] + be[c];
            }
            union { unsigned u[4]; sv8_t s8; } pk;
            pk.u[0] = packbf(y[0], y[1]); pk.u[1] = packbf(y[2], y[3]);
            pk.u[2] = packbf(y[4], y[5]); pk.u[3] = packbf(y[6], y[7]);
            lds_st8(xt, r * 256 + SWZB(r, (q * 32 + c0) * 2), pk.s8);
        }
    }
    __syncthreads();
    int wv = tid >> 6, lane = tid & 63, l15 = lane & 15, lhi = lane >> 4;

    if (wv < 2) {
        int nb = wv * 128;
        fv4_t acc[4][8];
        for (int m = 0; m < 4; m++) for (int f = 0; f < 8; f++) acc[m][f] = (fv4_t){0.f, 0.f, 0.f, 0.f};
        for (int kk = 0; kk < 4; kk++) {
            sv8_t x4[4];
            #pragma unroll
            for (int m = 0; m < 4; m++) {
                int ar = 16 * m + l15;
                x4[m] = lds_ld8(xt, ar * 256 + SWZB(ar, (kk * 32 + 8 * lhi) * 2));
            }
            #pragma unroll
            for (int f = 0; f < 8; f++) {
                sv8_t wf = *(const sv8_t*)(wT + (size_t)(nb + 16 * f + l15) * 128 + kk * 32 + 8 * lhi);
                #pragma unroll
                for (int m = 0; m < 4; m++)
                    acc[m][f] = __builtin_amdgcn_mfma_f32_16x16x32_bf16(wf, x4[m], acc[m][f], 0, 0, 0);
            }
        }
        float sc_ = (wv == 0) ? 0.17677669529663687f : 1.f;
        #pragma unroll
        for (int f = 0; f < 8; f++) {
            f4ld_t b4 = *(const f4ld_t*)(bias + nb + 16 * f + 4 * lhi);
            #pragma unroll
            for (int m = 0; m < 4; m++) {
                int row = row0 + 16 * m + l15;
                union { unsigned u[2]; uint2 u2; } pk;
                pk.u[0] = packbf((acc[m][f][0] + b4.x) * sc_, (acc[m][f][1] + b4.y) * sc_);
                pk.u[1] = packbf((acc[m][f][2] + b4.z) * sc_, (acc[m][f][3] + b4.w) * sc_);
                *(uint2*)(qkbuf + (size_t)row * 256 + nb + 16 * f + 4 * lhi) = pk.u2;
            }
        }
    } else {
        int d16base = (wv - 2) * 4;
        fv4_t acc[4][4];   // [m][f]
        for (int m = 0; m < 4; m++) for (int f = 0; f < 4; f++) acc[m][f] = (fv4_t){0.f, 0.f, 0.f, 0.f};
        for (int kk = 0; kk < 4; kk++) {
            sv8_t x4[4];
            #pragma unroll
            for (int m = 0; m < 4; m++) {
                int ar = 16 * m + l15;
                x4[m] = lds_ld8(xt, ar * 256 + SWZB(ar, (kk * 32 + 8 * lhi) * 2));
            }
            #pragma unroll
            for (int f = 0; f < 4; f++) {
                sv8_t wf = *(const sv8_t*)(wT + (size_t)(256 + (d16base + f) * 16 + l15) * 128 + kk * 32 + 8 * lhi);
                #pragma unroll
                for (int m = 0; m < 4; m++)
                    acc[m][f] = __builtin_amdgcn_mfma_f32_16x16x32_bf16(wf, x4[m], acc[m][f], 0, 0, 0);
            }
        }
        #pragma unroll
        for (int f = 0; f < 4; f++) {
            f4ld_t b4 = *(const f4ld_t*)(bias + 256 + (d16base + f) * 16 + 4 * lhi);
            #pragma unroll
            for (int r = 0; r < 4; r++) {
                int d = (d16base + f) * 16 + 4 * lhi + r;
                #pragma unroll
                for (int m = 0; m < 4; m++) {
                    int row = row0 + 16 * m + l15;
                    int win = row / 98, tok = row - win * 98;
                    vT[(size_t)win * VT_WSTRIDE + d * 112 + tok] = f2bf(acc[m][f][r] + b4[r]);
                }
            }
        }
    }
}

// ---------------- attention core + proj, one block per window ----------------
// Swapped QK^T, in-lane softmax. P never touches LDS: per-lane P is repacked
// (cvt_pk) and redistributed to the PV A-fragment layout via __shfl + cndmask
// (lane l15,lhi needs P[q=l15][k=32kk+8lhi+i]; source lane 16h'+l15 holds the
// packed pair of j'=2kk+(lhi>>1), h'=2(lhi&1)+(i>>2)). LDS = ot only (~29KB).
__global__ __launch_bounds__(256, 3) void k_attn_proj(const unsigned short* __restrict__ qk,
                                                      const unsigned short* __restrict__ vT,
                                                      const float* __restrict__ biasb,  // [4][q 112][k 112]
                                                      const unsigned short* __restrict__ pwT, // [128][128]
                                                      const float* __restrict__ pb,
                                                      float* __restrict__ xbuf,
                                                      int shifted) {
    __shared__ unsigned short ot[112 * 128];
    __shared__ int lablut[112];
    int win = blockIdx.x;
    int tid = threadIdx.x;
    int wv = tid >> 6, lane = tid & 63;
    int head = wv;
    int l15 = lane & 15, lhi = lane >> 4;
    int wrem = win & 255;
    int tw = wrem >> 6, hw = (wrem >> 3) & 7, ww = wrem & 7;

    for (int m = tid; m < 112; m += 256) {
        int t0 = min(m, 97);
        int it = t0 / 49, r2 = t0 - it * 49, ih = r2 / 7, iw = r2 - ih * 7;
        int lab = 0;
        if (shifted) {
            int t = tw * 2 + it, h = hw * 7 + ih, w = ww * 7 + iw;
            int ct = (t < TT - 2) ? 0 : ((t < TT - 1) ? 1 : 2);
            int ch = (h < HH - 7) ? 0 : ((h < HH - 3) ? 1 : 2);
            int cw = (w < WW2 - 7) ? 0 : ((w < WW2 - 3) ? 1 : 2);
            lab = ct * 9 + ch * 3 + cw;
        }
        lablut[m] = lab;
    }
    __syncthreads();

    size_t rowbase = (size_t)win * 98;
    sv8_t kf[7];
    #pragma unroll
    for (int j = 0; j < 7; j++) {
        int tok = min(16 * j + l15, 97);
        kf[j] = *(const sv8_t*)(qk + (rowbase + tok) * 256 + 128 + head * 32 + 8 * lhi);
    }
    const unsigned short* vbase = vT + (size_t)win * VT_WSTRIDE + (head * 32) * 112;
    sv8_t vf[4][2];
    #pragma unroll
    for (int kk = 0; kk < 4; kk++)
        #pragma unroll
        for (int j = 0; j < 2; j++)
            vf[kk][j] = *(const sv8_t*)(vbase + (16 * j + l15) * 112 + kk * 32 + 8 * lhi);

    int klab[7];
    if (shifted) {
        #pragma unroll
        for (int j = 0; j < 7; j++) {
            int kb = 16 * j + 4 * lhi;
            klab[j] = lablut[kb] | (lablut[kb + 1] << 8) | (lablut[kb + 2] << 16) | (lablut[kb + 3] << 24);
        }
    }

    // shuffle sources for P redistribution (constant across ms)
    int src0 = ((lane & 16) << 1) + l15;   // 32*(lhi&1) + l15
    int src1 = src0 + 16;
    bool jlo = (lane < 32);                // lhi>>1 == 0

    sv8_t qa_c = *(const sv8_t*)(qk + (rowbase + l15) * 256 + head * 32 + 8 * lhi);

    for (int ms = 0; ms < 7; ms++) {
        sv8_t qa_n = qa_c;
        if (ms < 6) {
            int qtok = min(16 * (ms + 1) + l15, 97);
            qa_n = *(const sv8_t*)(qk + (rowbase + qtok) * 256 + head * 32 + 8 * lhi);
        }
        int ql = min(16 * ms + l15, 97);
        int labq = shifted ? lablut[ql] : 0;
        const float* bq = biasb + ((size_t)head * 112 + ql) * 112;
        f4ld_t bv[7];
        #pragma unroll
        for (int j = 0; j < 7; j++)
            bv[j] = *(const f4ld_t*)(bq + 16 * j + 4 * lhi);
        fv4_t sc[7];
        __builtin_amdgcn_s_setprio(1);
        #pragma unroll
        for (int j = 0; j < 7; j++) {
            fv4_t z = {0.f, 0.f, 0.f, 0.f};
            sc[j] = __builtin_amdgcn_mfma_f32_16x16x32_bf16(kf[j], qa_c, z, 0, 0, 0);
        }
        __builtin_amdgcn_s_setprio(0);
        float mx = -1e30f;
        #pragma unroll
        for (int j = 0; j < 7; j++) {
            #pragma unroll
            for (int r = 0; r < 4; r++) {
                float s = sc[j][r] + bv[j][r];
                if (shifted && (((klab[j] >> (8 * r)) & 255) != labq)) s -= 100.f;
                if (16 * j + 4 * lhi + r >= 98) s = -1e30f;
                sc[j][r] = s;
                mx = fmaxf(mx, s);
            }
        }
        mx = fmaxf(mx, __shfl_xor(mx, 16));
        mx = fmaxf(mx, __shfl_xor(mx, 32));
        float sm = 0.f;
        #pragma unroll
        for (int j = 0; j < 7; j++)
            #pragma unroll
            for (int r = 0; r < 4; r++) {
                float p = __expf(sc[j][r] - mx);
                sc[j][r] = p;
                sm += p;
            }
        sm += __shfl_xor(sm, 16);
        sm += __shfl_xor(sm, 32);
        float inv = __builtin_amdgcn_rcpf(sm);
        // pack normalized P pairs; entry 7 = zero (k in [112,128) pad)
        int pkl[8], pkh[8];
        #pragma unroll
        for (int j = 0; j < 7; j++) {
            pkl[j] = (int)packbf(sc[j][0] * inv, sc[j][1] * inv);
            pkh[j] = (int)packbf(sc[j][2] * inv, sc[j][3] * inv);
        }
        pkl[7] = 0; pkh[7] = 0;
        fv4_t oacc[2] = {{0.f, 0.f, 0.f, 0.f}, {0.f, 0.f, 0.f, 0.f}};
        #pragma unroll
        for (int kk = 0; kk < 4; kk++) {
            int e_lo0 = __shfl(pkl[2 * kk], src0), o_lo0 = __shfl(pkl[2 * kk + 1], src0);
            int e_hi0 = __shfl(pkh[2 * kk], src0), o_hi0 = __shfl(pkh[2 * kk + 1], src0);
            int e_lo1 = __shfl(pkl[2 * kk], src1), o_lo1 = __shfl(pkl[2 * kk + 1], src1);
            int e_hi1 = __shfl(pkh[2 * kk], src1), o_hi1 = __shfl(pkh[2 * kk + 1], src1);
            union { int u[4]; sv8_t s8; } pa;
            pa.u[0] = jlo ? e_lo0 : o_lo0;
            pa.u[1] = jlo ? e_hi0 : o_hi0;
            pa.u[2] = jlo ? e_lo1 : o_lo1;
            pa.u[3] = jlo ? e_hi1 : o_hi1;
            __builtin_amdgcn_s_setprio(1);
            #pragma unroll
            for (int j = 0; j < 2; j++)
                oacc[j] = __builtin_amdgcn_mfma_f32_16x16x32_bf16(pa.s8, vf[kk][j], oacc[j], 0, 0, 0);
            __builtin_amdgcn_s_setprio(0);
        }
        #pragma unroll
        for (int r = 0; r < 4; r++) {
            int orow = 16 * ms + 4 * lhi + r;
            #pragma unroll
            for (int j = 0; j < 2; j++) {
                int ocol = head * 32 + 16 * j + l15;
                float v = (orow < 98) ? oacc[j][r] : 0.f;
                lds_st1(ot, orow * 256 + SWZB(orow, ocol * 2), f2bf(v));
            }
        }
        qa_c = qa_n;
    }
    __syncthreads();

    {
        int nb = wv * 32;
        fv4_t acc[7][2];
        for (int m = 0; m < 7; m++) for (int j = 0; j < 2; j++) acc[m][j] = (fv4_t){0.f, 0.f, 0.f, 0.f};
        for (int kk = 0; kk < 4; kk++) {
            sv8_t b[2];
            #pragma unroll
            for (int j = 0; j < 2; j++)
                b[j] = *(const sv8_t*)(pwT + (size_t)(nb + 16 * j + l15) * 128 + kk * 32 + 8 * lhi);
            __builtin_amdgcn_s_setprio(1);
            #pragma unroll
            for (int m = 0; m < 7; m++) {
                int ar = 16 * m + l15;
                sv8_t a = lds_ld8(ot, ar * 256 + SWZB(ar, (kk * 32 + 8 * lhi) * 2));
                #pragma unroll
                for (int j = 0; j < 2; j++)
                    acc[m][j] = __builtin_amdgcn_mfma_f32_16x16x32_bf16(a, b[j], acc[m][j], 0, 0, 0);
            }
            __builtin_amdgcn_s_setprio(0);
        }
        int b_ = win >> 8;
        for (int m = 0; m < 7; m++)
            #pragma unroll
            for (int r = 0; r < 4; r++) {
                int row = 16 * m + lhi * 4 + r;
                if (row < 98) {
                    int it = row / 49, r2 = row - it * 49, ih = r2 / 7, iw = r2 - ih * 7;
                    int t = tw * 2 + it, h = hw * 7 + ih, w = ww * 7 + iw;
                    if (shifted) {
                        t += 1; if (t >= TT) t -= TT;
                        h += 3; if (h >= HH) h -= HH;
                        w += 3; if (w >= WW2) w -= WW2;
                    }
                    float* xp = xbuf + ((size_t)b_ * PSPAT + t * (HH * WW2) + h * WW2 + w) * 128 + nb;
                    #pragma unroll
                    for (int j = 0; j < 2; j++) {
                        int c = 16 * j + l15;
                        xp[c] += acc[m][j][r] + pb[nb + c];
                    }
                }
            }
    }
}

// ---------------- fused LN2 + fc1 + GELU + fc2 + residual (+final transpose) ----
#define LOAD_CHUNK(c, R)                                                                   \
    if ((c) < 16) {                                                                        \
        if (((c) & 2) == 0) {                                                              \
            _Pragma("unroll")                                                              \
            for (int i_ = 0; i_ < 4; i_++)                                                 \
                R[i_] = *(const sv8_t*)(w1T + (size_t)(((c) >> 2) * 128 + ((c)&1) * 64 + i_ * 16 + r1) * 128 + (c1 >> 1)); \
        } else {                                                                           \
            _Pragma("unroll")                                                              \
            for (int i_ = 0; i_ < 4; i_++)                                                 \
                R[i_] = *(const sv8_t*)(w2T + (size_t)(i_ * 32 + r2) * 512 + ((c) >> 2) * 128 + ((c)&1) * 64 + (c2 >> 1)); \
        }                                                                                  \
    }
#define WRITE_CHUNK(c, R)                                                                  \
    if ((c) < 16) {                                                                        \
        unsigned short* bst_ = Bst[(c)&1];                                                 \
        if (((c) & 2) == 0) {                                                              \
            _Pragma("unroll")                                                              \
            for (int i_ = 0; i_ < 4; i_++)                                                 \
                lds_st8(bst_, (i_ * 16 + r1) * 256 + SWZB(i_ * 16 + r1, c1), R[i_]);       \
        } else {                                                                           \
            _Pragma("unroll")                                                              \
            for (int i_ = 0; i_ < 4; i_++)                                                 \
                lds_st8(bst_, (i_ * 32 + r2) * 128 + SWZB(i_ * 32 + r2, c2), R[i_]);       \
        }                                                                                  \
    }

__global__ __launch_bounds__(256, 2) void k_mlp(const float* __restrict__ xin,
                                                const float* __restrict__ g,
                                                const float* __restrict__ be,
                                                const unsigned short* __restrict__ w1T,  // [512][128]
                                                const float* __restrict__ b1p,
                                                const unsigned short* __restrict__ w2T,  // [128][512]
                                                const float* __restrict__ b2p,
                                                float* __restrict__ xbuf,
                                                float* __restrict__ outp,
                                                int final_layer) {
    __shared__ unsigned short A[4][32 * 128];   // 32 KB: per-wave xt then U slice
    __shared__ unsigned short Bst[2][8192];     // 2 x 16 KB ping-pong chunks
    int tid = threadIdx.x;
    int wv = tid >> 6, lane = tid & 63, l15 = lane & 15, lhi = lane >> 4;
    unsigned short* bw = A[wv];
    int tok0 = blockIdx.x * 128 + wv * 32;

    int r1 = tid >> 4, c1 = (tid & 15) * 16;   // w1 chunk coords (64x128)
    int r2 = tid >> 3, c2 = (tid & 7) * 16;    // w2 chunk coords (128x64)

    sv8_t wA[4], wB[4];
    LOAD_CHUNK(0, wA)                          // hidden under LN

    // ---- LN (wave-private xt in A[wv])
    #pragma unroll
    for (int tf = 0; tf < 2; tf++) {
        int lrow = 16 * tf + l15;
        const float* src = xin + (size_t)(tok0 + lrow) * 128 + lhi * 32;
        float v[32];
        float s = 0.f, sq = 0.f;
        #pragma unroll
        for (int i = 0; i < 8; i++) {
            f4ld_t f = *(const f4ld_t*)(src + i * 4);
            v[i * 4 + 0] = f.x; v[i * 4 + 1] = f.y; v[i * 4 + 2] = f.z; v[i * 4 + 3] = f.w;
            s += f.x + f.y + f.z + f.w;
            sq += f.x * f.x + f.y * f.y + f.z * f.z + f.w * f.w;
        }
        s += __shfl_xor(s, 16); sq += __shfl_xor(sq, 16);
        s += __shfl_xor(s, 32); sq += __shfl_xor(sq, 32);
        float mu = s * (1.f / 128.f);
        float var = sq * (1.f / 128.f) - mu * mu;
        float rs = rsqrtf(var + 1e-5f);
        #pragma unroll
        for (int j = 0; j < 4; j++) {
            int c0 = lhi * 32 + 8 * j;
            f4ld_t g0 = *(const f4ld_t*)(g + c0);
            f4ld_t g1 = *(const f4ld_t*)(g + c0 + 4);
            f4ld_t b0 = *(const f4ld_t*)(be + c0);
            f4ld_t b1 = *(const f4ld_t*)(be + c0 + 4);
            float y0 = (v[8 * j + 0] - mu) * rs * g0.x + b0.x;
            float y1 = (v[8 * j + 1] - mu) * rs * g0.y + b0.y;
            float y2 = (v[8 * j + 2] - mu) * rs * g0.z + b0.z;
            float y3 = (v[8 * j + 3] - mu) * rs * g0.w + b0.w;
            float y4 = (v[8 * j + 4] - mu) * rs * g1.x + b1.x;
            float y5 = (v[8 * j + 5] - mu) * rs * g1.y + b1.y;
            float y6 = (v[8 * j + 6] - mu) * rs * g1.z + b1.z;
            float y7 = (v[8 * j + 7] - mu) * rs * g1.w + b1.w;
            union { unsigned u[4]; sv8_t s8; } pk;
            pk.u[0] = packbf(y0, y1); pk.u[1] = packbf(y2, y3);
            pk.u[2] = packbf(y4, y5); pk.u[3] = packbf(y6, y7);
            lds_st8(bw, lrow * 256 + SWZB(lrow, 64 * lhi + 16 * j), pk.s8);
        }
    }
    sv8_t xf[2][4];
    #pragma unroll
    for (int tf = 0; tf < 2; tf++)
        #pragma unroll
        for (int kk = 0; kk < 4; kk++) {
            int lrow = 16 * tf + l15;
            xf[tf][kk] = lds_ld8(bw, lrow * 256 + SWZB(lrow, 64 * kk + 16 * lhi));
        }

    fv4_t acc2[8][2];
    #pragma unroll
    for (int cg = 0; cg < 8; cg++)
        #pragma unroll
        for (int tf = 0; tf < 2; tf++) acc2[cg][tf] = (fv4_t){0.f, 0.f, 0.f, 0.f};

    // prologue: stage chunk0, issue chunk1
    WRITE_CHUNK(0, wA)
    LOAD_CHUNK(1, wB)
    __syncthreads();

    #pragma unroll
    for (int q = 0; q < 4; q++) {
        // ---- phase s=0: fc1 fg 0..3 from Bst[0]
        {
            const int c = 4 * q;
            WRITE_CHUNK(c + 1, wB)
            LOAD_CHUNK(c + 2, wA)
            #pragma unroll
            for (int f = 0; f < 4; f++) {
                int fg = f;
                sv8_t wf[4];
                #pragma unroll
                for (int kk = 0; kk < 4; kk++) {
                    int wrow = 16 * f + l15;
                    wf[kk] = lds_ld8(Bst[0], wrow * 256 + SWZB(wrow, kk * 64 + 16 * lhi));
                }
                fv4_t a1[2] = {{0.f, 0.f, 0.f, 0.f}, {0.f, 0.f, 0.f, 0.f}};
                __builtin_amdgcn_s_setprio(1);
                #pragma unroll
                for (int kk = 0; kk < 4; kk++) {
                    a1[0] = __builtin_amdgcn_mfma_f32_16x16x32_bf16(wf[kk], xf[0][kk], a1[0], 0, 0, 0);
                    a1[1] = __builtin_amdgcn_mfma_f32_16x16x32_bf16(wf[kk], xf[1][kk], a1[1], 0, 0, 0);
                }
                __builtin_amdgcn_s_setprio(0);
                f4ld_t b4 = *(const f4ld_t*)(b1p + q * 128 + 16 * fg + 4 * lhi);
                #pragma unroll
                for (int tf = 0; tf < 2; tf++) {
                    float g0 = gelu_f(a1[tf][0] + b4.x);
                    float g1 = gelu_f(a1[tf][1] + b4.y);
                    float g2 = gelu_f(a1[tf][2] + b4.z);
                    float g3 = gelu_f(a1[tf][3] + b4.w);
                    union { unsigned u[2]; uint2 u2; } pk;
                    pk.u[0] = packbf(g0, g1); pk.u[1] = packbf(g2, g3);
                    int lrow = 16 * tf + l15;
                    *(uint2*)((char*)bw + lrow * 256 + SWZB(lrow, 32 * fg + 8 * lhi)) = pk.u2;
                }
            }
            __syncthreads();
        }
        // ---- phase s=1: fc1 fg 4..7 from Bst[1]
        {
            const int c = 4 * q + 1;
            WRITE_CHUNK(c + 1, wA)
            LOAD_CHUNK(c + 2, wB)
            #pragma unroll
            for (int f = 0; f < 4; f++) {
                int fg = 4 + f;
                sv8_t wf[4];
                #pragma unroll
                for (int kk = 0; kk < 4; kk++) {
                    int wrow = 16 * f + l15;
                    wf[kk] = lds_ld8(Bst[1], wrow * 256 + SWZB(wrow, kk * 64 + 16 * lhi));
                }
                fv4_t a1[2] = {{0.f, 0.f, 0.f, 0.f}, {0.f, 0.f, 0.f, 0.f}};
                __builtin_amdgcn_s_setprio(1);
                #pragma unroll
                for (int kk = 0; kk < 4; kk++) {
                    a1[0] = __builtin_amdgcn_mfma_f32_16x16x32_bf16(wf[kk], xf[0][kk], a1[0], 0, 0, 0);
                    a1[1] = __builtin_amdgcn_mfma_f32_16x16x32_bf16(wf[kk], xf[1][kk], a1[1], 0, 0, 0);
                }
                __builtin_amdgcn_s_setprio(0);
                f4ld_t b4 = *(const f4ld_t*)(b1p + q * 128 + 16 * fg + 4 * lhi);
                #pragma unroll
                for (int tf = 0; tf < 2; tf++) {
                    float g0 = gelu_f(a1[tf][0] + b4.x);
                    float g1 = gelu_f(a1[tf][1] + b4.y);
                    float g2 = gelu_f(a1[tf][2] + b4.z);
                    float g3 = gelu_f(a1[tf][3] + b4.w);
                    union { unsigned u[2]; uint2 u2; } pk;
                    pk.u[0] = packbf(g0, g1); pk.u[1] = packbf(g2, g3);
                    int lrow = 16 * tf + l15;
                    *(uint2*)((char*)bw + lrow * 256 + SWZB(lrow, 32 * fg + 8 * lhi)) = pk.u2;
                }
            }
            __syncthreads();
        }
        // ---- phase s=2: fc2 kq 0,1 from Bst[0]
        {
            const int c = 4 * q + 2;
            WRITE_CHUNK(c + 1, wB)
            LOAD_CHUNK(c + 2, wA)
            #pragma unroll
            for (int kq = 0; kq < 2; kq++) {
                sv8_t uf[2];
                #pragma unroll
                for (int tf = 0; tf < 2; tf++) {
                    int lrow = 16 * tf + l15;
                    uf[tf] = lds_ld8(bw, lrow * 256 + SWZB(lrow, 64 * kq + 16 * lhi));
                }
                #pragma unroll
                for (int cb = 0; cb < 2; cb++) {
                    sv8_t w2f[4];
                    #pragma unroll
                    for (int cc = 0; cc < 4; cc++) {
                        int wrow = 16 * (4 * cb + cc) + l15;
                        w2f[cc] = lds_ld8(Bst[0], wrow * 128 + SWZB(wrow, kq * 64 + 16 * lhi));
                    }
                    __builtin_amdgcn_s_setprio(1);
                    #pragma unroll
                    for (int cc = 0; cc < 4; cc++) {
                        int cg = 4 * cb + cc;
                        acc2[cg][0] = __builtin_amdgcn_mfma_f32_16x16x32_bf16(w2f[cc], uf[0], acc2[cg][0], 0, 0, 0);
                        acc2[cg][1] = __builtin_amdgcn_mfma_f32_16x16x32_bf16(w2f[cc], uf[1], acc2[cg][1], 0, 0, 0);
                    }
                    __builtin_amdgcn_s_setprio(0);
                }
            }
            __syncthreads();
        }
        // ---- phase s=3: fc2 kq 2,3 from Bst[1]
        {
            const int c = 4 * q + 3;
            WRITE_CHUNK(c + 1, wA)
            LOAD_CHUNK(c + 2, wB)
            #pragma unroll
            for (int kq = 2; kq < 4; kq++) {
                sv8_t uf[2];
                #pragma unroll
                for (int tf = 0; tf < 2; tf++) {
                    int lrow = 16 * tf + l15;
                    uf[tf] = lds_ld8(bw, lrow * 256 + SWZB(lrow, 64 * kq + 16 * lhi));
                }
                #pragma unroll
                for (int cb = 0; cb < 2; cb++) {
                    sv8_t w2f[4];
                    #pragma unroll
                    for (int cc = 0; cc < 4; cc++) {
                        int wrow = 16 * (4 * cb + cc) + l15;
                        w2f[cc] = lds_ld8(Bst[1], wrow * 128 + SWZB(wrow, (kq - 2) * 64 + 16 * lhi));
                    }
                    __builtin_amdgcn_s_setprio(1);
                    #pragma unroll
                    for (int cc = 0; cc < 4; cc++) {
                        int cg = 4 * cb + cc;
                        acc2[cg][0] = __builtin_amdgcn_mfma_f32_16x16x32_bf16(w2f[cc], uf[0], acc2[cg][0], 0, 0, 0);
                        acc2[cg][1] = __builtin_amdgcn_mfma_f32_16x16x32_bf16(w2f[cc], uf[1], acc2[cg][1], 0, 0, 0);
                    }
                    __builtin_amdgcn_s_setprio(0);
                }
            }
            __syncthreads();
        }
    }
    // ---- epilogue
    if (!final_layer) {
        #pragma unroll
        for (int tf = 0; tf < 2; tf++) {
            int row = tok0 + 16 * tf + l15;
            #pragma unroll
            for (int cg = 0; cg < 8; cg++) {
                int c0 = 16 * cg + 4 * lhi;
                f4ld_t b4 = *(const f4ld_t*)(b2p + c0);
                float* xp = xbuf + (size_t)row * 128 + c0;
                f4ld_t o = *(f4ld_t*)xp;
                o.x += acc2[cg][tf][0] + b4.x;
                o.y += acc2[cg][tf][1] + b4.y;
                o.z += acc2[cg][tf][2] + b4.z;
                o.w += acc2[cg][tf][3] + b4.w;
                *(f4ld_t*)xp = o;
            }
        }
    } else {
        #pragma unroll
        for (int tf = 0; tf < 2; tf++) {
            int row = tok0 + 16 * tf + l15;
            int b_ = row / PSPAT, p = row - b_ * PSPAT;
            float* ob = outp + (size_t)b_ * 128 * PSPAT + p;
            #pragma unroll
            for (int cg = 0; cg < 8; cg++) {
                int c0 = 16 * cg + 4 * lhi;
                f4ld_t b4 = *(const f4ld_t*)(b2p + c0);
                const float* xp = xbuf + (size_t)row * 128 + c0;
                f4ld_t o = *(const f4ld_t*)xp;
                o.x += acc2[cg][tf][0] + b4.x;
                o.y += acc2[cg][tf][1] + b4.y;
                o.z += acc2[cg][tf][2] + b4.z;
                o.w += acc2[cg][tf][3] + b4.w;
                ob[(size_t)(c0 + 0) * PSPAT] = o.x;
                ob[(size_t)(c0 + 1) * PSPAT] = o.y;
                ob[(size_t)(c0 + 2) * PSPAT] = o.z;
                ob[(size_t)(c0 + 3) * PSPAT] = o.w;
            }
        }
    }
}

extern "C" void kernel_launch(void* const* d_in, const int* in_sizes, int n_in,
                              void* d_out, int out_size, void* d_ws, size_t ws_size,
                              hipStream_t stream) {
    const float* x_in   = (const float*)d_in[0];
    const float* ln1_g  = (const float*)d_in[1];
    const float* ln1_b  = (const float*)d_in[2];
    const float* qkv_w  = (const float*)d_in[3];
    const float* qkv_b  = (const float*)d_in[4];
    const float* rpb    = (const float*)d_in[5];
    const float* proj_w = (const float*)d_in[6];
    const float* proj_b = (const float*)d_in[7];
    const float* ln2_g  = (const float*)d_in[8];
    const float* ln2_b  = (const float*)d_in[9];
    const float* fc1_w  = (const float*)d_in[10];
    const float* fc1_b  = (const float*)d_in[11];
    const float* fc2_w  = (const float*)d_in[12];
    const float* fc2_b  = (const float*)d_in[13];
    float* out = (float*)d_out;

    char* ws = (char*)d_ws;
    float* xbuf = (float*)ws;                                        // 102,760,448 B
    unsigned short* qkbuf = (unsigned short*)(ws + 102760448);       // 102,760,448 B
    unsigned short* vTbuf = (unsigned short*)(ws + 205520896);       //  58,720,256 B
    unsigned short* wbase = (unsigned short*)(ws + 264241408);       //     786,432 B
    float* biasb = (float*)(ws + 264241408 + 786432);                //     401,408 B

    k_transpose_in<<<dim3(PSPAT / 32, 4, BB), dim3(32, 8), 0, stream>>>(x_in, xbuf);

    for (int l = 0; l < 2; l++) {
        unsigned short* wqT = wbase + (size_t)l * 196608;
        unsigned short* wpT = wqT + 49152;
        unsigned short* w1T = wpT + 16384;
        unsigned short* w2T = w1T + 65536;
        k_prep_w<<<dim3(12, 4), dim3(32, 8), 0, stream>>>(qkv_w + (size_t)l * 49152, wqT, 128, 384);
        k_prep_w<<<dim3(4, 4),  dim3(32, 8), 0, stream>>>(proj_w + (size_t)l * 16384, wpT, 128, 128);
        k_prep_w<<<dim3(16, 4), dim3(32, 8), 0, stream>>>(fc1_w + (size_t)l * 65536, w1T, 128, 512);
        k_prep_w<<<dim3(4, 16), dim3(32, 8), 0, stream>>>(fc2_w + (size_t)l * 65536, w2T, 512, 128);
    }
    k_prep_bias<<<dim3(112, 4, 2), 112, 0, stream>>>(rpb, biasb);

    for (int layer = 0; layer < 2; layer++) {
        unsigned short* wqT = wbase + (size_t)layer * 196608;
        unsigned short* wpT = wqT + 49152;
        unsigned short* w1T = wpT + 16384;
        unsigned short* w2T = w1T + 65536;
        int shifted = layer & 1;

        k_qkv<<<TOK_TOTAL / 64, 256, 0, stream>>>(xbuf, ln1_g + layer * 128, ln1_b + layer * 128,
                                                  wqT, qkv_b + layer * 384, qkbuf, vTbuf, shifted);
        k_attn_proj<<<BNW, 256, 0, stream>>>(qkbuf, vTbuf, biasb + (size_t)layer * 4 * 112 * 112,
                                             wpT, proj_b + layer * 128, xbuf, shifted);
        k_mlp<<<TOK_TOTAL / 128, 256, 0, stream>>>(xbuf, ln2_g + layer * 128, ln2_b + layer * 128,
                                                   w1T, fc1_b + layer * 512, w2T, fc2_b + layer * 128,
                                                   xbuf, out, layer == 1);
    }
}

// Round 17
// 774.469 us; speedup vs baseline: 1.3679x; 1.0059x over previous
//
#include <hip/hip_runtime.h>
#include <hip/hip_bf16.h>

typedef __attribute__((ext_vector_type(8))) short sv8_t;   // 8 bf16 (4 VGPR)
typedef __attribute__((ext_vector_type(4))) float fv4_t;   // MFMA accumulator
typedef __attribute__((ext_vector_type(4))) float f4ld_t;  // global float4 load

#define BB 8
#define TT 8
#define HH 56
#define WW2 56
#define NTOK 98
#define BNW 2048
#define PSPAT 25088
#define TOK_TOTAL 200704
#define ACT_ELEMS 25690112
#define VT_WSTRIDE 14336   // 128 * 112

#define SWZB(row, cb) ((cb) ^ ((((unsigned)(row)) & 7u) << 4))

__device__ __forceinline__ unsigned short f2bf(float f) {
    union { float f; unsigned u; } x; x.f = f;
    unsigned r = x.u + 0x7fffu + ((x.u >> 16) & 1u);
    return (unsigned short)(r >> 16);
}
// packed pair via v_cvt_pk_bf16_f32 (RNE, bit-identical to f2bf pair, 1 inst)
__device__ __forceinline__ unsigned packbf(float lo, float hi) {
    __hip_bfloat162 h = __float22bfloat162_rn(make_float2(lo, hi));
    union { __hip_bfloat162 h; unsigned u; } cv; cv.h = h; return cv.u;
}
__device__ __forceinline__ sv8_t lds_ld8(const unsigned short* p, int byteoff) {
    return *(const sv8_t*)((const char*)p + byteoff);
}
__device__ __forceinline__ void lds_st8(unsigned short* p, int byteoff, sv8_t v) {
    *(sv8_t*)((char*)p + byteoff) = v;
}
__device__ __forceinline__ void lds_st1(unsigned short* p, int byteoff, unsigned short v) {
    *(unsigned short*)((char*)p + byteoff) = v;
}
// GELU, sigmoid form: x*sigmoid(1.702x)
__device__ __forceinline__ float gelu_f(float v) {
    float e = __expf(-1.702f * v);
    return v * __builtin_amdgcn_rcpf(1.f + e);
}

// ---------------- transpose in: (B,C,P) -> (B,P,C) f32 ----------------
__global__ __launch_bounds__(256) void k_transpose_in(const float* __restrict__ in,
                                                      float* __restrict__ xbuf) {
    __shared__ float tile[32][33];
    int p0 = blockIdx.x * 32, c0 = blockIdx.y * 32, b = blockIdx.z;
    int pi = threadIdx.x, ci = threadIdx.y;
    const float* src = in + ((size_t)b * 128 + c0) * PSPAT + p0;
    for (int r = 0; r < 32; r += 8)
        tile[ci + r][pi] = src[(size_t)(ci + r) * PSPAT + pi];
    __syncthreads();
    float* dst = xbuf + ((size_t)b * PSPAT + p0) * 128 + c0;
    for (int r = 0; r < 32; r += 8)
        dst[(size_t)(ci + r) * 128 + pi] = tile[pi][ci + r];
}

// ---------------- weight prep: in f32 [K][N] -> out bf16 [N][K] ----------------
__global__ __launch_bounds__(256) void k_prep_w(const float* __restrict__ in,
                                                unsigned short* __restrict__ out,
                                                int K, int N) {
    __shared__ float tile[32][33];
    int n0 = blockIdx.x * 32, k0 = blockIdx.y * 32;
    int x = threadIdx.x, y = threadIdx.y;
    for (int r = 0; r < 32; r += 8)
        tile[y + r][x] = in[(size_t)(k0 + y + r) * N + n0 + x];
    __syncthreads();
    for (int r = 0; r < 32; r += 8)
        out[(size_t)(n0 + y + r) * K + k0 + x] = f2bf(tile[x][y + r]);
}

// ---------------- bias prep: biasb[layer][head][q row][k col] ----------------
__global__ void k_prep_bias(const float* __restrict__ rpb, float* __restrict__ biasb) {
    int col = threadIdx.x;   // 0..111 (k index)
    int row = blockIdx.x;    // 0..111 (q index)
    int head = blockIdx.y;   // 0..3
    int layer = blockIdx.z;
    int tn = min(row, 97), tm = min(col, 97);
    int itn = tn / 49, rn = tn - itn * 49, ihn = rn / 7, iwn = rn - ihn * 7;
    int itm = tm / 49, rm = tm - itm * 49, ihm = rm / 7, iwm = rm - ihm * 7;
    int dt = itn - itm + 1, dh = ihn - ihm + 6, dw = iwn - iwm + 6;
    float v = rpb[((size_t)layer * 507 + dt * 169 + dh * 13 + dw) * 4 + head];
    biasb[(((size_t)layer * 4 + head) * 112 + row) * 112 + col] = v;
}

// ---------------- fused LN1 + gather + qkv GEMM ----------------
__global__ __launch_bounds__(256) void k_qkv(const float* __restrict__ xbuf,
                                             const float* __restrict__ g,
                                             const float* __restrict__ be,
                                             const unsigned short* __restrict__ wT,  // [384][128]
                                             const float* __restrict__ bias,         // [384]
                                             unsigned short* __restrict__ qkbuf,
                                             unsigned short* __restrict__ vT,
                                             int shifted) {
    __shared__ unsigned short xt[64 * 128];
    int tid = threadIdx.x;
    int row0 = blockIdx.x * 64;
    {
        int r = tid >> 2, q = tid & 3;
        int wt = row0 + r;
        int win = wt / 98, n = wt - win * 98;
        int b_ = win >> 8, wrem = win & 255;
        int tw = wrem >> 6, hw = (wrem >> 3) & 7, ww = wrem & 7;
        int it = n / 49, r2 = n - it * 49, ih = r2 / 7, iw = r2 - ih * 7;
        int t = tw * 2 + it, h = hw * 7 + ih, w = ww * 7 + iw;
        if (shifted) {
            t += 1; if (t >= TT) t -= TT;
            h += 3; if (h >= HH) h -= HH;
            w += 3; if (w >= WW2) w -= WW2;
        }
        const float* src = xbuf + ((size_t)b_ * PSPAT + t * (HH * WW2) + h * WW2 + w) * 128 + q * 32;
        float v[32];
        float s = 0.f, sq = 0.f;
        for (int i = 0; i < 8; i++) {
            f4ld_t f = *(const f4ld_t*)(src + i * 4);
            v[i * 4 + 0] = f.x; v[i * 4 + 1] = f.y; v[i * 4 + 2] = f.z; v[i * 4 + 3] = f.w;
            s += f.x + f.y + f.z + f.w;
            sq += f.x * f.x + f.y * f.y + f.z * f.z + f.w * f.w;
        }
        s += __shfl_xor(s, 1); sq += __shfl_xor(sq, 1);
        s += __shfl_xor(s, 2); sq += __shfl_xor(sq, 2);
        float mu = s * (1.f / 128.f);
        float var = sq * (1.f / 128.f) - mu * mu;
        float rs = rsqrtf(var + 1e-5f);
        for (int c0 = 0; c0 < 32; c0 += 8) {
            float y[8];
            #pragma unroll
            for (int i = 0; i < 8; i++) {
                int c = q * 32 + c0 + i;
                y[i] = (v[c0 + i] - mu) * rs * g[c] + be[c];
            }
            union { unsigned u[4]; sv8_t s8; } pk;
            pk.u[0] = packbf(y[0], y[1]); pk.u[1] = packbf(y[2], y[3]);
            pk.u[2] = packbf(y[4], y[5]); pk.u[3] = packbf(y[6], y[7]);
            lds_st8(xt, r * 256 + SWZB(r, (q * 32 + c0) * 2), pk.s8);
        }
    }
    __syncthreads();
    int wv = tid >> 6, lane = tid & 63, l15 = lane & 15, lhi = lane >> 4;

    if (wv < 2) {
        // Q (wv0) or K (wv1), swapped: C[d][tok]; 8 d16-frags, packed 8B stores
        int nb = wv * 128;
        fv4_t acc[4][8];
        for (int m = 0; m < 4; m++) for (int f = 0; f < 8; f++) acc[m][f] = (fv4_t){0.f, 0.f, 0.f, 0.f};
        for (int kk = 0; kk < 4; kk++) {
            sv8_t x4[4];
            #pragma unroll
            for (int m = 0; m < 4; m++) {
                int ar = 16 * m + l15;
                x4[m] = lds_ld8(xt, ar * 256 + SWZB(ar, (kk * 32 + 8 * lhi) * 2));
            }
            #pragma unroll
            for (int f = 0; f < 8; f++) {
                sv8_t wf = *(const sv8_t*)(wT + (size_t)(nb + 16 * f + l15) * 128 + kk * 32 + 8 * lhi);
                #pragma unroll
                for (int m = 0; m < 4; m++)
                    acc[m][f] = __builtin_amdgcn_mfma_f32_16x16x32_bf16(wf, x4[m], acc[m][f], 0, 0, 0);
            }
        }
        float sc_ = (wv == 0) ? 0.17677669529663687f : 1.f;
        #pragma unroll
        for (int f = 0; f < 8; f++) {
            f4ld_t b4 = *(const f4ld_t*)(bias + nb + 16 * f + 4 * lhi);
            #pragma unroll
            for (int m = 0; m < 4; m++) {
                int row = row0 + 16 * m + l15;
                union { unsigned u[2]; uint2 u2; } pk;
                pk.u[0] = packbf((acc[m][f][0] + b4.x) * sc_, (acc[m][f][1] + b4.y) * sc_);
                pk.u[1] = packbf((acc[m][f][2] + b4.z) * sc_, (acc[m][f][3] + b4.w) * sc_);
                *(uint2*)(qkbuf + (size_t)row * 256 + nb + 16 * f + 4 * lhi) = pk.u2;
            }
        }
    } else {
        int d16base = (wv - 2) * 4;
        fv4_t acc[4][4];   // [m][f]
        for (int m = 0; m < 4; m++) for (int f = 0; f < 4; f++) acc[m][f] = (fv4_t){0.f, 0.f, 0.f, 0.f};
        for (int kk = 0; kk < 4; kk++) {
            sv8_t x4[4];
            #pragma unroll
            for (int m = 0; m < 4; m++) {
                int ar = 16 * m + l15;
                x4[m] = lds_ld8(xt, ar * 256 + SWZB(ar, (kk * 32 + 8 * lhi) * 2));
            }
            #pragma unroll
            for (int f = 0; f < 4; f++) {
                sv8_t wf = *(const sv8_t*)(wT + (size_t)(256 + (d16base + f) * 16 + l15) * 128 + kk * 32 + 8 * lhi);
                #pragma unroll
                for (int m = 0; m < 4; m++)
                    acc[m][f] = __builtin_amdgcn_mfma_f32_16x16x32_bf16(wf, x4[m], acc[m][f], 0, 0, 0);
            }
        }
        #pragma unroll
        for (int f = 0; f < 4; f++) {
            f4ld_t b4 = *(const f4ld_t*)(bias + 256 + (d16base + f) * 16 + 4 * lhi);
            #pragma unroll
            for (int r = 0; r < 4; r++) {
                int d = (d16base + f) * 16 + 4 * lhi + r;
                #pragma unroll
                for (int m = 0; m < 4; m++) {
                    int row = row0 + 16 * m + l15;
                    int win = row / 98, tok = row - win * 98;
                    vT[(size_t)win * VT_WSTRIDE + d * 112 + tok] = f2bf(acc[m][f][r] + b4[r]);
                }
            }
        }
    }
}

// ---------------- attention core + proj, one block per window ----------------
// Swapped QK^T, in-lane softmax; P redistributed in-register via shfl+select.
__global__ __launch_bounds__(256, 3) void k_attn_proj(const unsigned short* __restrict__ qk,
                                                      const unsigned short* __restrict__ vT,
                                                      const float* __restrict__ biasb,  // [4][q 112][k 112]
                                                      const unsigned short* __restrict__ pwT, // [128][128]
                                                      const float* __restrict__ pb,
                                                      float* __restrict__ xbuf,
                                                      int shifted) {
    __shared__ unsigned short ot[112 * 128];
    __shared__ int lablut[112];
    int win = blockIdx.x;
    int tid = threadIdx.x;
    int wv = tid >> 6, lane = tid & 63;
    int head = wv;
    int l15 = lane & 15, lhi = lane >> 4;
    int wrem = win & 255;
    int tw = wrem >> 6, hw = (wrem >> 3) & 7, ww = wrem & 7;

    for (int m = tid; m < 112; m += 256) {
        int t0 = min(m, 97);
        int it = t0 / 49, r2 = t0 - it * 49, ih = r2 / 7, iw = r2 - ih * 7;
        int lab = 0;
        if (shifted) {
            int t = tw * 2 + it, h = hw * 7 + ih, w = ww * 7 + iw;
            int ct = (t < TT - 2) ? 0 : ((t < TT - 1) ? 1 : 2);
            int ch = (h < HH - 7) ? 0 : ((h < HH - 3) ? 1 : 2);
            int cw = (w < WW2 - 7) ? 0 : ((w < WW2 - 3) ? 1 : 2);
            lab = ct * 9 + ch * 3 + cw;
        }
        lablut[m] = lab;
    }
    __syncthreads();

    size_t rowbase = (size_t)win * 98;
    sv8_t kf[7];
    #pragma unroll
    for (int j = 0; j < 7; j++) {
        int tok = min(16 * j + l15, 97);
        kf[j] = *(const sv8_t*)(qk + (rowbase + tok) * 256 + 128 + head * 32 + 8 * lhi);
    }
    const unsigned short* vbase = vT + (size_t)win * VT_WSTRIDE + (head * 32) * 112;
    sv8_t vf[4][2];
    #pragma unroll
    for (int kk = 0; kk < 4; kk++)
        #pragma unroll
        for (int j = 0; j < 2; j++)
            vf[kk][j] = *(const sv8_t*)(vbase + (16 * j + l15) * 112 + kk * 32 + 8 * lhi);

    int klab[7];
    if (shifted) {
        #pragma unroll
        for (int j = 0; j < 7; j++) {
            int kb = 16 * j + 4 * lhi;
            klab[j] = lablut[kb] | (lablut[kb + 1] << 8) | (lablut[kb + 2] << 16) | (lablut[kb + 3] << 24);
        }
    }

    int src0 = ((lane & 16) << 1) + l15;   // 32*(lhi&1) + l15
    int src1 = src0 + 16;
    bool jlo = (lane < 32);

    sv8_t qa_c = *(const sv8_t*)(qk + (rowbase + l15) * 256 + head * 32 + 8 * lhi);

    for (int ms = 0; ms < 7; ms++) {
        sv8_t qa_n = qa_c;
        if (ms < 6) {
            int qtok = min(16 * (ms + 1) + l15, 97);
            qa_n = *(const sv8_t*)(qk + (rowbase + qtok) * 256 + head * 32 + 8 * lhi);
        }
        int ql = min(16 * ms + l15, 97);
        int labq = shifted ? lablut[ql] : 0;
        const float* bq = biasb + ((size_t)head * 112 + ql) * 112;
        f4ld_t bv[7];
        #pragma unroll
        for (int j = 0; j < 7; j++)
            bv[j] = *(const f4ld_t*)(bq + 16 * j + 4 * lhi);
        fv4_t sc[7];
        __builtin_amdgcn_s_setprio(1);
        #pragma unroll
        for (int j = 0; j < 7; j++) {
            fv4_t z = {0.f, 0.f, 0.f, 0.f};
            sc[j] = __builtin_amdgcn_mfma_f32_16x16x32_bf16(kf[j], qa_c, z, 0, 0, 0);
        }
        __builtin_amdgcn_s_setprio(0);
        float mx = -1e30f;
        #pragma unroll
        for (int j = 0; j < 7; j++) {
            #pragma unroll
            for (int r = 0; r < 4; r++) {
                float s = sc[j][r] + bv[j][r];
                if (shifted && (((klab[j] >> (8 * r)) & 255) != labq)) s -= 100.f;
                if (16 * j + 4 * lhi + r >= 98) s = -1e30f;
                sc[j][r] = s;
                mx = fmaxf(mx, s);
            }
        }
        mx = fmaxf(mx, __shfl_xor(mx, 16));
        mx = fmaxf(mx, __shfl_xor(mx, 32));
        float sm = 0.f;
        #pragma unroll
        for (int j = 0; j < 7; j++)
            #pragma unroll
            for (int r = 0; r < 4; r++) {
                float p = __expf(sc[j][r] - mx);
                sc[j][r] = p;
                sm += p;
            }
        sm += __shfl_xor(sm, 16);
        sm += __shfl_xor(sm, 32);
        float inv = __builtin_amdgcn_rcpf(sm);
        int pkl[8], pkh[8];
        #pragma unroll
        for (int j = 0; j < 7; j++) {
            pkl[j] = (int)packbf(sc[j][0] * inv, sc[j][1] * inv);
            pkh[j] = (int)packbf(sc[j][2] * inv, sc[j][3] * inv);
        }
        pkl[7] = 0; pkh[7] = 0;
        fv4_t oacc[2] = {{0.f, 0.f, 0.f, 0.f}, {0.f, 0.f, 0.f, 0.f}};
        #pragma unroll
        for (int kk = 0; kk < 4; kk++) {
            int e_lo0 = __shfl(pkl[2 * kk], src0), o_lo0 = __shfl(pkl[2 * kk + 1], src0);
            int e_hi0 = __shfl(pkh[2 * kk], src0), o_hi0 = __shfl(pkh[2 * kk + 1], src0);
            int e_lo1 = __shfl(pkl[2 * kk], src1), o_lo1 = __shfl(pkl[2 * kk + 1], src1);
            int e_hi1 = __shfl(pkh[2 * kk], src1), o_hi1 = __shfl(pkh[2 * kk + 1], src1);
            union { int u[4]; sv8_t s8; } pa;
            pa.u[0] = jlo ? e_lo0 : o_lo0;
            pa.u[1] = jlo ? e_hi0 : o_hi0;
            pa.u[2] = jlo ? e_lo1 : o_lo1;
            pa.u[3] = jlo ? e_hi1 : o_hi1;
            __builtin_amdgcn_s_setprio(1);
            #pragma unroll
            for (int j = 0; j < 2; j++)
                oacc[j] = __builtin_amdgcn_mfma_f32_16x16x32_bf16(pa.s8, vf[kk][j], oacc[j], 0, 0, 0);
            __builtin_amdgcn_s_setprio(0);
        }
        #pragma unroll
        for (int r = 0; r < 4; r++) {
            int orow = 16 * ms + 4 * lhi + r;
            #pragma unroll
            for (int j = 0; j < 2; j++) {
                int ocol = head * 32 + 16 * j + l15;
                float v = (orow < 98) ? oacc[j][r] : 0.f;
                lds_st1(ot, orow * 256 + SWZB(orow, ocol * 2), f2bf(v));
            }
        }
        qa_c = qa_n;
    }
    __syncthreads();

    {
        int nb = wv * 32;
        fv4_t acc[7][2];
        for (int m = 0; m < 7; m++) for (int j = 0; j < 2; j++) acc[m][j] = (fv4_t){0.f, 0.f, 0.f, 0.f};
        for (int kk = 0; kk < 4; kk++) {
            sv8_t b[2];
            #pragma unroll
            for (int j = 0; j < 2; j++)
                b[j] = *(const sv8_t*)(pwT + (size_t)(nb + 16 * j + l15) * 128 + kk * 32 + 8 * lhi);
            __builtin_amdgcn_s_setprio(1);
            #pragma unroll
            for (int m = 0; m < 7; m++) {
                int ar = 16 * m + l15;
                sv8_t a = lds_ld8(ot, ar * 256 + SWZB(ar, (kk * 32 + 8 * lhi) * 2));
                #pragma unroll
                for (int j = 0; j < 2; j++)
                    acc[m][j] = __builtin_amdgcn_mfma_f32_16x16x32_bf16(a, b[j], acc[m][j], 0, 0, 0);
            }
            __builtin_amdgcn_s_setprio(0);
        }
        int b_ = win >> 8;
        for (int m = 0; m < 7; m++)
            #pragma unroll
            for (int r = 0; r < 4; r++) {
                int row = 16 * m + lhi * 4 + r;
                if (row < 98) {
                    int it = row / 49, r2 = row - it * 49, ih = r2 / 7, iw = r2 - ih * 7;
                    int t = tw * 2 + it, h = hw * 7 + ih, w = ww * 7 + iw;
                    if (shifted) {
                        t += 1; if (t >= TT) t -= TT;
                        h += 3; if (h >= HH) h -= HH;
                        w += 3; if (w >= WW2) w -= WW2;
                    }
                    float* xp = xbuf + ((size_t)b_ * PSPAT + t * (HH * WW2) + h * WW2 + w) * 128 + nb;
                    #pragma unroll
                    for (int j = 0; j < 2; j++) {
                        int c = 16 * j + l15;
                        xp[c] += acc[m][j][r] + pb[nb + c];
                    }
                }
            }
    }
}

// ---------------- fused LN2 + fc1 + GELU + fc2 + residual (+final transpose) ----
// 48 KB LDS (A 16 KB U-half + Bst 32 KB) -> 3 blocks/CU. Phase order per quarter:
// {w1h0->fc1(fg0-3), w2h0->fc2(kq0,1), w1h1->fc1(fg4-7), w2h1->fc2(kq2,3)} so the
// per-wave U buffer holds only a 64-col half. xt is staged in Bst during LN
// (chunk0 still in registers). Same ping-pong 2-ahead prefetch, 17 barriers.
// chunk c: type=c&1 (0=w1, 1=w2), q=c>>2, half=(c>>1)&1, buffer=Bst[c&1].
#define LOAD_CHUNK(c, R)                                                                   \
    if ((c) < 16) {                                                                        \
        if (((c) & 1) == 0) {                                                              \
            _Pragma("unroll")                                                              \
            for (int i_ = 0; i_ < 4; i_++)                                                 \
                R[i_] = *(const sv8_t*)(w1T + (size_t)(((c) >> 2) * 128 + (((c) >> 1) & 1) * 64 + i_ * 16 + r1) * 128 + (c1 >> 1)); \
        } else {                                                                           \
            _Pragma("unroll")                                                              \
            for (int i_ = 0; i_ < 4; i_++)                                                 \
                R[i_] = *(const sv8_t*)(w2T + (size_t)(i_ * 32 + r2) * 512 + ((c) >> 2) * 128 + (((c) >> 1) & 1) * 64 + (c2 >> 1)); \
        }                                                                                  \
    }
#define WRITE_CHUNK(c, R)                                                                  \
    if ((c) < 16) {                                                                        \
        unsigned short* bst_ = Bst[(c)&1];                                                 \
        if (((c) & 1) == 0) {                                                              \
            _Pragma("unroll")                                                              \
            for (int i_ = 0; i_ < 4; i_++)                                                 \
                lds_st8(bst_, (i_ * 16 + r1) * 256 + SWZB(i_ * 16 + r1, c1), R[i_]);       \
        } else {                                                                           \
            _Pragma("unroll")                                                              \
            for (int i_ = 0; i_ < 4; i_++)                                                 \
                lds_st8(bst_, (i_ * 32 + r2) * 128 + SWZB(i_ * 32 + r2, c2), R[i_]);       \
        }                                                                                  \
    }

__global__ __launch_bounds__(256, 3) void k_mlp(const float* __restrict__ xin,
                                                const float* __restrict__ g,
                                                const float* __restrict__ be,
                                                const unsigned short* __restrict__ w1T,  // [512][128]
                                                const float* __restrict__ b1p,
                                                const unsigned short* __restrict__ w2T,  // [128][512]
                                                const float* __restrict__ b2p,
                                                float* __restrict__ xbuf,
                                                float* __restrict__ outp,
                                                int final_layer) {
    __shared__ unsigned short A[4][32 * 64];    // 16 KB: per-wave U half (32 tok x 64 ucols)
    __shared__ unsigned short Bst[2][8192];     // 32 KB: ping-pong chunks; xt during LN
    int tid = threadIdx.x;
    int wv = tid >> 6, lane = tid & 63, l15 = lane & 15, lhi = lane >> 4;
    unsigned short* uw = A[wv];
    unsigned short* xts = &Bst[0][0];           // 128 rows x 256B during LN
    int tok0 = blockIdx.x * 128 + wv * 32;

    int r1 = tid >> 4, c1 = (tid & 15) * 16;   // w1 chunk coords (64x128 elems, 256B rows)
    int r2 = tid >> 3, c2 = (tid & 7) * 16;    // w2 chunk coords (128x64 elems, 128B rows)

    sv8_t wA[4], wB[4];
    LOAD_CHUNK(0, wA)                          // hidden under LN

    // ---- LN (xt staged in Bst; wave-private rows wv*32..+31)
    #pragma unroll
    for (int tf = 0; tf < 2; tf++) {
        int lrow = 16 * tf + l15;
        int grow = wv * 32 + lrow;
        const float* src = xin + (size_t)(tok0 + lrow) * 128 + lhi * 32;
        float v[32];
        float s = 0.f, sq = 0.f;
        #pragma unroll
        for (int i = 0; i < 8; i++) {
            f4ld_t f = *(const f4ld_t*)(src + i * 4);
            v[i * 4 + 0] = f.x; v[i * 4 + 1] = f.y; v[i * 4 + 2] = f.z; v[i * 4 + 3] = f.w;
            s += f.x + f.y + f.z + f.w;
            sq += f.x * f.x + f.y * f.y + f.z * f.z + f.w * f.w;
        }
        s += __shfl_xor(s, 16); sq += __shfl_xor(sq, 16);
        s += __shfl_xor(s, 32); sq += __shfl_xor(sq, 32);
        float mu = s * (1.f / 128.f);
        float var = sq * (1.f / 128.f) - mu * mu;
        float rs = rsqrtf(var + 1e-5f);
        #pragma unroll
        for (int j = 0; j < 4; j++) {
            int c0 = lhi * 32 + 8 * j;
            f4ld_t g0 = *(const f4ld_t*)(g + c0);
            f4ld_t g1 = *(const f4ld_t*)(g + c0 + 4);
            f4ld_t b0 = *(const f4ld_t*)(be + c0);
            f4ld_t b1 = *(const f4ld_t*)(be + c0 + 4);
            float y0 = (v[8 * j + 0] - mu) * rs * g0.x + b0.x;
            float y1 = (v[8 * j + 1] - mu) * rs * g0.y + b0.y;
            float y2 = (v[8 * j + 2] - mu) * rs * g0.z + b0.z;
            float y3 = (v[8 * j + 3] - mu) * rs * g0.w + b0.w;
            float y4 = (v[8 * j + 4] - mu) * rs * g1.x + b1.x;
            float y5 = (v[8 * j + 5] - mu) * rs * g1.y + b1.y;
            float y6 = (v[8 * j + 6] - mu) * rs * g1.z + b1.z;
            float y7 = (v[8 * j + 7] - mu) * rs * g1.w + b1.w;
            union { unsigned u[4]; sv8_t s8; } pk;
            pk.u[0] = packbf(y0, y1); pk.u[1] = packbf(y2, y3);
            pk.u[2] = packbf(y4, y5); pk.u[3] = packbf(y6, y7);
            lds_st8(xts, grow * 256 + SWZB(grow, 64 * lhi + 16 * j), pk.s8);
        }
    }
    sv8_t xf[2][4];
    #pragma unroll
    for (int tf = 0; tf < 2; tf++)
        #pragma unroll
        for (int kk = 0; kk < 4; kk++) {
            int grow = wv * 32 + 16 * tf + l15;
            xf[tf][kk] = lds_ld8(xts, grow * 256 + SWZB(grow, 64 * kk + 16 * lhi));
        }

    fv4_t acc2[8][2];
    #pragma unroll
    for (int cg = 0; cg < 8; cg++)
        #pragma unroll
        for (int tf = 0; tf < 2; tf++) acc2[cg][tf] = (fv4_t){0.f, 0.f, 0.f, 0.f};

    __syncthreads();   // all waves done with xt in Bst
    // prologue: stage chunk0, issue chunk1
    WRITE_CHUNK(0, wA)
    LOAD_CHUNK(1, wB)
    __syncthreads();

    #pragma unroll
    for (int q = 0; q < 4; q++) {
        // ---- phase c=4q+0: fc1 fg 0..3 from Bst[0] (w1 h0) -> U half
        {
            const int c = 4 * q;
            WRITE_CHUNK(c + 1, wB)
            LOAD_CHUNK(c + 2, wA)
            #pragma unroll
            for (int f = 0; f < 4; f++) {
                sv8_t wf[4];
                #pragma unroll
                for (int kk = 0; kk < 4; kk++) {
                    int wrow = 16 * f + l15;
                    wf[kk] = lds_ld8(Bst[0], wrow * 256 + SWZB(wrow, kk * 64 + 16 * lhi));
                }
                fv4_t a1[2] = {{0.f, 0.f, 0.f, 0.f}, {0.f, 0.f, 0.f, 0.f}};
                __builtin_amdgcn_s_setprio(1);
                #pragma unroll
                for (int kk = 0; kk < 4; kk++) {
                    a1[0] = __builtin_amdgcn_mfma_f32_16x16x32_bf16(wf[kk], xf[0][kk], a1[0], 0, 0, 0);
                    a1[1] = __builtin_amdgcn_mfma_f32_16x16x32_bf16(wf[kk], xf[1][kk], a1[1], 0, 0, 0);
                }
                __builtin_amdgcn_s_setprio(0);
                f4ld_t b4 = *(const f4ld_t*)(b1p + q * 128 + 16 * f + 4 * lhi);
                #pragma unroll
                for (int tf = 0; tf < 2; tf++) {
                    float g0 = gelu_f(a1[tf][0] + b4.x);
                    float g1 = gelu_f(a1[tf][1] + b4.y);
                    float g2 = gelu_f(a1[tf][2] + b4.z);
                    float g3 = gelu_f(a1[tf][3] + b4.w);
                    union { unsigned u[2]; uint2 u2; } pk;
                    pk.u[0] = packbf(g0, g1); pk.u[1] = packbf(g2, g3);
                    int lrow = 16 * tf + l15;
                    *(uint2*)((char*)uw + lrow * 128 + SWZB(lrow, 32 * f + 8 * lhi)) = pk.u2;
                }
            }
            __syncthreads();
        }
        // ---- phase c=4q+1: fc2 (K = U cols q*128..+63) from Bst[1] (w2 h0)
        {
            const int c = 4 * q + 1;
            WRITE_CHUNK(c + 1, wA)
            LOAD_CHUNK(c + 2, wB)
            #pragma unroll
            for (int kql = 0; kql < 2; kql++) {
                sv8_t uf[2];
                #pragma unroll
                for (int tf = 0; tf < 2; tf++) {
                    int lrow = 16 * tf + l15;
                    uf[tf] = lds_ld8(uw, lrow * 128 + SWZB(lrow, 64 * kql + 16 * lhi));
                }
                #pragma unroll
                for (int cb = 0; cb < 2; cb++) {
                    sv8_t w2f[4];
                    #pragma unroll
                    for (int cc = 0; cc < 4; cc++) {
                        int wrow = 16 * (4 * cb + cc) + l15;
                        w2f[cc] = lds_ld8(Bst[1], wrow * 128 + SWZB(wrow, kql * 64 + 16 * lhi));
                    }
                    __builtin_amdgcn_s_setprio(1);
                    #pragma unroll
                    for (int cc = 0; cc < 4; cc++) {
                        int cg = 4 * cb + cc;
                        acc2[cg][0] = __builtin_amdgcn_mfma_f32_16x16x32_bf16(w2f[cc], uf[0], acc2[cg][0], 0, 0, 0);
                        acc2[cg][1] = __builtin_amdgcn_mfma_f32_16x16x32_bf16(w2f[cc], uf[1], acc2[cg][1], 0, 0, 0);
                    }
                    __builtin_amdgcn_s_setprio(0);
                }
            }
            __syncthreads();
        }
        // ---- phase c=4q+2: fc1 fg 4..7 from Bst[0] (w1 h1) -> same U half buffer
        {
            const int c = 4 * q + 2;
            WRITE_CHUNK(c + 1, wB)
            LOAD_CHUNK(c + 2, wA)
            #pragma unroll
            for (int f = 0; f < 4; f++) {
                sv8_t wf[4];
                #pragma unroll
                for (int kk = 0; kk < 4; kk++) {
                    int wrow = 16 * f + l15;
                    wf[kk] = lds_ld8(Bst[0], wrow * 256 + SWZB(wrow, kk * 64 + 16 * lhi));
                }
                fv4_t a1[2] = {{0.f, 0.f, 0.f, 0.f}, {0.f, 0.f, 0.f, 0.f}};
                __builtin_amdgcn_s_setprio(1);
                #pragma unroll
                for (int kk = 0; kk < 4; kk++) {
                    a1[0] = __builtin_amdgcn_mfma_f32_16x16x32_bf16(wf[kk], xf[0][kk], a1[0], 0, 0, 0);
                    a1[1] = __builtin_amdgcn_mfma_f32_16x16x32_bf16(wf[kk], xf[1][kk], a1[1], 0, 0, 0);
                }
                __builtin_amdgcn_s_setprio(0);
                f4ld_t b4 = *(const f4ld_t*)(b1p + q * 128 + 64 + 16 * f + 4 * lhi);
                #pragma unroll
                for (int tf = 0; tf < 2; tf++) {
                    float g0 = gelu_f(a1[tf][0] + b4.x);
                    float g1 = gelu_f(a1[tf][1] + b4.y);
                    float g2 = gelu_f(a1[tf][2] + b4.z);
                    float g3 = gelu_f(a1[tf][3] + b4.w);
                    union { unsigned u[2]; uint2 u2; } pk;
                    pk.u[0] = packbf(g0, g1); pk.u[1] = packbf(g2, g3);
                    int lrow = 16 * tf + l15;
                    *(uint2*)((char*)uw + lrow * 128 + SWZB(lrow, 32 * f + 8 * lhi)) = pk.u2;
                }
            }
            __syncthreads();
        }
        // ---- phase c=4q+3: fc2 (K = U cols q*128+64..+127) from Bst[1] (w2 h1)
        {
            const int c = 4 * q + 3;
            WRITE_CHUNK(c + 1, wA)
            LOAD_CHUNK(c + 2, wB)
            #pragma unroll
            for (int kql = 0; kql < 2; kql++) {
                sv8_t uf[2];
                #pragma unroll
                for (int tf = 0; tf < 2; tf++) {
                    int lrow = 16 * tf + l15;
                    uf[tf] = lds_ld8(uw, lrow * 128 + SWZB(lrow, 64 * kql + 16 * lhi));
                }
                #pragma unroll
                for (int cb = 0; cb < 2; cb++) {
                    sv8_t w2f[4];
                    #pragma unroll
                    for (int cc = 0; cc < 4; cc++) {
                        int wrow = 16 * (4 * cb + cc) + l15;
                        w2f[cc] = lds_ld8(Bst[1], wrow * 128 + SWZB(wrow, kql * 64 + 16 * lhi));
                    }
                    __builtin_amdgcn_s_setprio(1);
                    #pragma unroll
                    for (int cc = 0; cc < 4; cc++) {
                        int cg = 4 * cb + cc;
                        acc2[cg][0] = __builtin_amdgcn_mfma_f32_16x16x32_bf16(w2f[cc], uf[0], acc2[cg][0], 0, 0, 0);
                        acc2[cg][1] = __builtin_amdgcn_mfma_f32_16x16x32_bf16(w2f[cc], uf[1], acc2[cg][1], 0, 0, 0);
                    }
                    __builtin_amdgcn_s_setprio(0);
                }
            }
            __syncthreads();
        }
    }
    // ---- epilogue
    if (!final_layer) {
        #pragma unroll
        for (int tf = 0; tf < 2; tf++) {
            int row = tok0 + 16 * tf + l15;
            #pragma unroll
            for (int cg = 0; cg < 8; cg++) {
                int c0 = 16 * cg + 4 * lhi;
                f4ld_t b4 = *(const f4ld_t*)(b2p + c0);
                float* xp = xbuf + (size_t)row * 128 + c0;
                f4ld_t o = *(f4ld_t*)xp;
                o.x += acc2[cg][tf][0] + b4.x;
                o.y += acc2[cg][tf][1] + b4.y;
                o.z += acc2[cg][tf][2] + b4.z;
                o.w += acc2[cg][tf][3] + b4.w;
                *(f4ld_t*)xp = o;
            }
        }
    } else {
        #pragma unroll
        for (int tf = 0; tf < 2; tf++) {
            int row = tok0 + 16 * tf + l15;
            int b_ = row / PSPAT, p = row - b_ * PSPAT;
            float* ob = outp + (size_t)b_ * 128 * PSPAT + p;
            #pragma unroll
            for (int cg = 0; cg < 8; cg++) {
                int c0 = 16 * cg + 4 * lhi;
                f4ld_t b4 = *(const f4ld_t*)(b2p + c0);
                const float* xp = xbuf + (size_t)row * 128 + c0;
                f4ld_t o = *(const f4ld_t*)xp;
                o.x += acc2[cg][tf][0] + b4.x;
                o.y += acc2[cg][tf][1] + b4.y;
                o.z += acc2[cg][tf][2] + b4.z;
                o.w += acc2[cg][tf][3] + b4.w;
                ob[(size_t)(c0 + 0) * PSPAT] = o.x;
                ob[(size_t)(c0 + 1) * PSPAT] = o.y;
                ob[(size_t)(c0 + 2) * PSPAT] = o.z;
                ob[(size_t)(c0 + 3) * PSPAT] = o.w;
            }
        }
    }
}

extern "C" void kernel_launch(void* const* d_in, const int* in_sizes, int n_in,
                              void* d_out, int out_size, void* d_ws, size_t ws_size,
                              hipStream_t stream) {
    const float* x_in   = (const float*)d_in[0];
    const float* ln1_g  = (const float*)d_in[1];
    const float* ln1_b  = (const float*)d_in[2];
    const float* qkv_w  = (const float*)d_in[3];
    const float* qkv_b  = (const float*)d_in[4];
    const float* rpb    = (const float*)d_in[5];
    const float* proj_w = (const float*)d_in[6];
    const float* proj_b = (const float*)d_in[7];
    const float* ln2_g  = (const float*)d_in[8];
    const float* ln2_b  = (const float*)d_in[9];
    const float* fc1_w  = (const float*)d_in[10];
    const float* fc1_b  = (const float*)d_in[11];
    const float* fc2_w  = (const float*)d_in[12];
    const float* fc2_b  = (const float*)d_in[13];
    float* out = (float*)d_out;

    char* ws = (char*)d_ws;
    float* xbuf = (float*)ws;                                        // 102,760,448 B
    unsigned short* qkbuf = (unsigned short*)(ws + 102760448);       // 102,760,448 B
    unsigned short* vTbuf = (unsigned short*)(ws + 205520896);       //  58,720,256 B
    unsigned short* wbase = (unsigned short*)(ws + 264241408);       //     786,432 B
    float* biasb = (float*)(ws + 264241408 + 786432);                //     401,408 B

    k_transpose_in<<<dim3(PSPAT / 32, 4, BB), dim3(32, 8), 0, stream>>>(x_in, xbuf);

    for (int l = 0; l < 2; l++) {
        unsigned short* wqT = wbase + (size_t)l * 196608;
        unsigned short* wpT = wqT + 49152;
        unsigned short* w1T = wpT + 16384;
        unsigned short* w2T = w1T + 65536;
        k_prep_w<<<dim3(12, 4), dim3(32, 8), 0, stream>>>(qkv_w + (size_t)l * 49152, wqT, 128, 384);
        k_prep_w<<<dim3(4, 4),  dim3(32, 8), 0, stream>>>(proj_w + (size_t)l * 16384, wpT, 128, 128);
        k_prep_w<<<dim3(16, 4), dim3(32, 8), 0, stream>>>(fc1_w + (size_t)l * 65536, w1T, 128, 512);
        k_prep_w<<<dim3(4, 16), dim3(32, 8), 0, stream>>>(fc2_w + (size_t)l * 65536, w2T, 512, 128);
    }
    k_prep_bias<<<dim3(112, 4, 2), 112, 0, stream>>>(rpb, biasb);

    for (int layer = 0; layer < 2; layer++) {
        unsigned short* wqT = wbase + (size_t)layer * 196608;
        unsigned short* wpT = wqT + 49152;
        unsigned short* w1T = wpT + 16384;
        unsigned short* w2T = w1T + 65536;
        int shifted = layer & 1;

        k_qkv<<<TOK_TOTAL / 64, 256, 0, stream>>>(xbuf, ln1_g + layer * 128, ln1_b + layer * 128,
                                                  wqT, qkv_b + layer * 384, qkbuf, vTbuf, shifted);
        k_attn_proj<<<BNW, 256, 0, stream>>>(qkbuf, vTbuf, biasb + (size_t)layer * 4 * 112 * 112,
                                             wpT, proj_b + layer * 128, xbuf, shifted);
        k_mlp<<<TOK_TOTAL / 128, 256, 0, stream>>>(xbuf, ln2_g + layer * 128, ln2_b + layer * 128,
                                                   w1T, fc1_b + layer * 512, w2T, fc2_b + layer * 128,
                                                   xbuf, out, layer == 1);
    }
}

// Round 18
// 692.287 us; speedup vs baseline: 1.5303x; 1.1187x over previous
//
#include <hip/hip_runtime.h>
#include <hip/hip_bf16.h>

typedef __attribute__((ext_vector_type(8))) short sv8_t;   // 8 bf16 (4 VGPR)
typedef __attribute__((ext_vector_type(4))) float fv4_t;   // MFMA accumulator
typedef __attribute__((ext_vector_type(4))) float f4ld_t;  // global float4 load

#define BB 8
#define TT 8
#define HH 56
#define WW2 56
#define NTOK 98
#define BNW 2048
#define PSPAT 25088
#define TOK_TOTAL 200704
#define VT_WSTRIDE 14336   // 128 * 112

#define SWZB(row, cb) ((cb) ^ ((((unsigned)(row)) & 7u) << 4))

__device__ __forceinline__ unsigned short f2bf(float f) {
    union { float f; unsigned u; } x; x.f = f;
    unsigned r = x.u + 0x7fffu + ((x.u >> 16) & 1u);
    return (unsigned short)(r >> 16);
}
__device__ __forceinline__ float bf2f(unsigned short u) {
    union { unsigned u; float f; } x; x.u = ((unsigned)u) << 16; return x.f;
}
// packed pair via v_cvt_pk_bf16_f32 (RNE, bit-identical to f2bf pair, 1 inst)
__device__ __forceinline__ unsigned packbf(float lo, float hi) {
    __hip_bfloat162 h = __float22bfloat162_rn(make_float2(lo, hi));
    union { __hip_bfloat162 h; unsigned u; } cv; cv.h = h; return cv.u;
}
__device__ __forceinline__ sv8_t lds_ld8(const unsigned short* p, int byteoff) {
    return *(const sv8_t*)((const char*)p + byteoff);
}
__device__ __forceinline__ void lds_st8(unsigned short* p, int byteoff, sv8_t v) {
    *(sv8_t*)((char*)p + byteoff) = v;
}
__device__ __forceinline__ void lds_st1(unsigned short* p, int byteoff, unsigned short v) {
    *(unsigned short*)((char*)p + byteoff) = v;
}
// GELU, sigmoid form: x*sigmoid(1.702x)
__device__ __forceinline__ float gelu_f(float v) {
    float e = __expf(-1.702f * v);
    return v * __builtin_amdgcn_rcpf(1.f + e);
}

// ---------------- transpose in: (B,C,P) f32 -> (B,P,C) bf16 ----------------
__global__ __launch_bounds__(256) void k_transpose_in(const float* __restrict__ in,
                                                      unsigned short* __restrict__ xbuf) {
    __shared__ float tile[32][33];
    int p0 = blockIdx.x * 32, c0 = blockIdx.y * 32, b = blockIdx.z;
    int pi = threadIdx.x, ci = threadIdx.y;
    const float* src = in + ((size_t)b * 128 + c0) * PSPAT + p0;
    for (int r = 0; r < 32; r += 8)
        tile[ci + r][pi] = src[(size_t)(ci + r) * PSPAT + pi];
    __syncthreads();
    unsigned short* dst = xbuf + ((size_t)b * PSPAT + p0) * 128 + c0;
    for (int r = 0; r < 32; r += 8)
        dst[(size_t)(ci + r) * 128 + pi] = f2bf(tile[pi][ci + r]);
}

// ---------------- weight prep: in f32 [K][N] -> out bf16 [N][K] ----------------
__global__ __launch_bounds__(256) void k_prep_w(const float* __restrict__ in,
                                                unsigned short* __restrict__ out,
                                                int K, int N) {
    __shared__ float tile[32][33];
    int n0 = blockIdx.x * 32, k0 = blockIdx.y * 32;
    int x = threadIdx.x, y = threadIdx.y;
    for (int r = 0; r < 32; r += 8)
        tile[y + r][x] = in[(size_t)(k0 + y + r) * N + n0 + x];
    __syncthreads();
    for (int r = 0; r < 32; r += 8)
        out[(size_t)(n0 + y + r) * K + k0 + x] = f2bf(tile[x][y + r]);
}

// ---------------- bias prep: biasb[layer][head][q row][k col] ----------------
__global__ void k_prep_bias(const float* __restrict__ rpb, float* __restrict__ biasb) {
    int col = threadIdx.x;   // 0..111 (k index)
    int row = blockIdx.x;    // 0..111 (q index)
    int head = blockIdx.y;   // 0..3
    int layer = blockIdx.z;
    int tn = min(row, 97), tm = min(col, 97);
    int itn = tn / 49, rn = tn - itn * 49, ihn = rn / 7, iwn = rn - ihn * 7;
    int itm = tm / 49, rm = tm - itm * 49, ihm = rm / 7, iwm = rm - ihm * 7;
    int dt = itn - itm + 1, dh = ihn - ihm + 6, dw = iwn - iwm + 6;
    float v = rpb[((size_t)layer * 507 + dt * 169 + dh * 13 + dw) * 4 + head];
    biasb[(((size_t)layer * 4 + head) * 112 + row) * 112 + col] = v;
}

// ---------------- fused LN1 + gather + qkv GEMM ----------------
__global__ __launch_bounds__(256) void k_qkv(const unsigned short* __restrict__ xb,
                                             const float* __restrict__ g,
                                             const float* __restrict__ be,
                                             const unsigned short* __restrict__ wT,  // [384][128]
                                             const float* __restrict__ bias,         // [384]
                                             unsigned short* __restrict__ qkbuf,
                                             unsigned short* __restrict__ vT,
                                             int shifted) {
    __shared__ unsigned short xt[64 * 128];
    int tid = threadIdx.x;
    int row0 = blockIdx.x * 64;
    {
        int r = tid >> 2, q = tid & 3;
        int wt = row0 + r;
        int win = wt / 98, n = wt - win * 98;
        int b_ = win >> 8, wrem = win & 255;
        int tw = wrem >> 6, hw = (wrem >> 3) & 7, ww = wrem & 7;
        int it = n / 49, r2 = n - it * 49, ih = r2 / 7, iw = r2 - ih * 7;
        int t = tw * 2 + it, h = hw * 7 + ih, w = ww * 7 + iw;
        if (shifted) {
            t += 1; if (t >= TT) t -= TT;
            h += 3; if (h >= HH) h -= HH;
            w += 3; if (w >= WW2) w -= WW2;
        }
        const unsigned short* src = xb + ((size_t)b_ * PSPAT + t * (HH * WW2) + h * WW2 + w) * 128 + q * 32;
        float v[32];
        float s = 0.f, sq = 0.f;
        #pragma unroll
        for (int i = 0; i < 4; i++) {
            sv8_t raw = *(const sv8_t*)(src + i * 8);
            #pragma unroll
            for (int e = 0; e < 8; e++) {
                float f = bf2f((unsigned short)raw[e]);
                v[i * 8 + e] = f; s += f; sq += f * f;
            }
        }
        s += __shfl_xor(s, 1); sq += __shfl_xor(sq, 1);
        s += __shfl_xor(s, 2); sq += __shfl_xor(sq, 2);
        float mu = s * (1.f / 128.f);
        float var = sq * (1.f / 128.f) - mu * mu;
        float rs = rsqrtf(var + 1e-5f);
        for (int c0 = 0; c0 < 32; c0 += 8) {
            float y[8];
            #pragma unroll
            for (int i = 0; i < 8; i++) {
                int c = q * 32 + c0 + i;
                y[i] = (v[c0 + i] - mu) * rs * g[c] + be[c];
            }
            union { unsigned u[4]; sv8_t s8; } pk;
            pk.u[0] = packbf(y[0], y[1]); pk.u[1] = packbf(y[2], y[3]);
            pk.u[2] = packbf(y[4], y[5]); pk.u[3] = packbf(y[6], y[7]);
            lds_st8(xt, r * 256 + SWZB(r, (q * 32 + c0) * 2), pk.s8);
        }
    }
    __syncthreads();
    int wv = tid >> 6, lane = tid & 63, l15 = lane & 15, lhi = lane >> 4;

    if (wv < 2) {
        // Q (wv0) or K (wv1), swapped: C[d][tok]; 8 d16-frags, packed 8B stores
        int nb = wv * 128;
        fv4_t acc[4][8];
        for (int m = 0; m < 4; m++) for (int f = 0; f < 8; f++) acc[m][f] = (fv4_t){0.f, 0.f, 0.f, 0.f};
        for (int kk = 0; kk < 4; kk++) {
            sv8_t x4[4];
            #pragma unroll
            for (int m = 0; m < 4; m++) {
                int ar = 16 * m + l15;
                x4[m] = lds_ld8(xt, ar * 256 + SWZB(ar, (kk * 32 + 8 * lhi) * 2));
            }
            #pragma unroll
            for (int f = 0; f < 8; f++) {
                sv8_t wf = *(const sv8_t*)(wT + (size_t)(nb + 16 * f + l15) * 128 + kk * 32 + 8 * lhi);
                #pragma unroll
                for (int m = 0; m < 4; m++)
                    acc[m][f] = __builtin_amdgcn_mfma_f32_16x16x32_bf16(wf, x4[m], acc[m][f], 0, 0, 0);
            }
        }
        float sc_ = (wv == 0) ? 0.17677669529663687f : 1.f;
        #pragma unroll
        for (int f = 0; f < 8; f++) {
            f4ld_t b4 = *(const f4ld_t*)(bias + nb + 16 * f + 4 * lhi);
            #pragma unroll
            for (int m = 0; m < 4; m++) {
                int row = row0 + 16 * m + l15;
                union { unsigned u[2]; uint2 u2; } pk;
                pk.u[0] = packbf((acc[m][f][0] + b4.x) * sc_, (acc[m][f][1] + b4.y) * sc_);
                pk.u[1] = packbf((acc[m][f][2] + b4.z) * sc_, (acc[m][f][3] + b4.w) * sc_);
                *(uint2*)(qkbuf + (size_t)row * 256 + nb + 16 * f + 4 * lhi) = pk.u2;
            }
        }
    } else {
        int d16base = (wv - 2) * 4;
        fv4_t acc[4][4];   // [m][f]
        for (int m = 0; m < 4; m++) for (int f = 0; f < 4; f++) acc[m][f] = (fv4_t){0.f, 0.f, 0.f, 0.f};
        for (int kk = 0; kk < 4; kk++) {
            sv8_t x4[4];
            #pragma unroll
            for (int m = 0; m < 4; m++) {
                int ar = 16 * m + l15;
                x4[m] = lds_ld8(xt, ar * 256 + SWZB(ar, (kk * 32 + 8 * lhi) * 2));
            }
            #pragma unroll
            for (int f = 0; f < 4; f++) {
                sv8_t wf = *(const sv8_t*)(wT + (size_t)(256 + (d16base + f) * 16 + l15) * 128 + kk * 32 + 8 * lhi);
                #pragma unroll
                for (int m = 0; m < 4; m++)
                    acc[m][f] = __builtin_amdgcn_mfma_f32_16x16x32_bf16(wf, x4[m], acc[m][f], 0, 0, 0);
            }
        }
        #pragma unroll
        for (int f = 0; f < 4; f++) {
            f4ld_t b4 = *(const f4ld_t*)(bias + 256 + (d16base + f) * 16 + 4 * lhi);
            #pragma unroll
            for (int r = 0; r < 4; r++) {
                int d = (d16base + f) * 16 + 4 * lhi + r;
                #pragma unroll
                for (int m = 0; m < 4; m++) {
                    int row = row0 + 16 * m + l15;
                    int win = row / 98, tok = row - win * 98;
                    vT[(size_t)win * VT_WSTRIDE + d * 112 + tok] = f2bf(acc[m][f][r] + b4[r]);
                }
            }
        }
    }
}

// ---------------- attention core + proj, one block per window ----------------
// Swapped QK^T, in-lane softmax; P redistributed in-register via shfl+select.
__global__ __launch_bounds__(256, 3) void k_attn_proj(const unsigned short* __restrict__ qk,
                                                      const unsigned short* __restrict__ vT,
                                                      const float* __restrict__ biasb,  // [4][q 112][k 112]
                                                      const unsigned short* __restrict__ pwT, // [128][128]
                                                      const float* __restrict__ pb,
                                                      unsigned short* __restrict__ xbuf,
                                                      int shifted) {
    __shared__ unsigned short ot[112 * 128];
    __shared__ int lablut[112];
    int win = blockIdx.x;
    int tid = threadIdx.x;
    int wv = tid >> 6, lane = tid & 63;
    int head = wv;
    int l15 = lane & 15, lhi = lane >> 4;
    int wrem = win & 255;
    int tw = wrem >> 6, hw = (wrem >> 3) & 7, ww = wrem & 7;

    for (int m = tid; m < 112; m += 256) {
        int t0 = min(m, 97);
        int it = t0 / 49, r2 = t0 - it * 49, ih = r2 / 7, iw = r2 - ih * 7;
        int lab = 0;
        if (shifted) {
            int t = tw * 2 + it, h = hw * 7 + ih, w = ww * 7 + iw;
            int ct = (t < TT - 2) ? 0 : ((t < TT - 1) ? 1 : 2);
            int ch = (h < HH - 7) ? 0 : ((h < HH - 3) ? 1 : 2);
            int cw = (w < WW2 - 7) ? 0 : ((w < WW2 - 3) ? 1 : 2);
            lab = ct * 9 + ch * 3 + cw;
        }
        lablut[m] = lab;
    }
    __syncthreads();

    size_t rowbase = (size_t)win * 98;
    sv8_t kf[7];
    #pragma unroll
    for (int j = 0; j < 7; j++) {
        int tok = min(16 * j + l15, 97);
        kf[j] = *(const sv8_t*)(qk + (rowbase + tok) * 256 + 128 + head * 32 + 8 * lhi);
    }
    const unsigned short* vbase = vT + (size_t)win * VT_WSTRIDE + (head * 32) * 112;
    sv8_t vf[4][2];
    #pragma unroll
    for (int kk = 0; kk < 4; kk++)
        #pragma unroll
        for (int j = 0; j < 2; j++)
            vf[kk][j] = *(const sv8_t*)(vbase + (16 * j + l15) * 112 + kk * 32 + 8 * lhi);

    int klab[7];
    if (shifted) {
        #pragma unroll
        for (int j = 0; j < 7; j++) {
            int kb = 16 * j + 4 * lhi;
            klab[j] = lablut[kb] | (lablut[kb + 1] << 8) | (lablut[kb + 2] << 16) | (lablut[kb + 3] << 24);
        }
    }

    int src0 = ((lane & 16) << 1) + l15;   // 32*(lhi&1) + l15
    int src1 = src0 + 16;
    bool jlo = (lane < 32);

    sv8_t qa_c = *(const sv8_t*)(qk + (rowbase + l15) * 256 + head * 32 + 8 * lhi);

    for (int ms = 0; ms < 7; ms++) {
        sv8_t qa_n = qa_c;
        if (ms < 6) {
            int qtok = min(16 * (ms + 1) + l15, 97);
            qa_n = *(const sv8_t*)(qk + (rowbase + qtok) * 256 + head * 32 + 8 * lhi);
        }
        int ql = min(16 * ms + l15, 97);
        int labq = shifted ? lablut[ql] : 0;
        const float* bq = biasb + ((size_t)head * 112 + ql) * 112;
        f4ld_t bv[7];
        #pragma unroll
        for (int j = 0; j < 7; j++)
            bv[j] = *(const f4ld_t*)(bq + 16 * j + 4 * lhi);
        fv4_t sc[7];
        __builtin_amdgcn_s_setprio(1);
        #pragma unroll
        for (int j = 0; j < 7; j++) {
            fv4_t z = {0.f, 0.f, 0.f, 0.f};
            sc[j] = __builtin_amdgcn_mfma_f32_16x16x32_bf16(kf[j], qa_c, z, 0, 0, 0);
        }
        __builtin_amdgcn_s_setprio(0);
        float mx = -1e30f;
        #pragma unroll
        for (int j = 0; j < 7; j++) {
            #pragma unroll
            for (int r = 0; r < 4; r++) {
                float s = sc[j][r] + bv[j][r];
                if (shifted && (((klab[j] >> (8 * r)) & 255) != labq)) s -= 100.f;
                if (16 * j + 4 * lhi + r >= 98) s = -1e30f;
                sc[j][r] = s;
                mx = fmaxf(mx, s);
            }
        }
        mx = fmaxf(mx, __shfl_xor(mx, 16));
        mx = fmaxf(mx, __shfl_xor(mx, 32));
        float sm = 0.f;
        #pragma unroll
        for (int j = 0; j < 7; j++)
            #pragma unroll
            for (int r = 0; r < 4; r++) {
                float p = __expf(sc[j][r] - mx);
                sc[j][r] = p;
                sm += p;
            }
        sm += __shfl_xor(sm, 16);
        sm += __shfl_xor(sm, 32);
        float inv = __builtin_amdgcn_rcpf(sm);
        int pkl[8], pkh[8];
        #pragma unroll
        for (int j = 0; j < 7; j++) {
            pkl[j] = (int)packbf(sc[j][0] * inv, sc[j][1] * inv);
            pkh[j] = (int)packbf(sc[j][2] * inv, sc[j][3] * inv);
        }
        pkl[7] = 0; pkh[7] = 0;
        fv4_t oacc[2] = {{0.f, 0.f, 0.f, 0.f}, {0.f, 0.f, 0.f, 0.f}};
        #pragma unroll
        for (int kk = 0; kk < 4; kk++) {
            int e_lo0 = __shfl(pkl[2 * kk], src0), o_lo0 = __shfl(pkl[2 * kk + 1], src0);
            int e_hi0 = __shfl(pkh[2 * kk], src0), o_hi0 = __shfl(pkh[2 * kk + 1], src0);
            int e_lo1 = __shfl(pkl[2 * kk], src1), o_lo1 = __shfl(pkl[2 * kk + 1], src1);
            int e_hi1 = __shfl(pkh[2 * kk], src1), o_hi1 = __shfl(pkh[2 * kk + 1], src1);
            union { int u[4]; sv8_t s8; } pa;
            pa.u[0] = jlo ? e_lo0 : o_lo0;
            pa.u[1] = jlo ? e_hi0 : o_hi0;
            pa.u[2] = jlo ? e_lo1 : o_lo1;
            pa.u[3] = jlo ? e_hi1 : o_hi1;
            __builtin_amdgcn_s_setprio(1);
            #pragma unroll
            for (int j = 0; j < 2; j++)
                oacc[j] = __builtin_amdgcn_mfma_f32_16x16x32_bf16(pa.s8, vf[kk][j], oacc[j], 0, 0, 0);
            __builtin_amdgcn_s_setprio(0);
        }
        #pragma unroll
        for (int r = 0; r < 4; r++) {
            int orow = 16 * ms + 4 * lhi + r;
            #pragma unroll
            for (int j = 0; j < 2; j++) {
                int ocol = head * 32 + 16 * j + l15;
                float v = (orow < 98) ? oacc[j][r] : 0.f;
                lds_st1(ot, orow * 256 + SWZB(orow, ocol * 2), f2bf(v));
            }
        }
        qa_c = qa_n;
    }
    __syncthreads();

    {
        int nb = wv * 32;
        fv4_t acc[7][2];
        for (int m = 0; m < 7; m++) for (int j = 0; j < 2; j++) acc[m][j] = (fv4_t){0.f, 0.f, 0.f, 0.f};
        for (int kk = 0; kk < 4; kk++) {
            sv8_t b[2];
            #pragma unroll
            for (int j = 0; j < 2; j++)
                b[j] = *(const sv8_t*)(pwT + (size_t)(nb + 16 * j + l15) * 128 + kk * 32 + 8 * lhi);
            __builtin_amdgcn_s_setprio(1);
            #pragma unroll
            for (int m = 0; m < 7; m++) {
                int ar = 16 * m + l15;
                sv8_t a = lds_ld8(ot, ar * 256 + SWZB(ar, (kk * 32 + 8 * lhi) * 2));
                #pragma unroll
                for (int j = 0; j < 2; j++)
                    acc[m][j] = __builtin_amdgcn_mfma_f32_16x16x32_bf16(a, b[j], acc[m][j], 0, 0, 0);
            }
            __builtin_amdgcn_s_setprio(0);
        }
        int b_ = win >> 8;
        for (int m = 0; m < 7; m++)
            #pragma unroll
            for (int r = 0; r < 4; r++) {
                int row = 16 * m + lhi * 4 + r;
                if (row < 98) {
                    int it = row / 49, r2 = row - it * 49, ih = r2 / 7, iw = r2 - ih * 7;
                    int t = tw * 2 + it, h = hw * 7 + ih, w = ww * 7 + iw;
                    if (shifted) {
                        t += 1; if (t >= TT) t -= TT;
                        h += 3; if (h >= HH) h -= HH;
                        w += 3; if (w >= WW2) w -= WW2;
                    }
                    unsigned short* xp = xbuf + ((size_t)b_ * PSPAT + t * (HH * WW2) + h * WW2 + w) * 128 + nb;
                    #pragma unroll
                    for (int j = 0; j < 2; j++) {
                        int c = 16 * j + l15;
                        float old = bf2f(xp[c]);
                        xp[c] = f2bf(old + acc[m][j][r] + pb[nb + c]);
                    }
                }
            }
    }
}

// ---------------- fused LN2 + fc1 + GELU + fc2 + residual (+final transpose) ----
// 48 KB LDS (A 16 KB U-half + Bst 32 KB) -> 3 blocks/CU; xt staged in Bst at LN.
#define LOAD_CHUNK(c, R)                                                                   \
    if ((c) < 16) {                                                                        \
        if (((c) & 1) == 0) {                                                              \
            _Pragma("unroll")                                                              \
            for (int i_ = 0; i_ < 4; i_++)                                                 \
                R[i_] = *(const sv8_t*)(w1T + (size_t)(((c) >> 2) * 128 + (((c) >> 1) & 1) * 64 + i_ * 16 + r1) * 128 + (c1 >> 1)); \
        } else {                                                                           \
            _Pragma("unroll")                                                              \
            for (int i_ = 0; i_ < 4; i_++)                                                 \
                R[i_] = *(const sv8_t*)(w2T + (size_t)(i_ * 32 + r2) * 512 + ((c) >> 2) * 128 + (((c) >> 1) & 1) * 64 + (c2 >> 1)); \
        }                                                                                  \
    }
#define WRITE_CHUNK(c, R)                                                                  \
    if ((c) < 16) {                                                                        \
        unsigned short* bst_ = Bst[(c)&1];                                                 \
        if (((c) & 1) == 0) {                                                              \
            _Pragma("unroll")                                                              \
            for (int i_ = 0; i_ < 4; i_++)                                                 \
                lds_st8(bst_, (i_ * 16 + r1) * 256 + SWZB(i_ * 16 + r1, c1), R[i_]);       \
        } else {                                                                           \
            _Pragma("unroll")                                                              \
            for (int i_ = 0; i_ < 4; i_++)                                                 \
                lds_st8(bst_, (i_ * 32 + r2) * 128 + SWZB(i_ * 32 + r2, c2), R[i_]);       \
        }                                                                                  \
    }

__global__ __launch_bounds__(256, 3) void k_mlp(const unsigned short* __restrict__ xin,
                                                const float* __restrict__ g,
                                                const float* __restrict__ be,
                                                const unsigned short* __restrict__ w1T,  // [512][128]
                                                const float* __restrict__ b1p,
                                                const unsigned short* __restrict__ w2T,  // [128][512]
                                                const float* __restrict__ b2p,
                                                unsigned short* __restrict__ xbuf,
                                                float* __restrict__ outp,
                                                int final_layer) {
    __shared__ unsigned short A[4][32 * 64];    // 16 KB: per-wave U half
    __shared__ unsigned short Bst[2][8192];     // 32 KB: ping-pong chunks; xt during LN
    int tid = threadIdx.x;
    int wv = tid >> 6, lane = tid & 63, l15 = lane & 15, lhi = lane >> 4;
    unsigned short* uw = A[wv];
    unsigned short* xts = &Bst[0][0];
    int tok0 = blockIdx.x * 128 + wv * 32;

    int r1 = tid >> 4, c1 = (tid & 15) * 16;   // w1 chunk coords (64x128 elems)
    int r2 = tid >> 3, c2 = (tid & 7) * 16;    // w2 chunk coords (128x64 elems)

    sv8_t wA[4], wB[4];
    LOAD_CHUNK(0, wA)                          // hidden under LN

    // ---- LN (xt staged in Bst; wave-private rows wv*32..+31)
    #pragma unroll
    for (int tf = 0; tf < 2; tf++) {
        int lrow = 16 * tf + l15;
        int grow = wv * 32 + lrow;
        const unsigned short* src = xin + (size_t)(tok0 + lrow) * 128 + lhi * 32;
        float v[32];
        float s = 0.f, sq = 0.f;
        #pragma unroll
        for (int i = 0; i < 4; i++) {
            sv8_t raw = *(const sv8_t*)(src + i * 8);
            #pragma unroll
            for (int e = 0; e < 8; e++) {
                float f = bf2f((unsigned short)raw[e]);
                v[i * 8 + e] = f; s += f; sq += f * f;
            }
        }
        s += __shfl_xor(s, 16); sq += __shfl_xor(sq, 16);
        s += __shfl_xor(s, 32); sq += __shfl_xor(sq, 32);
        float mu = s * (1.f / 128.f);
        float var = sq * (1.f / 128.f) - mu * mu;
        float rs = rsqrtf(var + 1e-5f);
        #pragma unroll
        for (int j = 0; j < 4; j++) {
            int c0 = lhi * 32 + 8 * j;
            f4ld_t g0 = *(const f4ld_t*)(g + c0);
            f4ld_t g1 = *(const f4ld_t*)(g + c0 + 4);
            f4ld_t b0 = *(const f4ld_t*)(be + c0);
            f4ld_t b1 = *(const f4ld_t*)(be + c0 + 4);
            float y0 = (v[8 * j + 0] - mu) * rs * g0.x + b0.x;
            float y1 = (v[8 * j + 1] - mu) * rs * g0.y + b0.y;
            float y2 = (v[8 * j + 2] - mu) * rs * g0.z + b0.z;
            float y3 = (v[8 * j + 3] - mu) * rs * g0.w + b0.w;
            float y4 = (v[8 * j + 4] - mu) * rs * g1.x + b1.x;
            float y5 = (v[8 * j + 5] - mu) * rs * g1.y + b1.y;
            float y6 = (v[8 * j + 6] - mu) * rs * g1.z + b1.z;
            float y7 = (v[8 * j + 7] - mu) * rs * g1.w + b1.w;
            union { unsigned u[4]; sv8_t s8; } pk;
            pk.u[0] = packbf(y0, y1); pk.u[1] = packbf(y2, y3);
            pk.u[2] = packbf(y4, y5); pk.u[3] = packbf(y6, y7);
            lds_st8(xts, grow * 256 + SWZB(grow, 64 * lhi + 16 * j), pk.s8);
        }
    }
    sv8_t xf[2][4];
    #pragma unroll
    for (int tf = 0; tf < 2; tf++)
        #pragma unroll
        for (int kk = 0; kk < 4; kk++) {
            int grow = wv * 32 + 16 * tf + l15;
            xf[tf][kk] = lds_ld8(xts, grow * 256 + SWZB(grow, 64 * kk + 16 * lhi));
        }

    fv4_t acc2[8][2];
    #pragma unroll
    for (int cg = 0; cg < 8; cg++)
        #pragma unroll
        for (int tf = 0; tf < 2; tf++) acc2[cg][tf] = (fv4_t){0.f, 0.f, 0.f, 0.f};

    __syncthreads();
    WRITE_CHUNK(0, wA)
    LOAD_CHUNK(1, wB)
    __syncthreads();

    #pragma unroll
    for (int q = 0; q < 4; q++) {
        // ---- phase c=4q+0: fc1 fg 0..3 from Bst[0] (w1 h0) -> U half
        {
            const int c = 4 * q;
            WRITE_CHUNK(c + 1, wB)
            LOAD_CHUNK(c + 2, wA)
            #pragma unroll
            for (int f = 0; f < 4; f++) {
                sv8_t wf[4];
                #pragma unroll
                for (int kk = 0; kk < 4; kk++) {
                    int wrow = 16 * f + l15;
                    wf[kk] = lds_ld8(Bst[0], wrow * 256 + SWZB(wrow, kk * 64 + 16 * lhi));
                }
                fv4_t a1[2] = {{0.f, 0.f, 0.f, 0.f}, {0.f, 0.f, 0.f, 0.f}};
                __builtin_amdgcn_s_setprio(1);
                #pragma unroll
                for (int kk = 0; kk < 4; kk++) {
                    a1[0] = __builtin_amdgcn_mfma_f32_16x16x32_bf16(wf[kk], xf[0][kk], a1[0], 0, 0, 0);
                    a1[1] = __builtin_amdgcn_mfma_f32_16x16x32_bf16(wf[kk], xf[1][kk], a1[1], 0, 0, 0);
                }
                __builtin_amdgcn_s_setprio(0);
                f4ld_t b4 = *(const f4ld_t*)(b1p + q * 128 + 16 * f + 4 * lhi);
                #pragma unroll
                for (int tf = 0; tf < 2; tf++) {
                    float g0 = gelu_f(a1[tf][0] + b4.x);
                    float g1 = gelu_f(a1[tf][1] + b4.y);
                    float g2 = gelu_f(a1[tf][2] + b4.z);
                    float g3 = gelu_f(a1[tf][3] + b4.w);
                    union { unsigned u[2]; uint2 u2; } pk;
                    pk.u[0] = packbf(g0, g1); pk.u[1] = packbf(g2, g3);
                    int lrow = 16 * tf + l15;
                    *(uint2*)((char*)uw + lrow * 128 + SWZB(lrow, 32 * f + 8 * lhi)) = pk.u2;
                }
            }
            __syncthreads();
        }
        // ---- phase c=4q+1: fc2 (K = U cols q*128..+63) from Bst[1] (w2 h0)
        {
            const int c = 4 * q + 1;
            WRITE_CHUNK(c + 1, wA)
            LOAD_CHUNK(c + 2, wB)
            #pragma unroll
            for (int kql = 0; kql < 2; kql++) {
                sv8_t uf[2];
                #pragma unroll
                for (int tf = 0; tf < 2; tf++) {
                    int lrow = 16 * tf + l15;
                    uf[tf] = lds_ld8(uw, lrow * 128 + SWZB(lrow, 64 * kql + 16 * lhi));
                }
                #pragma unroll
                for (int cb = 0; cb < 2; cb++) {
                    sv8_t w2f[4];
                    #pragma unroll
                    for (int cc = 0; cc < 4; cc++) {
                        int wrow = 16 * (4 * cb + cc) + l15;
                        w2f[cc] = lds_ld8(Bst[1], wrow * 128 + SWZB(wrow, kql * 64 + 16 * lhi));
                    }
                    __builtin_amdgcn_s_setprio(1);
                    #pragma unroll
                    for (int cc = 0; cc < 4; cc++) {
                        int cg = 4 * cb + cc;
                        acc2[cg][0] = __builtin_amdgcn_mfma_f32_16x16x32_bf16(w2f[cc], uf[0], acc2[cg][0], 0, 0, 0);
                        acc2[cg][1] = __builtin_amdgcn_mfma_f32_16x16x32_bf16(w2f[cc], uf[1], acc2[cg][1], 0, 0, 0);
                    }
                    __builtin_amdgcn_s_setprio(0);
                }
            }
            __syncthreads();
        }
        // ---- phase c=4q+2: fc1 fg 4..7 from Bst[0] (w1 h1) -> same U half buffer
        {
            const int c = 4 * q + 2;
            WRITE_CHUNK(c + 1, wB)
            LOAD_CHUNK(c + 2, wA)
            #pragma unroll
            for (int f = 0; f < 4; f++) {
                sv8_t wf[4];
                #pragma unroll
                for (int kk = 0; kk < 4; kk++) {
                    int wrow = 16 * f + l15;
                    wf[kk] = lds_ld8(Bst[0], wrow * 256 + SWZB(wrow, kk * 64 + 16 * lhi));
                }
                fv4_t a1[2] = {{0.f, 0.f, 0.f, 0.f}, {0.f, 0.f, 0.f, 0.f}};
                __builtin_amdgcn_s_setprio(1);
                #pragma unroll
                for (int kk = 0; kk < 4; kk++) {
                    a1[0] = __builtin_amdgcn_mfma_f32_16x16x32_bf16(wf[kk], xf[0][kk], a1[0], 0, 0, 0);
                    a1[1] = __builtin_amdgcn_mfma_f32_16x16x32_bf16(wf[kk], xf[1][kk], a1[1], 0, 0, 0);
                }
                __builtin_amdgcn_s_setprio(0);
                f4ld_t b4 = *(const f4ld_t*)(b1p + q * 128 + 64 + 16 * f + 4 * lhi);
                #pragma unroll
                for (int tf = 0; tf < 2; tf++) {
                    float g0 = gelu_f(a1[tf][0] + b4.x);
                    float g1 = gelu_f(a1[tf][1] + b4.y);
                    float g2 = gelu_f(a1[tf][2] + b4.z);
                    float g3 = gelu_f(a1[tf][3] + b4.w);
                    union { unsigned u[2]; uint2 u2; } pk;
                    pk.u[0] = packbf(g0, g1); pk.u[1] = packbf(g2, g3);
                    int lrow = 16 * tf + l15;
                    *(uint2*)((char*)uw + lrow * 128 + SWZB(lrow, 32 * f + 8 * lhi)) = pk.u2;
                }
            }
            __syncthreads();
        }
        // ---- phase c=4q+3: fc2 (K = U cols q*128+64..+127) from Bst[1] (w2 h1)
        {
            const int c = 4 * q + 3;
            WRITE_CHUNK(c + 1, wA)
            LOAD_CHUNK(c + 2, wB)
            #pragma unroll
            for (int kql = 0; kql < 2; kql++) {
                sv8_t uf[2];
                #pragma unroll
                for (int tf = 0; tf < 2; tf++) {
                    int lrow = 16 * tf + l15;
                    uf[tf] = lds_ld8(uw, lrow * 128 + SWZB(lrow, 64 * kql + 16 * lhi));
                }
                #pragma unroll
                for (int cb = 0; cb < 2; cb++) {
                    sv8_t w2f[4];
                    #pragma unroll
                    for (int cc = 0; cc < 4; cc++) {
                        int wrow = 16 * (4 * cb + cc) + l15;
                        w2f[cc] = lds_ld8(Bst[1], wrow * 128 + SWZB(wrow, kql * 64 + 16 * lhi));
                    }
                    __builtin_amdgcn_s_setprio(1);
                    #pragma unroll
                    for (int cc = 0; cc < 4; cc++) {
                        int cg = 4 * cb + cc;
                        acc2[cg][0] = __builtin_amdgcn_mfma_f32_16x16x32_bf16(w2f[cc], uf[0], acc2[cg][0], 0, 0, 0);
                        acc2[cg][1] = __builtin_amdgcn_mfma_f32_16x16x32_bf16(w2f[cc], uf[1], acc2[cg][1], 0, 0, 0);
                    }
                    __builtin_amdgcn_s_setprio(0);
                }
            }
            __syncthreads();
        }
    }
    // ---- epilogue
    if (!final_layer) {
        #pragma unroll
        for (int tf = 0; tf < 2; tf++) {
            int row = tok0 + 16 * tf + l15;
            #pragma unroll
            for (int cg = 0; cg < 8; cg++) {
                int c0 = 16 * cg + 4 * lhi;
                f4ld_t b4 = *(const f4ld_t*)(b2p + c0);
                unsigned short* xp = xbuf + (size_t)row * 128 + c0;
                uint2 oldp = *(uint2*)xp;
                float o0 = bf2f((unsigned short)(oldp.x & 0xffff)) + acc2[cg][tf][0] + b4.x;
                float o1 = bf2f((unsigned short)(oldp.x >> 16))    + acc2[cg][tf][1] + b4.y;
                float o2 = bf2f((unsigned short)(oldp.y & 0xffff)) + acc2[cg][tf][2] + b4.z;
                float o3 = bf2f((unsigned short)(oldp.y >> 16))    + acc2[cg][tf][3] + b4.w;
                uint2 np;
                np.x = packbf(o0, o1); np.y = packbf(o2, o3);
                *(uint2*)xp = np;
            }
        }
    } else {
        // final layer: out[b][c][p] = bf16 residual + mlp, f32 write (fuses transpose)
        #pragma unroll
        for (int tf = 0; tf < 2; tf++) {
            int row = tok0 + 16 * tf + l15;
            int b_ = row / PSPAT, p = row - b_ * PSPAT;
            float* ob = outp + (size_t)b_ * 128 * PSPAT + p;
            #pragma unroll
            for (int cg = 0; cg < 8; cg++) {
                int c0 = 16 * cg + 4 * lhi;
                f4ld_t b4 = *(const f4ld_t*)(b2p + c0);
                const unsigned short* xp = xbuf + (size_t)row * 128 + c0;
                uint2 oldp = *(const uint2*)xp;
                float o0 = bf2f((unsigned short)(oldp.x & 0xffff)) + acc2[cg][tf][0] + b4.x;
                float o1 = bf2f((unsigned short)(oldp.x >> 16))    + acc2[cg][tf][1] + b4.y;
                float o2 = bf2f((unsigned short)(oldp.y & 0xffff)) + acc2[cg][tf][2] + b4.z;
                float o3 = bf2f((unsigned short)(oldp.y >> 16))    + acc2[cg][tf][3] + b4.w;
                ob[(size_t)(c0 + 0) * PSPAT] = o0;
                ob[(size_t)(c0 + 1) * PSPAT] = o1;
                ob[(size_t)(c0 + 2) * PSPAT] = o2;
                ob[(size_t)(c0 + 3) * PSPAT] = o3;
            }
        }
    }
}

extern "C" void kernel_launch(void* const* d_in, const int* in_sizes, int n_in,
                              void* d_out, int out_size, void* d_ws, size_t ws_size,
                              hipStream_t stream) {
    const float* x_in   = (const float*)d_in[0];
    const float* ln1_g  = (const float*)d_in[1];
    const float* ln1_b  = (const float*)d_in[2];
    const float* qkv_w  = (const float*)d_in[3];
    const float* qkv_b  = (const float*)d_in[4];
    const float* rpb    = (const float*)d_in[5];
    const float* proj_w = (const float*)d_in[6];
    const float* proj_b = (const float*)d_in[7];
    const float* ln2_g  = (const float*)d_in[8];
    const float* ln2_b  = (const float*)d_in[9];
    const float* fc1_w  = (const float*)d_in[10];
    const float* fc1_b  = (const float*)d_in[11];
    const float* fc2_w  = (const float*)d_in[12];
    const float* fc2_b  = (const float*)d_in[13];
    float* out = (float*)d_out;

    char* ws = (char*)d_ws;
    unsigned short* xbufb = (unsigned short*)ws;                     //  51,380,224 B (bf16)
    unsigned short* qkbuf = (unsigned short*)(ws + 51380224);        // 102,760,448 B
    unsigned short* vTbuf = (unsigned short*)(ws + 154140672);       //  58,720,256 B
    unsigned short* wbase = (unsigned short*)(ws + 212860928);       //     786,432 B
    float* biasb = (float*)(ws + 212860928 + 786432);                //     401,408 B

    k_transpose_in<<<dim3(PSPAT / 32, 4, BB), dim3(32, 8), 0, stream>>>(x_in, xbufb);

    for (int l = 0; l < 2; l++) {
        unsigned short* wqT = wbase + (size_t)l * 196608;
        unsigned short* wpT = wqT + 49152;
        unsigned short* w1T = wpT + 16384;
        unsigned short* w2T = w1T + 65536;
        k_prep_w<<<dim3(12, 4), dim3(32, 8), 0, stream>>>(qkv_w + (size_t)l * 49152, wqT, 128, 384);
        k_prep_w<<<dim3(4, 4),  dim3(32, 8), 0, stream>>>(proj_w + (size_t)l * 16384, wpT, 128, 128);
        k_prep_w<<<dim3(16, 4), dim3(32, 8), 0, stream>>>(fc1_w + (size_t)l * 65536, w1T, 128, 512);
        k_prep_w<<<dim3(4, 16), dim3(32, 8), 0, stream>>>(fc2_w + (size_t)l * 65536, w2T, 512, 128);
    }
    k_prep_bias<<<dim3(112, 4, 2), 112, 0, stream>>>(rpb, biasb);

    for (int layer = 0; layer < 2; layer++) {
        unsigned short* wqT = wbase + (size_t)layer * 196608;
        unsigned short* wpT = wqT + 49152;
        unsigned short* w1T = wpT + 16384;
        unsigned short* w2T = w1T + 65536;
        int shifted = layer & 1;

        k_qkv<<<TOK_TOTAL / 64, 256, 0, stream>>>(xbufb, ln1_g + layer * 128, ln1_b + layer * 128,
                                                  wqT, qkv_b + layer * 384, qkbuf, vTbuf, shifted);
        k_attn_proj<<<BNW, 256, 0, stream>>>(qkbuf, vTbuf, biasb + (size_t)layer * 4 * 112 * 112,
                                             wpT, proj_b + layer * 128, xbufb, shifted);
        k_mlp<<<TOK_TOTAL / 128, 256, 0, stream>>>(xbufb, ln2_g + layer * 128, ln2_b + layer * 128,
                                                   w1T, fc1_b + layer * 512, w2T, fc2_b + layer * 128,
                                                   xbufb, out, layer == 1);
    }
}

// Round 19
// 662.064 us; speedup vs baseline: 1.6002x; 1.0456x over previous
//
#include <hip/hip_runtime.h>
#include <hip/hip_bf16.h>

typedef __attribute__((ext_vector_type(8))) short sv8_t;   // 8 bf16 (4 VGPR)
typedef __attribute__((ext_vector_type(4))) float fv4_t;   // MFMA accumulator
typedef __attribute__((ext_vector_type(4))) float f4ld_t;  // global float4 load

#define BB 8
#define TT 8
#define HH 56
#define WW2 56
#define NTOK 98
#define BNW 2048
#define PSPAT 25088
#define TOK_TOTAL 200704
#define VT_WSTRIDE 14336   // 128 * 112

#define SWZB(row, cb) ((cb) ^ ((((unsigned)(row)) & 7u) << 4))

__device__ __forceinline__ unsigned short f2bf(float f) {
    union { float f; unsigned u; } x; x.f = f;
    unsigned r = x.u + 0x7fffu + ((x.u >> 16) & 1u);
    return (unsigned short)(r >> 16);
}
__device__ __forceinline__ float bf2f(unsigned short u) {
    union { unsigned u; float f; } x; x.u = ((unsigned)u) << 16; return x.f;
}
// packed pair via v_cvt_pk_bf16_f32 (RNE, bit-identical to f2bf pair, 1 inst)
__device__ __forceinline__ unsigned packbf(float lo, float hi) {
    __hip_bfloat162 h = __float22bfloat162_rn(make_float2(lo, hi));
    union { __hip_bfloat162 h; unsigned u; } cv; cv.h = h; return cv.u;
}
__device__ __forceinline__ sv8_t lds_ld8(const unsigned short* p, int byteoff) {
    return *(const sv8_t*)((const char*)p + byteoff);
}
__device__ __forceinline__ void lds_st8(unsigned short* p, int byteoff, sv8_t v) {
    *(sv8_t*)((char*)p + byteoff) = v;
}
__device__ __forceinline__ void lds_st1(unsigned short* p, int byteoff, unsigned short v) {
    *(unsigned short*)((char*)p + byteoff) = v;
}
// GELU, sigmoid form: x*sigmoid(1.702x)
__device__ __forceinline__ float gelu_f(float v) {
    float e = __expf(-1.702f * v);
    return v * __builtin_amdgcn_rcpf(1.f + e);
}

// ---------------- transpose in: (B,C,P) f32 -> (B,P,C) bf16 ----------------
__global__ __launch_bounds__(256) void k_transpose_in(const float* __restrict__ in,
                                                      unsigned short* __restrict__ xbuf) {
    __shared__ float tile[32][33];
    int p0 = blockIdx.x * 32, c0 = blockIdx.y * 32, b = blockIdx.z;
    int pi = threadIdx.x, ci = threadIdx.y;
    const float* src = in + ((size_t)b * 128 + c0) * PSPAT + p0;
    for (int r = 0; r < 32; r += 8)
        tile[ci + r][pi] = src[(size_t)(ci + r) * PSPAT + pi];
    __syncthreads();
    unsigned short* dst = xbuf + ((size_t)b * PSPAT + p0) * 128 + c0;
    for (int r = 0; r < 32; r += 8)
        dst[(size_t)(ci + r) * 128 + pi] = f2bf(tile[pi][ci + r]);
}

// ---------------- weight prep: in f32 [K][N] -> out bf16 [N][K] ----------------
__global__ __launch_bounds__(256) void k_prep_w(const float* __restrict__ in,
                                                unsigned short* __restrict__ out,
                                                int K, int N) {
    __shared__ float tile[32][33];
    int n0 = blockIdx.x * 32, k0 = blockIdx.y * 32;
    int x = threadIdx.x, y = threadIdx.y;
    for (int r = 0; r < 32; r += 8)
        tile[y + r][x] = in[(size_t)(k0 + y + r) * N + n0 + x];
    __syncthreads();
    for (int r = 0; r < 32; r += 8)
        out[(size_t)(n0 + y + r) * K + k0 + x] = f2bf(tile[x][y + r]);
}

// ---------------- bias prep: biasb[layer][head][q row][k col] ----------------
__global__ void k_prep_bias(const float* __restrict__ rpb, float* __restrict__ biasb) {
    int col = threadIdx.x;   // 0..111 (k index)
    int row = blockIdx.x;    // 0..111 (q index)
    int head = blockIdx.y;   // 0..3
    int layer = blockIdx.z;
    int tn = min(row, 97), tm = min(col, 97);
    int itn = tn / 49, rn = tn - itn * 49, ihn = rn / 7, iwn = rn - ihn * 7;
    int itm = tm / 49, rm = tm - itm * 49, ihm = rm / 7, iwm = rm - ihm * 7;
    int dt = itn - itm + 1, dh = ihn - ihm + 6, dw = iwn - iwm + 6;
    float v = rpb[((size_t)layer * 507 + dt * 169 + dh * 13 + dw) * 4 + head];
    biasb[(((size_t)layer * 4 + head) * 112 + row) * 112 + col] = v;
}

// ---------------- fused LN1 + gather + qkv GEMM ----------------
__global__ __launch_bounds__(256) void k_qkv(const unsigned short* __restrict__ xb,
                                             const float* __restrict__ g,
                                             const float* __restrict__ be,
                                             const unsigned short* __restrict__ wT,  // [384][128]
                                             const float* __restrict__ bias,         // [384]
                                             unsigned short* __restrict__ qkbuf,
                                             unsigned short* __restrict__ vT,
                                             int shifted) {
    __shared__ unsigned short xt[64 * 128];
    int tid = threadIdx.x;
    int row0 = blockIdx.x * 64;
    {
        int r = tid >> 2, q = tid & 3;
        int wt = row0 + r;
        int win = wt / 98, n = wt - win * 98;
        int b_ = win >> 8, wrem = win & 255;
        int tw = wrem >> 6, hw = (wrem >> 3) & 7, ww = wrem & 7;
        int it = n / 49, r2 = n - it * 49, ih = r2 / 7, iw = r2 - ih * 7;
        int t = tw * 2 + it, h = hw * 7 + ih, w = ww * 7 + iw;
        if (shifted) {
            t += 1; if (t >= TT) t -= TT;
            h += 3; if (h >= HH) h -= HH;
            w += 3; if (w >= WW2) w -= WW2;
        }
        const unsigned short* src = xb + ((size_t)b_ * PSPAT + t * (HH * WW2) + h * WW2 + w) * 128 + q * 32;
        float v[32];
        float s = 0.f, sq = 0.f;
        #pragma unroll
        for (int i = 0; i < 4; i++) {
            sv8_t raw = *(const sv8_t*)(src + i * 8);
            #pragma unroll
            for (int e = 0; e < 8; e++) {
                float f = bf2f((unsigned short)raw[e]);
                v[i * 8 + e] = f; s += f; sq += f * f;
            }
        }
        s += __shfl_xor(s, 1); sq += __shfl_xor(sq, 1);
        s += __shfl_xor(s, 2); sq += __shfl_xor(sq, 2);
        float mu = s * (1.f / 128.f);
        float var = sq * (1.f / 128.f) - mu * mu;
        float rs = rsqrtf(var + 1e-5f);
        for (int c0 = 0; c0 < 32; c0 += 8) {
            float y[8];
            #pragma unroll
            for (int i = 0; i < 8; i++) {
                int c = q * 32 + c0 + i;
                y[i] = (v[c0 + i] - mu) * rs * g[c] + be[c];
            }
            union { unsigned u[4]; sv8_t s8; } pk;
            pk.u[0] = packbf(y[0], y[1]); pk.u[1] = packbf(y[2], y[3]);
            pk.u[2] = packbf(y[4], y[5]); pk.u[3] = packbf(y[6], y[7]);
            lds_st8(xt, r * 256 + SWZB(r, (q * 32 + c0) * 2), pk.s8);
        }
    }
    __syncthreads();
    int wv = tid >> 6, lane = tid & 63, l15 = lane & 15, lhi = lane >> 4;

    if (wv < 2) {
        // Q (wv0) or K (wv1), swapped: C[d][tok]; 8 d16-frags, packed 8B stores
        int nb = wv * 128;
        fv4_t acc[4][8];
        for (int m = 0; m < 4; m++) for (int f = 0; f < 8; f++) acc[m][f] = (fv4_t){0.f, 0.f, 0.f, 0.f};
        for (int kk = 0; kk < 4; kk++) {
            sv8_t x4[4];
            #pragma unroll
            for (int m = 0; m < 4; m++) {
                int ar = 16 * m + l15;
                x4[m] = lds_ld8(xt, ar * 256 + SWZB(ar, (kk * 32 + 8 * lhi) * 2));
            }
            #pragma unroll
            for (int f = 0; f < 8; f++) {
                sv8_t wf = *(const sv8_t*)(wT + (size_t)(nb + 16 * f + l15) * 128 + kk * 32 + 8 * lhi);
                #pragma unroll
                for (int m = 0; m < 4; m++)
                    acc[m][f] = __builtin_amdgcn_mfma_f32_16x16x32_bf16(wf, x4[m], acc[m][f], 0, 0, 0);
            }
        }
        float sc_ = (wv == 0) ? 0.17677669529663687f : 1.f;
        #pragma unroll
        for (int f = 0; f < 8; f++) {
            f4ld_t b4 = *(const f4ld_t*)(bias + nb + 16 * f + 4 * lhi);
            #pragma unroll
            for (int m = 0; m < 4; m++) {
                int row = row0 + 16 * m + l15;
                union { unsigned u[2]; uint2 u2; } pk;
                pk.u[0] = packbf((acc[m][f][0] + b4.x) * sc_, (acc[m][f][1] + b4.y) * sc_);
                pk.u[1] = packbf((acc[m][f][2] + b4.z) * sc_, (acc[m][f][3] + b4.w) * sc_);
                *(uint2*)(qkbuf + (size_t)row * 256 + nb + 16 * f + 4 * lhi) = pk.u2;
            }
        }
    } else {
        int d16base = (wv - 2) * 4;
        fv4_t acc[4][4];   // [m][f]
        for (int m = 0; m < 4; m++) for (int f = 0; f < 4; f++) acc[m][f] = (fv4_t){0.f, 0.f, 0.f, 0.f};
        for (int kk = 0; kk < 4; kk++) {
            sv8_t x4[4];
            #pragma unroll
            for (int m = 0; m < 4; m++) {
                int ar = 16 * m + l15;
                x4[m] = lds_ld8(xt, ar * 256 + SWZB(ar, (kk * 32 + 8 * lhi) * 2));
            }
            #pragma unroll
            for (int f = 0; f < 4; f++) {
                sv8_t wf = *(const sv8_t*)(wT + (size_t)(256 + (d16base + f) * 16 + l15) * 128 + kk * 32 + 8 * lhi);
                #pragma unroll
                for (int m = 0; m < 4; m++)
                    acc[m][f] = __builtin_amdgcn_mfma_f32_16x16x32_bf16(wf, x4[m], acc[m][f], 0, 0, 0);
            }
        }
        #pragma unroll
        for (int f = 0; f < 4; f++) {
            f4ld_t b4 = *(const f4ld_t*)(bias + 256 + (d16base + f) * 16 + 4 * lhi);
            #pragma unroll
            for (int r = 0; r < 4; r++) {
                int d = (d16base + f) * 16 + 4 * lhi + r;
                #pragma unroll
                for (int m = 0; m < 4; m++) {
                    int row = row0 + 16 * m + l15;
                    int win = row / 98, tok = row - win * 98;
                    vT[(size_t)win * VT_WSTRIDE + d * 112 + tok] = f2bf(acc[m][f][r] + b4[r]);
                }
            }
        }
    }
}

// ---------------- attention core + proj, one block per window ----------------
// Swapped QK^T + swapped proj: all epilogues have lane=token, reg=4 consecutive
// cols -> uint2 RMW (14 ops vs 56 scalar) and 7 (t,h,w) computations vs 28.
__global__ __launch_bounds__(256, 3) void k_attn_proj(const unsigned short* __restrict__ qk,
                                                      const unsigned short* __restrict__ vT,
                                                      const float* __restrict__ biasb,  // [4][q 112][k 112]
                                                      const unsigned short* __restrict__ pwT, // [128][128]
                                                      const float* __restrict__ pb,
                                                      unsigned short* __restrict__ xbuf,
                                                      int shifted) {
    __shared__ unsigned short ot[112 * 128];
    __shared__ int lablut[112];
    int win = blockIdx.x;
    int tid = threadIdx.x;
    int wv = tid >> 6, lane = tid & 63;
    int head = wv;
    int l15 = lane & 15, lhi = lane >> 4;
    int wrem = win & 255;
    int tw = wrem >> 6, hw = (wrem >> 3) & 7, ww = wrem & 7;

    for (int m = tid; m < 112; m += 256) {
        int t0 = min(m, 97);
        int it = t0 / 49, r2 = t0 - it * 49, ih = r2 / 7, iw = r2 - ih * 7;
        int lab = 0;
        if (shifted) {
            int t = tw * 2 + it, h = hw * 7 + ih, w = ww * 7 + iw;
            int ct = (t < TT - 2) ? 0 : ((t < TT - 1) ? 1 : 2);
            int ch = (h < HH - 7) ? 0 : ((h < HH - 3) ? 1 : 2);
            int cw = (w < WW2 - 7) ? 0 : ((w < WW2 - 3) ? 1 : 2);
            lab = ct * 9 + ch * 3 + cw;
        }
        lablut[m] = lab;
    }
    __syncthreads();

    size_t rowbase = (size_t)win * 98;
    sv8_t kf[7];
    #pragma unroll
    for (int j = 0; j < 7; j++) {
        int tok = min(16 * j + l15, 97);
        kf[j] = *(const sv8_t*)(qk + (rowbase + tok) * 256 + 128 + head * 32 + 8 * lhi);
    }
    const unsigned short* vbase = vT + (size_t)win * VT_WSTRIDE + (head * 32) * 112;
    sv8_t vf[4][2];
    #pragma unroll
    for (int kk = 0; kk < 4; kk++)
        #pragma unroll
        for (int j = 0; j < 2; j++)
            vf[kk][j] = *(const sv8_t*)(vbase + (16 * j + l15) * 112 + kk * 32 + 8 * lhi);

    int klab[7];
    if (shifted) {
        #pragma unroll
        for (int j = 0; j < 7; j++) {
            int kb = 16 * j + 4 * lhi;
            klab[j] = lablut[kb] | (lablut[kb + 1] << 8) | (lablut[kb + 2] << 16) | (lablut[kb + 3] << 24);
        }
    }

    int src0 = ((lane & 16) << 1) + l15;   // 32*(lhi&1) + l15
    int src1 = src0 + 16;
    bool jlo = (lane < 32);

    sv8_t qa_c = *(const sv8_t*)(qk + (rowbase + l15) * 256 + head * 32 + 8 * lhi);

    for (int ms = 0; ms < 7; ms++) {
        sv8_t qa_n = qa_c;
        if (ms < 6) {
            int qtok = min(16 * (ms + 1) + l15, 97);
            qa_n = *(const sv8_t*)(qk + (rowbase + qtok) * 256 + head * 32 + 8 * lhi);
        }
        int ql = min(16 * ms + l15, 97);
        int labq = shifted ? lablut[ql] : 0;
        const float* bq = biasb + ((size_t)head * 112 + ql) * 112;
        f4ld_t bv[7];
        #pragma unroll
        for (int j = 0; j < 7; j++)
            bv[j] = *(const f4ld_t*)(bq + 16 * j + 4 * lhi);
        fv4_t sc[7];
        __builtin_amdgcn_s_setprio(1);
        #pragma unroll
        for (int j = 0; j < 7; j++) {
            fv4_t z = {0.f, 0.f, 0.f, 0.f};
            sc[j] = __builtin_amdgcn_mfma_f32_16x16x32_bf16(kf[j], qa_c, z, 0, 0, 0);
        }
        __builtin_amdgcn_s_setprio(0);
        float mx = -1e30f;
        #pragma unroll
        for (int j = 0; j < 7; j++) {
            #pragma unroll
            for (int r = 0; r < 4; r++) {
                float s = sc[j][r] + bv[j][r];
                if (shifted && (((klab[j] >> (8 * r)) & 255) != labq)) s -= 100.f;
                if (16 * j + 4 * lhi + r >= 98) s = -1e30f;
                sc[j][r] = s;
                mx = fmaxf(mx, s);
            }
        }
        mx = fmaxf(mx, __shfl_xor(mx, 16));
        mx = fmaxf(mx, __shfl_xor(mx, 32));
        float sm = 0.f;
        #pragma unroll
        for (int j = 0; j < 7; j++)
            #pragma unroll
            for (int r = 0; r < 4; r++) {
                float p = __expf(sc[j][r] - mx);
                sc[j][r] = p;
                sm += p;
            }
        sm += __shfl_xor(sm, 16);
        sm += __shfl_xor(sm, 32);
        float inv = __builtin_amdgcn_rcpf(sm);
        int pkl[8], pkh[8];
        #pragma unroll
        for (int j = 0; j < 7; j++) {
            pkl[j] = (int)packbf(sc[j][0] * inv, sc[j][1] * inv);
            pkh[j] = (int)packbf(sc[j][2] * inv, sc[j][3] * inv);
        }
        pkl[7] = 0; pkh[7] = 0;
        fv4_t oacc[2] = {{0.f, 0.f, 0.f, 0.f}, {0.f, 0.f, 0.f, 0.f}};
        #pragma unroll
        for (int kk = 0; kk < 4; kk++) {
            int e_lo0 = __shfl(pkl[2 * kk], src0), o_lo0 = __shfl(pkl[2 * kk + 1], src0);
            int e_hi0 = __shfl(pkh[2 * kk], src0), o_hi0 = __shfl(pkh[2 * kk + 1], src0);
            int e_lo1 = __shfl(pkl[2 * kk], src1), o_lo1 = __shfl(pkl[2 * kk + 1], src1);
            int e_hi1 = __shfl(pkh[2 * kk], src1), o_hi1 = __shfl(pkh[2 * kk + 1], src1);
            union { int u[4]; sv8_t s8; } pa;
            pa.u[0] = jlo ? e_lo0 : o_lo0;
            pa.u[1] = jlo ? e_hi0 : o_hi0;
            pa.u[2] = jlo ? e_lo1 : o_lo1;
            pa.u[3] = jlo ? e_hi1 : o_hi1;
            __builtin_amdgcn_s_setprio(1);
            #pragma unroll
            for (int j = 0; j < 2; j++)
                oacc[j] = __builtin_amdgcn_mfma_f32_16x16x32_bf16(pa.s8, vf[kk][j], oacc[j], 0, 0, 0);
            __builtin_amdgcn_s_setprio(0);
        }
        #pragma unroll
        for (int r = 0; r < 4; r++) {
            int orow = 16 * ms + 4 * lhi + r;
            #pragma unroll
            for (int j = 0; j < 2; j++) {
                int ocol = head * 32 + 16 * j + l15;
                float v = (orow < 98) ? oacc[j][r] : 0.f;
                lds_st1(ot, orow * 256 + SWZB(orow, ocol * 2), f2bf(v));
            }
        }
        qa_c = qa_n;
    }
    __syncthreads();

    // proj: SWAPPED operands -> C[outcol][token]: lane=token l15, reg=4 cols.
    {
        int nb = wv * 32;
        fv4_t acc[7][2];
        for (int m = 0; m < 7; m++) for (int j = 0; j < 2; j++) acc[m][j] = (fv4_t){0.f, 0.f, 0.f, 0.f};
        for (int kk = 0; kk < 4; kk++) {
            sv8_t wfr[2];
            #pragma unroll
            for (int j = 0; j < 2; j++)
                wfr[j] = *(const sv8_t*)(pwT + (size_t)(nb + 16 * j + l15) * 128 + kk * 32 + 8 * lhi);
            __builtin_amdgcn_s_setprio(1);
            #pragma unroll
            for (int m = 0; m < 7; m++) {
                int ar = 16 * m + l15;
                sv8_t a = lds_ld8(ot, ar * 256 + SWZB(ar, (kk * 32 + 8 * lhi) * 2));
                #pragma unroll
                for (int j = 0; j < 2; j++)
                    acc[m][j] = __builtin_amdgcn_mfma_f32_16x16x32_bf16(wfr[j], a, acc[m][j], 0, 0, 0);
            }
            __builtin_amdgcn_s_setprio(0);
        }
        int b_ = win >> 8;
        f4ld_t pb4[2];
        #pragma unroll
        for (int j = 0; j < 2; j++)
            pb4[j] = *(const f4ld_t*)(pb + nb + 16 * j + 4 * lhi);
        #pragma unroll
        for (int m = 0; m < 7; m++) {
            int tok = 16 * m + l15;
            if (tok < 98) {
                int it = tok / 49, r2 = tok - it * 49, ih = r2 / 7, iw = r2 - ih * 7;
                int t = tw * 2 + it, h = hw * 7 + ih, w = ww * 7 + iw;
                if (shifted) {
                    t += 1; if (t >= TT) t -= TT;
                    h += 3; if (h >= HH) h -= HH;
                    w += 3; if (w >= WW2) w -= WW2;
                }
                unsigned short* xp = xbuf + ((size_t)b_ * PSPAT + t * (HH * WW2) + h * WW2 + w) * 128 + nb;
                #pragma unroll
                for (int j = 0; j < 2; j++) {
                    int c0 = 16 * j + 4 * lhi;
                    uint2 oldp = *(uint2*)(xp + c0);
                    float o0 = bf2f((unsigned short)(oldp.x & 0xffff)) + acc[m][j][0] + pb4[j].x;
                    float o1 = bf2f((unsigned short)(oldp.x >> 16))    + acc[m][j][1] + pb4[j].y;
                    float o2 = bf2f((unsigned short)(oldp.y & 0xffff)) + acc[m][j][2] + pb4[j].z;
                    float o3 = bf2f((unsigned short)(oldp.y >> 16))    + acc[m][j][3] + pb4[j].w;
                    uint2 np;
                    np.x = packbf(o0, o1); np.y = packbf(o2, o3);
                    *(uint2*)(xp + c0) = np;
                }
            }
        }
    }
}

// ---------------- fused LN2 + fc1 + GELU + fc2 + residual (+final transpose) ----
// 48 KB LDS (A 16 KB U-half + Bst 32 KB) -> 3 blocks/CU; xt staged in Bst at LN.
#define LOAD_CHUNK(c, R)                                                                   \
    if ((c) < 16) {                                                                        \
        if (((c) & 1) == 0) {                                                              \
            _Pragma("unroll")                                                              \
            for (int i_ = 0; i_ < 4; i_++)                                                 \
                R[i_] = *(const sv8_t*)(w1T + (size_t)(((c) >> 2) * 128 + (((c) >> 1) & 1) * 64 + i_ * 16 + r1) * 128 + (c1 >> 1)); \
        } else {                                                                           \
            _Pragma("unroll")                                                              \
            for (int i_ = 0; i_ < 4; i_++)                                                 \
                R[i_] = *(const sv8_t*)(w2T + (size_t)(i_ * 32 + r2) * 512 + ((c) >> 2) * 128 + (((c) >> 1) & 1) * 64 + (c2 >> 1)); \
        }                                                                                  \
    }
#define WRITE_CHUNK(c, R)                                                                  \
    if ((c) < 16) {                                                                        \
        unsigned short* bst_ = Bst[(c)&1];                                                 \
        if (((c) & 1) == 0) {                                                              \
            _Pragma("unroll")                                                              \
            for (int i_ = 0; i_ < 4; i_++)                                                 \
                lds_st8(bst_, (i_ * 16 + r1) * 256 + SWZB(i_ * 16 + r1, c1), R[i_]);       \
        } else {                                                                           \
            _Pragma("unroll")                                                              \
            for (int i_ = 0; i_ < 4; i_++)                                                 \
                lds_st8(bst_, (i_ * 32 + r2) * 128 + SWZB(i_ * 32 + r2, c2), R[i_]);       \
        }                                                                                  \
    }

__global__ __launch_bounds__(256, 3) void k_mlp(const unsigned short* __restrict__ xin,
                                                const float* __restrict__ g,
                                                const float* __restrict__ be,
                                                const unsigned short* __restrict__ w1T,  // [512][128]
                                                const float* __restrict__ b1p,
                                                const unsigned short* __restrict__ w2T,  // [128][512]
                                                const float* __restrict__ b2p,
                                                unsigned short* __restrict__ xbuf,
                                                float* __restrict__ outp,
                                                int final_layer) {
    __shared__ unsigned short A[4][32 * 64];    // 16 KB: per-wave U half
    __shared__ unsigned short Bst[2][8192];     // 32 KB: ping-pong chunks; xt during LN
    int tid = threadIdx.x;
    int wv = tid >> 6, lane = tid & 63, l15 = lane & 15, lhi = lane >> 4;
    unsigned short* uw = A[wv];
    unsigned short* xts = &Bst[0][0];
    int tok0 = blockIdx.x * 128 + wv * 32;

    int r1 = tid >> 4, c1 = (tid & 15) * 16;   // w1 chunk coords (64x128 elems)
    int r2 = tid >> 3, c2 = (tid & 7) * 16;    // w2 chunk coords (128x64 elems)

    sv8_t wA[4], wB[4];
    LOAD_CHUNK(0, wA)                          // hidden under LN

    // ---- LN (xt staged in Bst; wave-private rows wv*32..+31)
    #pragma unroll
    for (int tf = 0; tf < 2; tf++) {
        int lrow = 16 * tf + l15;
        int grow = wv * 32 + lrow;
        const unsigned short* src = xin + (size_t)(tok0 + lrow) * 128 + lhi * 32;
        float v[32];
        float s = 0.f, sq = 0.f;
        #pragma unroll
        for (int i = 0; i < 4; i++) {
            sv8_t raw = *(const sv8_t*)(src + i * 8);
            #pragma unroll
            for (int e = 0; e < 8; e++) {
                float f = bf2f((unsigned short)raw[e]);
                v[i * 8 + e] = f; s += f; sq += f * f;
            }
        }
        s += __shfl_xor(s, 16); sq += __shfl_xor(sq, 16);
        s += __shfl_xor(s, 32); sq += __shfl_xor(sq, 32);
        float mu = s * (1.f / 128.f);
        float var = sq * (1.f / 128.f) - mu * mu;
        float rs = rsqrtf(var + 1e-5f);
        #pragma unroll
        for (int j = 0; j < 4; j++) {
            int c0 = lhi * 32 + 8 * j;
            f4ld_t g0 = *(const f4ld_t*)(g + c0);
            f4ld_t g1 = *(const f4ld_t*)(g + c0 + 4);
            f4ld_t b0 = *(const f4ld_t*)(be + c0);
            f4ld_t b1 = *(const f4ld_t*)(be + c0 + 4);
            float y0 = (v[8 * j + 0] - mu) * rs * g0.x + b0.x;
            float y1 = (v[8 * j + 1] - mu) * rs * g0.y + b0.y;
            float y2 = (v[8 * j + 2] - mu) * rs * g0.z + b0.z;
            float y3 = (v[8 * j + 3] - mu) * rs * g0.w + b0.w;
            float y4 = (v[8 * j + 4] - mu) * rs * g1.x + b1.x;
            float y5 = (v[8 * j + 5] - mu) * rs * g1.y + b1.y;
            float y6 = (v[8 * j + 6] - mu) * rs * g1.z + b1.z;
            float y7 = (v[8 * j + 7] - mu) * rs * g1.w + b1.w;
            union { unsigned u[4]; sv8_t s8; } pk;
            pk.u[0] = packbf(y0, y1); pk.u[1] = packbf(y2, y3);
            pk.u[2] = packbf(y4, y5); pk.u[3] = packbf(y6, y7);
            lds_st8(xts, grow * 256 + SWZB(grow, 64 * lhi + 16 * j), pk.s8);
        }
    }
    sv8_t xf[2][4];
    #pragma unroll
    for (int tf = 0; tf < 2; tf++)
        #pragma unroll
        for (int kk = 0; kk < 4; kk++) {
            int grow = wv * 32 + 16 * tf + l15;
            xf[tf][kk] = lds_ld8(xts, grow * 256 + SWZB(grow, 64 * kk + 16 * lhi));
        }

    fv4_t acc2[8][2];
    #pragma unroll
    for (int cg = 0; cg < 8; cg++)
        #pragma unroll
        for (int tf = 0; tf < 2; tf++) acc2[cg][tf] = (fv4_t){0.f, 0.f, 0.f, 0.f};

    __syncthreads();
    WRITE_CHUNK(0, wA)
    LOAD_CHUNK(1, wB)
    __syncthreads();

    #pragma unroll
    for (int q = 0; q < 4; q++) {
        // ---- phase c=4q+0: fc1 fg 0..3 from Bst[0] (w1 h0) -> U half
        {
            const int c = 4 * q;
            WRITE_CHUNK(c + 1, wB)
            LOAD_CHUNK(c + 2, wA)
            #pragma unroll
            for (int f = 0; f < 4; f++) {
                sv8_t wf[4];
                #pragma unroll
                for (int kk = 0; kk < 4; kk++) {
                    int wrow = 16 * f + l15;
                    wf[kk] = lds_ld8(Bst[0], wrow * 256 + SWZB(wrow, kk * 64 + 16 * lhi));
                }
                fv4_t a1[2] = {{0.f, 0.f, 0.f, 0.f}, {0.f, 0.f, 0.f, 0.f}};
                __builtin_amdgcn_s_setprio(1);
                #pragma unroll
                for (int kk = 0; kk < 4; kk++) {
                    a1[0] = __builtin_amdgcn_mfma_f32_16x16x32_bf16(wf[kk], xf[0][kk], a1[0], 0, 0, 0);
                    a1[1] = __builtin_amdgcn_mfma_f32_16x16x32_bf16(wf[kk], xf[1][kk], a1[1], 0, 0, 0);
                }
                __builtin_amdgcn_s_setprio(0);
                f4ld_t b4 = *(const f4ld_t*)(b1p + q * 128 + 16 * f + 4 * lhi);
                #pragma unroll
                for (int tf = 0; tf < 2; tf++) {
                    float g0 = gelu_f(a1[tf][0] + b4.x);
                    float g1 = gelu_f(a1[tf][1] + b4.y);
                    float g2 = gelu_f(a1[tf][2] + b4.z);
                    float g3 = gelu_f(a1[tf][3] + b4.w);
                    union { unsigned u[2]; uint2 u2; } pk;
                    pk.u[0] = packbf(g0, g1); pk.u[1] = packbf(g2, g3);
                    int lrow = 16 * tf + l15;
                    *(uint2*)((char*)uw + lrow * 128 + SWZB(lrow, 32 * f + 8 * lhi)) = pk.u2;
                }
            }
            __syncthreads();
        }
        // ---- phase c=4q+1: fc2 (K = U cols q*128..+63) from Bst[1] (w2 h0)
        {
            const int c = 4 * q + 1;
            WRITE_CHUNK(c + 1, wA)
            LOAD_CHUNK(c + 2, wB)
            #pragma unroll
            for (int kql = 0; kql < 2; kql++) {
                sv8_t uf[2];
                #pragma unroll
                for (int tf = 0; tf < 2; tf++) {
                    int lrow = 16 * tf + l15;
                    uf[tf] = lds_ld8(uw, lrow * 128 + SWZB(lrow, 64 * kql + 16 * lhi));
                }
                #pragma unroll
                for (int cb = 0; cb < 2; cb++) {
                    sv8_t w2f[4];
                    #pragma unroll
                    for (int cc = 0; cc < 4; cc++) {
                        int wrow = 16 * (4 * cb + cc) + l15;
                        w2f[cc] = lds_ld8(Bst[1], wrow * 128 + SWZB(wrow, kql * 64 + 16 * lhi));
                    }
                    __builtin_amdgcn_s_setprio(1);
                    #pragma unroll
                    for (int cc = 0; cc < 4; cc++) {
                        int cg = 4 * cb + cc;
                        acc2[cg][0] = __builtin_amdgcn_mfma_f32_16x16x32_bf16(w2f[cc], uf[0], acc2[cg][0], 0, 0, 0);
                        acc2[cg][1] = __builtin_amdgcn_mfma_f32_16x16x32_bf16(w2f[cc], uf[1], acc2[cg][1], 0, 0, 0);
                    }
                    __builtin_amdgcn_s_setprio(0);
                }
            }
            __syncthreads();
        }
        // ---- phase c=4q+2: fc1 fg 4..7 from Bst[0] (w1 h1) -> same U half buffer
        {
            const int c = 4 * q + 2;
            WRITE_CHUNK(c + 1, wB)
            LOAD_CHUNK(c + 2, wA)
            #pragma unroll
            for (int f = 0; f < 4; f++) {
                sv8_t wf[4];
                #pragma unroll
                for (int kk = 0; kk < 4; kk++) {
                    int wrow = 16 * f + l15;
                    wf[kk] = lds_ld8(Bst[0], wrow * 256 + SWZB(wrow, kk * 64 + 16 * lhi));
                }
                fv4_t a1[2] = {{0.f, 0.f, 0.f, 0.f}, {0.f, 0.f, 0.f, 0.f}};
                __builtin_amdgcn_s_setprio(1);
                #pragma unroll
                for (int kk = 0; kk < 4; kk++) {
                    a1[0] = __builtin_amdgcn_mfma_f32_16x16x32_bf16(wf[kk], xf[0][kk], a1[0], 0, 0, 0);
                    a1[1] = __builtin_amdgcn_mfma_f32_16x16x32_bf16(wf[kk], xf[1][kk], a1[1], 0, 0, 0);
                }
                __builtin_amdgcn_s_setprio(0);
                f4ld_t b4 = *(const f4ld_t*)(b1p + q * 128 + 64 + 16 * f + 4 * lhi);
                #pragma unroll
                for (int tf = 0; tf < 2; tf++) {
                    float g0 = gelu_f(a1[tf][0] + b4.x);
                    float g1 = gelu_f(a1[tf][1] + b4.y);
                    float g2 = gelu_f(a1[tf][2] + b4.z);
                    float g3 = gelu_f(a1[tf][3] + b4.w);
                    union { unsigned u[2]; uint2 u2; } pk;
                    pk.u[0] = packbf(g0, g1); pk.u[1] = packbf(g2, g3);
                    int lrow = 16 * tf + l15;
                    *(uint2*)((char*)uw + lrow * 128 + SWZB(lrow, 32 * f + 8 * lhi)) = pk.u2;
                }
            }
            __syncthreads();
        }
        // ---- phase c=4q+3: fc2 (K = U cols q*128+64..+127) from Bst[1] (w2 h1)
        {
            const int c = 4 * q + 3;
            WRITE_CHUNK(c + 1, wA)
            LOAD_CHUNK(c + 2, wB)
            #pragma unroll
            for (int kql = 0; kql < 2; kql++) {
                sv8_t uf[2];
                #pragma unroll
                for (int tf = 0; tf < 2; tf++) {
                    int lrow = 16 * tf + l15;
                    uf[tf] = lds_ld8(uw, lrow * 128 + SWZB(lrow, 64 * kql + 16 * lhi));
                }
                #pragma unroll
                for (int cb = 0; cb < 2; cb++) {
                    sv8_t w2f[4];
                    #pragma unroll
                    for (int cc = 0; cc < 4; cc++) {
                        int wrow = 16 * (4 * cb + cc) + l15;
                        w2f[cc] = lds_ld8(Bst[1], wrow * 128 + SWZB(wrow, kql * 64 + 16 * lhi));
                    }
                    __builtin_amdgcn_s_setprio(1);
                    #pragma unroll
                    for (int cc = 0; cc < 4; cc++) {
                        int cg = 4 * cb + cc;
                        acc2[cg][0] = __builtin_amdgcn_mfma_f32_16x16x32_bf16(w2f[cc], uf[0], acc2[cg][0], 0, 0, 0);
                        acc2[cg][1] = __builtin_amdgcn_mfma_f32_16x16x32_bf16(w2f[cc], uf[1], acc2[cg][1], 0, 0, 0);
                    }
                    __builtin_amdgcn_s_setprio(0);
                }
            }
            __syncthreads();
        }
    }
    // ---- epilogue
    if (!final_layer) {
        #pragma unroll
        for (int tf = 0; tf < 2; tf++) {
            int row = tok0 + 16 * tf + l15;
            #pragma unroll
            for (int cg = 0; cg < 8; cg++) {
                int c0 = 16 * cg + 4 * lhi;
                f4ld_t b4 = *(const f4ld_t*)(b2p + c0);
                unsigned short* xp = xbuf + (size_t)row * 128 + c0;
                uint2 oldp = *(uint2*)xp;
                float o0 = bf2f((unsigned short)(oldp.x & 0xffff)) + acc2[cg][tf][0] + b4.x;
                float o1 = bf2f((unsigned short)(oldp.x >> 16))    + acc2[cg][tf][1] + b4.y;
                float o2 = bf2f((unsigned short)(oldp.y & 0xffff)) + acc2[cg][tf][2] + b4.z;
                float o3 = bf2f((unsigned short)(oldp.y >> 16))    + acc2[cg][tf][3] + b4.w;
                uint2 np;
                np.x = packbf(o0, o1); np.y = packbf(o2, o3);
                *(uint2*)xp = np;
            }
        }
    } else {
        // final layer: out[b][c][p] = bf16 residual + mlp, f32 write (fuses transpose)
        #pragma unroll
        for (int tf = 0; tf < 2; tf++) {
            int row = tok0 + 16 * tf + l15;
            int b_ = row / PSPAT, p = row - b_ * PSPAT;
            float* ob = outp + (size_t)b_ * 128 * PSPAT + p;
            #pragma unroll
            for (int cg = 0; cg < 8; cg++) {
                int c0 = 16 * cg + 4 * lhi;
                f4ld_t b4 = *(const f4ld_t*)(b2p + c0);
                const unsigned short* xp = xbuf + (size_t)row * 128 + c0;
                uint2 oldp = *(const uint2*)xp;
                float o0 = bf2f((unsigned short)(oldp.x & 0xffff)) + acc2[cg][tf][0] + b4.x;
                float o1 = bf2f((unsigned short)(oldp.x >> 16))    + acc2[cg][tf][1] + b4.y;
                float o2 = bf2f((unsigned short)(oldp.y & 0xffff)) + acc2[cg][tf][2] + b4.z;
                float o3 = bf2f((unsigned short)(oldp.y >> 16))    + acc2[cg][tf][3] + b4.w;
                ob[(size_t)(c0 + 0) * PSPAT] = o0;
                ob[(size_t)(c0 + 1) * PSPAT] = o1;
                ob[(size_t)(c0 + 2) * PSPAT] = o2;
                ob[(size_t)(c0 + 3) * PSPAT] = o3;
            }
        }
    }
}

extern "C" void kernel_launch(void* const* d_in, const int* in_sizes, int n_in,
                              void* d_out, int out_size, void* d_ws, size_t ws_size,
                              hipStream_t stream) {
    const float* x_in   = (const float*)d_in[0];
    const float* ln1_g  = (const float*)d_in[1];
    const float* ln1_b  = (const float*)d_in[2];
    const float* qkv_w  = (const float*)d_in[3];
    const float* qkv_b  = (const float*)d_in[4];
    const float* rpb    = (const float*)d_in[5];
    const float* proj_w = (const float*)d_in[6];
    const float* proj_b = (const float*)d_in[7];
    const float* ln2_g  = (const float*)d_in[8];
    const float* ln2_b  = (const float*)d_in[9];
    const float* fc1_w  = (const float*)d_in[10];
    const float* fc1_b  = (const float*)d_in[11];
    const float* fc2_w  = (const float*)d_in[12];
    const float* fc2_b  = (const float*)d_in[13];
    float* out = (float*)d_out;

    char* ws = (char*)d_ws;
    unsigned short* xbufb = (unsigned short*)ws;                     //  51,380,224 B (bf16)
    unsigned short* qkbuf = (unsigned short*)(ws + 51380224);        // 102,760,448 B
    unsigned short* vTbuf = (unsigned short*)(ws + 154140672);       //  58,720,256 B
    unsigned short* wbase = (unsigned short*)(ws + 212860928);       //     786,432 B
    float* biasb = (float*)(ws + 212860928 + 786432);                //     401,408 B

    k_transpose_in<<<dim3(PSPAT / 32, 4, BB), dim3(32, 8), 0, stream>>>(x_in, xbufb);

    for (int l = 0; l < 2; l++) {
        unsigned short* wqT = wbase + (size_t)l * 196608;
        unsigned short* wpT = wqT + 49152;
        unsigned short* w1T = wpT + 16384;
        unsigned short* w2T = w1T + 65536;
        k_prep_w<<<dim3(12, 4), dim3(32, 8), 0, stream>>>(qkv_w + (size_t)l * 49152, wqT, 128, 384);
        k_prep_w<<<dim3(4, 4),  dim3(32, 8), 0, stream>>>(proj_w + (size_t)l * 16384, wpT, 128, 128);
        k_prep_w<<<dim3(16, 4), dim3(32, 8), 0, stream>>>(fc1_w + (size_t)l * 65536, w1T, 128, 512);
        k_prep_w<<<dim3(4, 16), dim3(32, 8), 0, stream>>>(fc2_w + (size_t)l * 65536, w2T, 512, 128);
    }
    k_prep_bias<<<dim3(112, 4, 2), 112, 0, stream>>>(rpb, biasb);

    for (int layer = 0; layer < 2; layer++) {
        unsigned short* wqT = wbase + (size_t)layer * 196608;
        unsigned short* wpT = wqT + 49152;
        unsigned short* w1T = wpT + 16384;
        unsigned short* w2T = w1T + 65536;
        int shifted = layer & 1;

        k_qkv<<<TOK_TOTAL / 64, 256, 0, stream>>>(xbufb, ln1_g + layer * 128, ln1_b + layer * 128,
                                                  wqT, qkv_b + layer * 384, qkbuf, vTbuf, shifted);
        k_attn_proj<<<BNW, 256, 0, stream>>>(qkbuf, vTbuf, biasb + (size_t)layer * 4 * 112 * 112,
                                             wpT, proj_b + layer * 128, xbufb, shifted);
        k_mlp<<<TOK_TOTAL / 128, 256, 0, stream>>>(xbufb, ln2_g + layer * 128, ln2_b + layer * 128,
                                                   w1T, fc1_b + layer * 512, w2T, fc2_b + layer * 128,
                                                   xbufb, out, layer == 1);
    }
}

// Round 20
// 642.455 us; speedup vs baseline: 1.6490x; 1.0305x over previous
//
#include <hip/hip_runtime.h>
#include <hip/hip_bf16.h>

typedef __attribute__((ext_vector_type(8))) short sv8_t;   // 8 bf16 (4 VGPR)
typedef __attribute__((ext_vector_type(4))) float fv4_t;   // MFMA accumulator
typedef __attribute__((ext_vector_type(4))) float f4ld_t;  // global float4 load

#define BB 8
#define TT 8
#define HH 56
#define WW2 56
#define NTOK 98
#define BNW 2048
#define PSPAT 25088
#define TOK_TOTAL 200704
#define VT_WSTRIDE 14336   // 128 * 112

#define SWZB(row, cb) ((cb) ^ ((((unsigned)(row)) & 7u) << 4))

__device__ __forceinline__ unsigned short f2bf(float f) {
    union { float f; unsigned u; } x; x.f = f;
    unsigned r = x.u + 0x7fffu + ((x.u >> 16) & 1u);
    return (unsigned short)(r >> 16);
}
__device__ __forceinline__ float bf2f(unsigned short u) {
    union { unsigned u; float f; } x; x.u = ((unsigned)u) << 16; return x.f;
}
// packed pair via v_cvt_pk_bf16_f32 (RNE, bit-identical to f2bf pair, 1 inst)
__device__ __forceinline__ unsigned packbf(float lo, float hi) {
    __hip_bfloat162 h = __float22bfloat162_rn(make_float2(lo, hi));
    union { __hip_bfloat162 h; unsigned u; } cv; cv.h = h; return cv.u;
}
__device__ __forceinline__ sv8_t lds_ld8(const unsigned short* p, int byteoff) {
    return *(const sv8_t*)((const char*)p + byteoff);
}
__device__ __forceinline__ void lds_st8(unsigned short* p, int byteoff, sv8_t v) {
    *(sv8_t*)((char*)p + byteoff) = v;
}
__device__ __forceinline__ void lds_st1(unsigned short* p, int byteoff, unsigned short v) {
    *(unsigned short*)((char*)p + byteoff) = v;
}
// GELU, sigmoid form: x*sigmoid(1.702x)
__device__ __forceinline__ float gelu_f(float v) {
    float e = __expf(-1.702f * v);
    return v * __builtin_amdgcn_rcpf(1.f + e);
}

// ---------------- merged prep: transpose-in + all weight transposes + bias ----
// blocks [0, 25088):            (B,C,P) f32 -> (B,P,C) bf16
// blocks [25088, 25088+384):    weight f32 [K][N] -> bf16 [N][K] (192 tiles/layer)
// blocks [25472, 25472+392):    bias table  biasb[layer][head][q 112][k 112]
#define NTRB 25088
__global__ __launch_bounds__(256) void k_prep_all(const float* __restrict__ in,
                                                  unsigned short* __restrict__ xbuf,
                                                  const float* __restrict__ qkv_w,
                                                  const float* __restrict__ proj_w,
                                                  const float* __restrict__ fc1_w,
                                                  const float* __restrict__ fc2_w,
                                                  unsigned short* __restrict__ wbase,
                                                  const float* __restrict__ rpb,
                                                  float* __restrict__ biasb) {
    int bid = blockIdx.x;
    int tid = threadIdx.x;
    if (bid < NTRB) {
        // ---- transpose-in tile
        __shared__ float tile[32][33];
        int p0 = (bid % 784) * 32;
        int c0 = ((bid / 784) & 3) * 32;
        int b = bid / (784 * 4);
        int pi = tid & 31, ci = tid >> 5;
        const float* src = in + ((size_t)b * 128 + c0) * PSPAT + p0;
        for (int r = 0; r < 32; r += 8)
            tile[ci + r][pi] = src[(size_t)(ci + r) * PSPAT + pi];
        __syncthreads();
        unsigned short* dst = xbuf + ((size_t)b * PSPAT + p0) * 128 + c0;
        for (int r = 0; r < 32; r += 8)
            dst[(size_t)(ci + r) * 128 + pi] = f2bf(tile[pi][ci + r]);
    } else if (bid < NTRB + 384) {
        // ---- weight transpose tile
        __shared__ float tile[32][33];
        int t = (bid - NTRB) % 192;
        int layer = (bid - NTRB) / 192;
        const float* win_;
        unsigned short* wout;
        int K, N, gx, gy;
        if (t < 48)       { win_ = qkv_w  + (size_t)layer * 49152; wout = wbase + (size_t)layer * 196608;          K = 128; N = 384; gx = t % 12;        gy = t / 12; }
        else if (t < 64)  { win_ = proj_w + (size_t)layer * 16384; wout = wbase + (size_t)layer * 196608 + 49152;  K = 128; N = 128; gx = (t - 48) % 4;  gy = (t - 48) / 4; }
        else if (t < 128) { win_ = fc1_w  + (size_t)layer * 65536; wout = wbase + (size_t)layer * 196608 + 65536;  K = 128; N = 512; gx = (t - 64) % 16; gy = (t - 64) / 16; }
        else              { win_ = fc2_w  + (size_t)layer * 65536; wout = wbase + (size_t)layer * 196608 + 131072; K = 512; N = 128; gx = (t - 128) % 4; gy = (t - 128) / 4; }
        int n0 = gx * 32, k0 = gy * 32;
        int x = tid & 31, y = tid >> 5;
        for (int r = 0; r < 32; r += 8)
            tile[y + r][x] = win_[(size_t)(k0 + y + r) * N + n0 + x];
        __syncthreads();
        for (int r = 0; r < 32; r += 8)
            wout[(size_t)(n0 + y + r) * K + k0 + x] = f2bf(tile[x][y + r]);
    } else {
        // ---- bias table
        int e = (bid - NTRB - 384) * 256 + tid;   // < 100352
        int col = e % 112;
        int row = (e / 112) % 112;
        int head = (e / 12544) & 3;
        int layer = e / 50176;
        int tn = min(row, 97), tm = min(col, 97);
        int itn = tn / 49, rn = tn - itn * 49, ihn = rn / 7, iwn = rn - ihn * 7;
        int itm = tm / 49, rm = tm - itm * 49, ihm = rm / 7, iwm = rm - ihm * 7;
        int dt = itn - itm + 1, dh = ihn - ihm + 6, dw = iwn - iwm + 6;
        float v = rpb[((size_t)layer * 507 + dt * 169 + dh * 13 + dw) * 4 + head];
        biasb[(((size_t)layer * 4 + head) * 112 + row) * 112 + col] = v;
    }
}

// ---------------- fused LN1 + gather + qkv GEMM ----------------
__global__ __launch_bounds__(256) void k_qkv(const unsigned short* __restrict__ xb,
                                             const float* __restrict__ g,
                                             const float* __restrict__ be,
                                             const unsigned short* __restrict__ wT,  // [384][128]
                                             const float* __restrict__ bias,         // [384]
                                             unsigned short* __restrict__ qkbuf,
                                             unsigned short* __restrict__ vT,
                                             int shifted) {
    __shared__ unsigned short xt[64 * 128];
    int tid = threadIdx.x;
    int row0 = blockIdx.x * 64;
    {
        int r = tid >> 2, q = tid & 3;
        int wt = row0 + r;
        int win = wt / 98, n = wt - win * 98;
        int b_ = win >> 8, wrem = win & 255;
        int tw = wrem >> 6, hw = (wrem >> 3) & 7, ww = wrem & 7;
        int it = n / 49, r2 = n - it * 49, ih = r2 / 7, iw = r2 - ih * 7;
        int t = tw * 2 + it, h = hw * 7 + ih, w = ww * 7 + iw;
        if (shifted) {
            t += 1; if (t >= TT) t -= TT;
            h += 3; if (h >= HH) h -= HH;
            w += 3; if (w >= WW2) w -= WW2;
        }
        const unsigned short* src = xb + ((size_t)b_ * PSPAT + t * (HH * WW2) + h * WW2 + w) * 128 + q * 32;
        float v[32];
        float s = 0.f, sq = 0.f;
        #pragma unroll
        for (int i = 0; i < 4; i++) {
            sv8_t raw = *(const sv8_t*)(src + i * 8);
            #pragma unroll
            for (int e = 0; e < 8; e++) {
                float f = bf2f((unsigned short)raw[e]);
                v[i * 8 + e] = f; s += f; sq += f * f;
            }
        }
        s += __shfl_xor(s, 1); sq += __shfl_xor(sq, 1);
        s += __shfl_xor(s, 2); sq += __shfl_xor(sq, 2);
        float mu = s * (1.f / 128.f);
        float var = sq * (1.f / 128.f) - mu * mu;
        float rs = rsqrtf(var + 1e-5f);
        for (int c0 = 0; c0 < 32; c0 += 8) {
            float y[8];
            #pragma unroll
            for (int i = 0; i < 8; i++) {
                int c = q * 32 + c0 + i;
                y[i] = (v[c0 + i] - mu) * rs * g[c] + be[c];
            }
            union { unsigned u[4]; sv8_t s8; } pk;
            pk.u[0] = packbf(y[0], y[1]); pk.u[1] = packbf(y[2], y[3]);
            pk.u[2] = packbf(y[4], y[5]); pk.u[3] = packbf(y[6], y[7]);
            lds_st8(xt, r * 256 + SWZB(r, (q * 32 + c0) * 2), pk.s8);
        }
    }
    __syncthreads();
    int wv = tid >> 6, lane = tid & 63, l15 = lane & 15, lhi = lane >> 4;

    if (wv < 2) {
        // Q (wv0) or K (wv1), swapped: C[d][tok]; 8 d16-frags, packed 8B stores
        int nb = wv * 128;
        fv4_t acc[4][8];
        for (int m = 0; m < 4; m++) for (int f = 0; f < 8; f++) acc[m][f] = (fv4_t){0.f, 0.f, 0.f, 0.f};
        for (int kk = 0; kk < 4; kk++) {
            sv8_t x4[4];
            #pragma unroll
            for (int m = 0; m < 4; m++) {
                int ar = 16 * m + l15;
                x4[m] = lds_ld8(xt, ar * 256 + SWZB(ar, (kk * 32 + 8 * lhi) * 2));
            }
            #pragma unroll
            for (int f = 0; f < 8; f++) {
                sv8_t wf = *(const sv8_t*)(wT + (size_t)(nb + 16 * f + l15) * 128 + kk * 32 + 8 * lhi);
                #pragma unroll
                for (int m = 0; m < 4; m++)
                    acc[m][f] = __builtin_amdgcn_mfma_f32_16x16x32_bf16(wf, x4[m], acc[m][f], 0, 0, 0);
            }
        }
        float sc_ = (wv == 0) ? 0.17677669529663687f : 1.f;
        #pragma unroll
        for (int f = 0; f < 8; f++) {
            f4ld_t b4 = *(const f4ld_t*)(bias + nb + 16 * f + 4 * lhi);
            #pragma unroll
            for (int m = 0; m < 4; m++) {
                int row = row0 + 16 * m + l15;
                union { unsigned u[2]; uint2 u2; } pk;
                pk.u[0] = packbf((acc[m][f][0] + b4.x) * sc_, (acc[m][f][1] + b4.y) * sc_);
                pk.u[1] = packbf((acc[m][f][2] + b4.z) * sc_, (acc[m][f][3] + b4.w) * sc_);
                *(uint2*)(qkbuf + (size_t)row * 256 + nb + 16 * f + 4 * lhi) = pk.u2;
            }
        }
    } else {
        int d16base = (wv - 2) * 4;
        fv4_t acc[4][4];   // [m][f]
        for (int m = 0; m < 4; m++) for (int f = 0; f < 4; f++) acc[m][f] = (fv4_t){0.f, 0.f, 0.f, 0.f};
        for (int kk = 0; kk < 4; kk++) {
            sv8_t x4[4];
            #pragma unroll
            for (int m = 0; m < 4; m++) {
                int ar = 16 * m + l15;
                x4[m] = lds_ld8(xt, ar * 256 + SWZB(ar, (kk * 32 + 8 * lhi) * 2));
            }
            #pragma unroll
            for (int f = 0; f < 4; f++) {
                sv8_t wf = *(const sv8_t*)(wT + (size_t)(256 + (d16base + f) * 16 + l15) * 128 + kk * 32 + 8 * lhi);
                #pragma unroll
                for (int m = 0; m < 4; m++)
                    acc[m][f] = __builtin_amdgcn_mfma_f32_16x16x32_bf16(wf, x4[m], acc[m][f], 0, 0, 0);
            }
        }
        #pragma unroll
        for (int f = 0; f < 4; f++) {
            f4ld_t b4 = *(const f4ld_t*)(bias + 256 + (d16base + f) * 16 + 4 * lhi);
            #pragma unroll
            for (int r = 0; r < 4; r++) {
                int d = (d16base + f) * 16 + 4 * lhi + r;
                #pragma unroll
                for (int m = 0; m < 4; m++) {
                    int row = row0 + 16 * m + l15;
                    int win = row / 98, tok = row - win * 98;
                    vT[(size_t)win * VT_WSTRIDE + d * 112 + tok] = f2bf(acc[m][f][r] + b4[r]);
                }
            }
        }
    }
}

// ---------------- attention core + proj, one block per window ----------------
// Swapped QK^T + swapped proj: all epilogues have lane=token, reg=4 consecutive
// cols -> uint2 RMW and 7 (t,h,w) computations vs 28.
__global__ __launch_bounds__(256, 3) void k_attn_proj(const unsigned short* __restrict__ qk,
                                                      const unsigned short* __restrict__ vT,
                                                      const float* __restrict__ biasb,  // [4][q 112][k 112]
                                                      const unsigned short* __restrict__ pwT, // [128][128]
                                                      const float* __restrict__ pb,
                                                      unsigned short* __restrict__ xbuf,
                                                      int shifted) {
    __shared__ unsigned short ot[112 * 128];
    __shared__ int lablut[112];
    int win = blockIdx.x;
    int tid = threadIdx.x;
    int wv = tid >> 6, lane = tid & 63;
    int head = wv;
    int l15 = lane & 15, lhi = lane >> 4;
    int wrem = win & 255;
    int tw = wrem >> 6, hw = (wrem >> 3) & 7, ww = wrem & 7;

    for (int m = tid; m < 112; m += 256) {
        int t0 = min(m, 97);
        int it = t0 / 49, r2 = t0 - it * 49, ih = r2 / 7, iw = r2 - ih * 7;
        int lab = 0;
        if (shifted) {
            int t = tw * 2 + it, h = hw * 7 + ih, w = ww * 7 + iw;
            int ct = (t < TT - 2) ? 0 : ((t < TT - 1) ? 1 : 2);
            int ch = (h < HH - 7) ? 0 : ((h < HH - 3) ? 1 : 2);
            int cw = (w < WW2 - 7) ? 0 : ((w < WW2 - 3) ? 1 : 2);
            lab = ct * 9 + ch * 3 + cw;
        }
        lablut[m] = lab;
    }
    __syncthreads();

    size_t rowbase = (size_t)win * 98;
    sv8_t kf[7];
    #pragma unroll
    for (int j = 0; j < 7; j++) {
        int tok = min(16 * j + l15, 97);
        kf[j] = *(const sv8_t*)(qk + (rowbase + tok) * 256 + 128 + head * 32 + 8 * lhi);
    }
    const unsigned short* vbase = vT + (size_t)win * VT_WSTRIDE + (head * 32) * 112;
    sv8_t vf[4][2];
    #pragma unroll
    for (int kk = 0; kk < 4; kk++)
        #pragma unroll
        for (int j = 0; j < 2; j++)
            vf[kk][j] = *(const sv8_t*)(vbase + (16 * j + l15) * 112 + kk * 32 + 8 * lhi);

    int klab[7];
    if (shifted) {
        #pragma unroll
        for (int j = 0; j < 7; j++) {
            int kb = 16 * j + 4 * lhi;
            klab[j] = lablut[kb] | (lablut[kb + 1] << 8) | (lablut[kb + 2] << 16) | (lablut[kb + 3] << 24);
        }
    }

    int src0 = ((lane & 16) << 1) + l15;   // 32*(lhi&1) + l15
    int src1 = src0 + 16;
    bool jlo = (lane < 32);

    sv8_t qa_c = *(const sv8_t*)(qk + (rowbase + l15) * 256 + head * 32 + 8 * lhi);

    for (int ms = 0; ms < 7; ms++) {
        sv8_t qa_n = qa_c;
        if (ms < 6) {
            int qtok = min(16 * (ms + 1) + l15, 97);
            qa_n = *(const sv8_t*)(qk + (rowbase + qtok) * 256 + head * 32 + 8 * lhi);
        }
        int ql = min(16 * ms + l15, 97);
        int labq = shifted ? lablut[ql] : 0;
        const float* bq = biasb + ((size_t)head * 112 + ql) * 112;
        f4ld_t bv[7];
        #pragma unroll
        for (int j = 0; j < 7; j++)
            bv[j] = *(const f4ld_t*)(bq + 16 * j + 4 * lhi);
        fv4_t sc[7];
        __builtin_amdgcn_s_setprio(1);
        #pragma unroll
        for (int j = 0; j < 7; j++) {
            fv4_t z = {0.f, 0.f, 0.f, 0.f};
            sc[j] = __builtin_amdgcn_mfma_f32_16x16x32_bf16(kf[j], qa_c, z, 0, 0, 0);
        }
        __builtin_amdgcn_s_setprio(0);
        float mx = -1e30f;
        #pragma unroll
        for (int j = 0; j < 7; j++) {
            #pragma unroll
            for (int r = 0; r < 4; r++) {
                float s = sc[j][r] + bv[j][r];
                if (shifted && (((klab[j] >> (8 * r)) & 255) != labq)) s -= 100.f;
                if (16 * j + 4 * lhi + r >= 98) s = -1e30f;
                sc[j][r] = s;
                mx = fmaxf(mx, s);
            }
        }
        mx = fmaxf(mx, __shfl_xor(mx, 16));
        mx = fmaxf(mx, __shfl_xor(mx, 32));
        float sm = 0.f;
        #pragma unroll
        for (int j = 0; j < 7; j++)
            #pragma unroll
            for (int r = 0; r < 4; r++) {
                float p = __expf(sc[j][r] - mx);
                sc[j][r] = p;
                sm += p;
            }
        sm += __shfl_xor(sm, 16);
        sm += __shfl_xor(sm, 32);
        float inv = __builtin_amdgcn_rcpf(sm);
        int pkl[8], pkh[8];
        #pragma unroll
        for (int j = 0; j < 7; j++) {
            pkl[j] = (int)packbf(sc[j][0] * inv, sc[j][1] * inv);
            pkh[j] = (int)packbf(sc[j][2] * inv, sc[j][3] * inv);
        }
        pkl[7] = 0; pkh[7] = 0;
        fv4_t oacc[2] = {{0.f, 0.f, 0.f, 0.f}, {0.f, 0.f, 0.f, 0.f}};
        #pragma unroll
        for (int kk = 0; kk < 4; kk++) {
            int e_lo0 = __shfl(pkl[2 * kk], src0), o_lo0 = __shfl(pkl[2 * kk + 1], src0);
            int e_hi0 = __shfl(pkh[2 * kk], src0), o_hi0 = __shfl(pkh[2 * kk + 1], src0);
            int e_lo1 = __shfl(pkl[2 * kk], src1), o_lo1 = __shfl(pkl[2 * kk + 1], src1);
            int e_hi1 = __shfl(pkh[2 * kk], src1), o_hi1 = __shfl(pkh[2 * kk + 1], src1);
            union { int u[4]; sv8_t s8; } pa;
            pa.u[0] = jlo ? e_lo0 : o_lo0;
            pa.u[1] = jlo ? e_hi0 : o_hi0;
            pa.u[2] = jlo ? e_lo1 : o_lo1;
            pa.u[3] = jlo ? e_hi1 : o_hi1;
            __builtin_amdgcn_s_setprio(1);
            #pragma unroll
            for (int j = 0; j < 2; j++)
                oacc[j] = __builtin_amdgcn_mfma_f32_16x16x32_bf16(pa.s8, vf[kk][j], oacc[j], 0, 0, 0);
            __builtin_amdgcn_s_setprio(0);
        }
        #pragma unroll
        for (int r = 0; r < 4; r++) {
            int orow = 16 * ms + 4 * lhi + r;
            #pragma unroll
            for (int j = 0; j < 2; j++) {
                int ocol = head * 32 + 16 * j + l15;
                float v = (orow < 98) ? oacc[j][r] : 0.f;
                lds_st1(ot, orow * 256 + SWZB(orow, ocol * 2), f2bf(v));
            }
        }
        qa_c = qa_n;
    }
    __syncthreads();

    // proj: SWAPPED operands -> C[outcol][token]: lane=token l15, reg=4 cols.
    {
        int nb = wv * 32;
        fv4_t acc[7][2];
        for (int m = 0; m < 7; m++) for (int j = 0; j < 2; j++) acc[m][j] = (fv4_t){0.f, 0.f, 0.f, 0.f};
        for (int kk = 0; kk < 4; kk++) {
            sv8_t wfr[2];
            #pragma unroll
            for (int j = 0; j < 2; j++)
                wfr[j] = *(const sv8_t*)(pwT + (size_t)(nb + 16 * j + l15) * 128 + kk * 32 + 8 * lhi);
            __builtin_amdgcn_s_setprio(1);
            #pragma unroll
            for (int m = 0; m < 7; m++) {
                int ar = 16 * m + l15;
                sv8_t a = lds_ld8(ot, ar * 256 + SWZB(ar, (kk * 32 + 8 * lhi) * 2));
                #pragma unroll
                for (int j = 0; j < 2; j++)
                    acc[m][j] = __builtin_amdgcn_mfma_f32_16x16x32_bf16(wfr[j], a, acc[m][j], 0, 0, 0);
            }
            __builtin_amdgcn_s_setprio(0);
        }
        int b_ = win >> 8;
        f4ld_t pb4[2];
        #pragma unroll
        for (int j = 0; j < 2; j++)
            pb4[j] = *(const f4ld_t*)(pb + nb + 16 * j + 4 * lhi);
        #pragma unroll
        for (int m = 0; m < 7; m++) {
            int tok = 16 * m + l15;
            if (tok < 98) {
                int it = tok / 49, r2 = tok - it * 49, ih = r2 / 7, iw = r2 - ih * 7;
                int t = tw * 2 + it, h = hw * 7 + ih, w = ww * 7 + iw;
                if (shifted) {
                    t += 1; if (t >= TT) t -= TT;
                    h += 3; if (h >= HH) h -= HH;
                    w += 3; if (w >= WW2) w -= WW2;
                }
                unsigned short* xp = xbuf + ((size_t)b_ * PSPAT + t * (HH * WW2) + h * WW2 + w) * 128 + nb;
                #pragma unroll
                for (int j = 0; j < 2; j++) {
                    int c0 = 16 * j + 4 * lhi;
                    uint2 oldp = *(uint2*)(xp + c0);
                    float o0 = bf2f((unsigned short)(oldp.x & 0xffff)) + acc[m][j][0] + pb4[j].x;
                    float o1 = bf2f((unsigned short)(oldp.x >> 16))    + acc[m][j][1] + pb4[j].y;
                    float o2 = bf2f((unsigned short)(oldp.y & 0xffff)) + acc[m][j][2] + pb4[j].z;
                    float o3 = bf2f((unsigned short)(oldp.y >> 16))    + acc[m][j][3] + pb4[j].w;
                    uint2 np;
                    np.x = packbf(o0, o1); np.y = packbf(o2, o3);
                    *(uint2*)(xp + c0) = np;
                }
            }
        }
    }
}

// ---------------- fused LN2 + fc1 + GELU + fc2 + residual (+final transpose) ----
// 48 KB LDS (A 16 KB U-half + Bst 32 KB) -> 3 blocks/CU; xt staged in Bst at LN.
#define LOAD_CHUNK(c, R)                                                                   \
    if ((c) < 16) {                                                                        \
        if (((c) & 1) == 0) {                                                              \
            _Pragma("unroll")                                                              \
            for (int i_ = 0; i_ < 4; i_++)                                                 \
                R[i_] = *(const sv8_t*)(w1T + (size_t)(((c) >> 2) * 128 + (((c) >> 1) & 1) * 64 + i_ * 16 + r1) * 128 + (c1 >> 1)); \
        } else {                                                                           \
            _Pragma("unroll")                                                              \
            for (int i_ = 0; i_ < 4; i_++)                                                 \
                R[i_] = *(const sv8_t*)(w2T + (size_t)(i_ * 32 + r2) * 512 + ((c) >> 2) * 128 + (((c) >> 1) & 1) * 64 + (c2 >> 1)); \
        }                                                                                  \
    }
#define WRITE_CHUNK(c, R)                                                                  \
    if ((c) < 16) {                                                                        \
        unsigned short* bst_ = Bst[(c)&1];                                                 \
        if (((c) & 1) == 0) {                                                              \
            _Pragma("unroll")                                                              \
            for (int i_ = 0; i_ < 4; i_++)                                                 \
                lds_st8(bst_, (i_ * 16 + r1) * 256 + SWZB(i_ * 16 + r1, c1), R[i_]);       \
        } else {                                                                           \
            _Pragma("unroll")                                                              \
            for (int i_ = 0; i_ < 4; i_++)                                                 \
                lds_st8(bst_, (i_ * 32 + r2) * 128 + SWZB(i_ * 32 + r2, c2), R[i_]);       \
        }                                                                                  \
    }

__global__ __launch_bounds__(256, 3) void k_mlp(const unsigned short* __restrict__ xin,
                                                const float* __restrict__ g,
                                                const float* __restrict__ be,
                                                const unsigned short* __restrict__ w1T,  // [512][128]
                                                const float* __restrict__ b1p,
                                                const unsigned short* __restrict__ w2T,  // [128][512]
                                                const float* __restrict__ b2p,
                                                unsigned short* __restrict__ xbuf,
                                                float* __restrict__ outp,
                                                int final_layer) {
    __shared__ unsigned short A[4][32 * 64];    // 16 KB: per-wave U half
    __shared__ unsigned short Bst[2][8192];     // 32 KB: ping-pong chunks; xt during LN
    int tid = threadIdx.x;
    int wv = tid >> 6, lane = tid & 63, l15 = lane & 15, lhi = lane >> 4;
    unsigned short* uw = A[wv];
    unsigned short* xts = &Bst[0][0];
    int tok0 = blockIdx.x * 128 + wv * 32;

    int r1 = tid >> 4, c1 = (tid & 15) * 16;   // w1 chunk coords (64x128 elems)
    int r2 = tid >> 3, c2 = (tid & 7) * 16;    // w2 chunk coords (128x64 elems)

    sv8_t wA[4], wB[4];
    LOAD_CHUNK(0, wA)                          // hidden under LN

    // ---- LN (xt staged in Bst; wave-private rows wv*32..+31)
    #pragma unroll
    for (int tf = 0; tf < 2; tf++) {
        int lrow = 16 * tf + l15;
        int grow = wv * 32 + lrow;
        const unsigned short* src = xin + (size_t)(tok0 + lrow) * 128 + lhi * 32;
        float v[32];
        float s = 0.f, sq = 0.f;
        #pragma unroll
        for (int i = 0; i < 4; i++) {
            sv8_t raw = *(const sv8_t*)(src + i * 8);
            #pragma unroll
            for (int e = 0; e < 8; e++) {
                float f = bf2f((unsigned short)raw[e]);
                v[i * 8 + e] = f; s += f; sq += f * f;
            }
        }
        s += __shfl_xor(s, 16); sq += __shfl_xor(sq, 16);
        s += __shfl_xor(s, 32); sq += __shfl_xor(sq, 32);
        float mu = s * (1.f / 128.f);
        float var = sq * (1.f / 128.f) - mu * mu;
        float rs = rsqrtf(var + 1e-5f);
        #pragma unroll
        for (int j = 0; j < 4; j++) {
            int c0 = lhi * 32 + 8 * j;
            f4ld_t g0 = *(const f4ld_t*)(g + c0);
            f4ld_t g1 = *(const f4ld_t*)(g + c0 + 4);
            f4ld_t b0 = *(const f4ld_t*)(be + c0);
            f4ld_t b1 = *(const f4ld_t*)(be + c0 + 4);
            float y0 = (v[8 * j + 0] - mu) * rs * g0.x + b0.x;
            float y1 = (v[8 * j + 1] - mu) * rs * g0.y + b0.y;
            float y2 = (v[8 * j + 2] - mu) * rs * g0.z + b0.z;
            float y3 = (v[8 * j + 3] - mu) * rs * g0.w + b0.w;
            float y4 = (v[8 * j + 4] - mu) * rs * g1.x + b1.x;
            float y5 = (v[8 * j + 5] - mu) * rs * g1.y + b1.y;
            float y6 = (v[8 * j + 6] - mu) * rs * g1.z + b1.z;
            float y7 = (v[8 * j + 7] - mu) * rs * g1.w + b1.w;
            union { unsigned u[4]; sv8_t s8; } pk;
            pk.u[0] = packbf(y0, y1); pk.u[1] = packbf(y2, y3);
            pk.u[2] = packbf(y4, y5); pk.u[3] = packbf(y6, y7);
            lds_st8(xts, grow * 256 + SWZB(grow, 64 * lhi + 16 * j), pk.s8);
        }
    }
    sv8_t xf[2][4];
    #pragma unroll
    for (int tf = 0; tf < 2; tf++)
        #pragma unroll
        for (int kk = 0; kk < 4; kk++) {
            int grow = wv * 32 + 16 * tf + l15;
            xf[tf][kk] = lds_ld8(xts, grow * 256 + SWZB(grow, 64 * kk + 16 * lhi));
        }

    fv4_t acc2[8][2];
    #pragma unroll
    for (int cg = 0; cg < 8; cg++)
        #pragma unroll
        for (int tf = 0; tf < 2; tf++) acc2[cg][tf] = (fv4_t){0.f, 0.f, 0.f, 0.f};

    __syncthreads();
    WRITE_CHUNK(0, wA)
    LOAD_CHUNK(1, wB)
    __syncthreads();

    #pragma unroll
    for (int q = 0; q < 4; q++) {
        // ---- phase c=4q+0: fc1 fg 0..3 from Bst[0] (w1 h0) -> U half
        {
            const int c = 4 * q;
            WRITE_CHUNK(c + 1, wB)
            LOAD_CHUNK(c + 2, wA)
            #pragma unroll
            for (int f = 0; f < 4; f++) {
                sv8_t wf[4];
                #pragma unroll
                for (int kk = 0; kk < 4; kk++) {
                    int wrow = 16 * f + l15;
                    wf[kk] = lds_ld8(Bst[0], wrow * 256 + SWZB(wrow, kk * 64 + 16 * lhi));
                }
                fv4_t a1[2] = {{0.f, 0.f, 0.f, 0.f}, {0.f, 0.f, 0.f, 0.f}};
                __builtin_amdgcn_s_setprio(1);
                #pragma unroll
                for (int kk = 0; kk < 4; kk++) {
                    a1[0] = __builtin_amdgcn_mfma_f32_16x16x32_bf16(wf[kk], xf[0][kk], a1[0], 0, 0, 0);
                    a1[1] = __builtin_amdgcn_mfma_f32_16x16x32_bf16(wf[kk], xf[1][kk], a1[1], 0, 0, 0);
                }
                __builtin_amdgcn_s_setprio(0);
                f4ld_t b4 = *(const f4ld_t*)(b1p + q * 128 + 16 * f + 4 * lhi);
                #pragma unroll
                for (int tf = 0; tf < 2; tf++) {
                    float g0 = gelu_f(a1[tf][0] + b4.x);
                    float g1 = gelu_f(a1[tf][1] + b4.y);
                    float g2 = gelu_f(a1[tf][2] + b4.z);
                    float g3 = gelu_f(a1[tf][3] + b4.w);
                    union { unsigned u[2]; uint2 u2; } pk;
                    pk.u[0] = packbf(g0, g1); pk.u[1] = packbf(g2, g3);
                    int lrow = 16 * tf + l15;
                    *(uint2*)((char*)uw + lrow * 128 + SWZB(lrow, 32 * f + 8 * lhi)) = pk.u2;
                }
            }
            __syncthreads();
        }
        // ---- phase c=4q+1: fc2 (K = U cols q*128..+63) from Bst[1] (w2 h0)
        {
            const int c = 4 * q + 1;
            WRITE_CHUNK(c + 1, wA)
            LOAD_CHUNK(c + 2, wB)
            #pragma unroll
            for (int kql = 0; kql < 2; kql++) {
                sv8_t uf[2];
                #pragma unroll
                for (int tf = 0; tf < 2; tf++) {
                    int lrow = 16 * tf + l15;
                    uf[tf] = lds_ld8(uw, lrow * 128 + SWZB(lrow, 64 * kql + 16 * lhi));
                }
                #pragma unroll
                for (int cb = 0; cb < 2; cb++) {
                    sv8_t w2f[4];
                    #pragma unroll
                    for (int cc = 0; cc < 4; cc++) {
                        int wrow = 16 * (4 * cb + cc) + l15;
                        w2f[cc] = lds_ld8(Bst[1], wrow * 128 + SWZB(wrow, kql * 64 + 16 * lhi));
                    }
                    __builtin_amdgcn_s_setprio(1);
                    #pragma unroll
                    for (int cc = 0; cc < 4; cc++) {
                        int cg = 4 * cb + cc;
                        acc2[cg][0] = __builtin_amdgcn_mfma_f32_16x16x32_bf16(w2f[cc], uf[0], acc2[cg][0], 0, 0, 0);
                        acc2[cg][1] = __builtin_amdgcn_mfma_f32_16x16x32_bf16(w2f[cc], uf[1], acc2[cg][1], 0, 0, 0);
                    }
                    __builtin_amdgcn_s_setprio(0);
                }
            }
            __syncthreads();
        }
        // ---- phase c=4q+2: fc1 fg 4..7 from Bst[0] (w1 h1) -> same U half buffer
        {
            const int c = 4 * q + 2;
            WRITE_CHUNK(c + 1, wB)
            LOAD_CHUNK(c + 2, wA)
            #pragma unroll
            for (int f = 0; f < 4; f++) {
                sv8_t wf[4];
                #pragma unroll
                for (int kk = 0; kk < 4; kk++) {
                    int wrow = 16 * f + l15;
                    wf[kk] = lds_ld8(Bst[0], wrow * 256 + SWZB(wrow, kk * 64 + 16 * lhi));
                }
                fv4_t a1[2] = {{0.f, 0.f, 0.f, 0.f}, {0.f, 0.f, 0.f, 0.f}};
                __builtin_amdgcn_s_setprio(1);
                #pragma unroll
                for (int kk = 0; kk < 4; kk++) {
                    a1[0] = __builtin_amdgcn_mfma_f32_16x16x32_bf16(wf[kk], xf[0][kk], a1[0], 0, 0, 0);
                    a1[1] = __builtin_amdgcn_mfma_f32_16x16x32_bf16(wf[kk], xf[1][kk], a1[1], 0, 0, 0);
                }
                __builtin_amdgcn_s_setprio(0);
                f4ld_t b4 = *(const f4ld_t*)(b1p + q * 128 + 64 + 16 * f + 4 * lhi);
                #pragma unroll
                for (int tf = 0; tf < 2; tf++) {
                    float g0 = gelu_f(a1[tf][0] + b4.x);
                    float g1 = gelu_f(a1[tf][1] + b4.y);
                    float g2 = gelu_f(a1[tf][2] + b4.z);
                    float g3 = gelu_f(a1[tf][3] + b4.w);
                    union { unsigned u[2]; uint2 u2; } pk;
                    pk.u[0] = packbf(g0, g1); pk.u[1] = packbf(g2, g3);
                    int lrow = 16 * tf + l15;
                    *(uint2*)((char*)uw + lrow * 128 + SWZB(lrow, 32 * f + 8 * lhi)) = pk.u2;
                }
            }
            __syncthreads();
        }
        // ---- phase c=4q+3: fc2 (K = U cols q*128+64..+127) from Bst[1] (w2 h1)
        {
            const int c = 4 * q + 3;
            WRITE_CHUNK(c + 1, wA)
            LOAD_CHUNK(c + 2, wB)
            #pragma unroll
            for (int kql = 0; kql < 2; kql++) {
                sv8_t uf[2];
                #pragma unroll
                for (int tf = 0; tf < 2; tf++) {
                    int lrow = 16 * tf + l15;
                    uf[tf] = lds_ld8(uw, lrow * 128 + SWZB(lrow, 64 * kql + 16 * lhi));
                }
                #pragma unroll
                for (int cb = 0; cb < 2; cb++) {
                    sv8_t w2f[4];
                    #pragma unroll
                    for (int cc = 0; cc < 4; cc++) {
                        int wrow = 16 * (4 * cb + cc) + l15;
                        w2f[cc] = lds_ld8(Bst[1], wrow * 128 + SWZB(wrow, kql * 64 + 16 * lhi));
                    }
                    __builtin_amdgcn_s_setprio(1);
                    #pragma unroll
                    for (int cc = 0; cc < 4; cc++) {
                        int cg = 4 * cb + cc;
                        acc2[cg][0] = __builtin_amdgcn_mfma_f32_16x16x32_bf16(w2f[cc], uf[0], acc2[cg][0], 0, 0, 0);
                        acc2[cg][1] = __builtin_amdgcn_mfma_f32_16x16x32_bf16(w2f[cc], uf[1], acc2[cg][1], 0, 0, 0);
                    }
                    __builtin_amdgcn_s_setprio(0);
                }
            }
            __syncthreads();
        }
    }
    // ---- epilogue
    if (!final_layer) {
        #pragma unroll
        for (int tf = 0; tf < 2; tf++) {
            int row = tok0 + 16 * tf + l15;
            #pragma unroll
            for (int cg = 0; cg < 8; cg++) {
                int c0 = 16 * cg + 4 * lhi;
                f4ld_t b4 = *(const f4ld_t*)(b2p + c0);
                unsigned short* xp = xbuf + (size_t)row * 128 + c0;
                uint2 oldp = *(uint2*)xp;
                float o0 = bf2f((unsigned short)(oldp.x & 0xffff)) + acc2[cg][tf][0] + b4.x;
                float o1 = bf2f((unsigned short)(oldp.x >> 16))    + acc2[cg][tf][1] + b4.y;
                float o2 = bf2f((unsigned short)(oldp.y & 0xffff)) + acc2[cg][tf][2] + b4.z;
                float o3 = bf2f((unsigned short)(oldp.y >> 16))    + acc2[cg][tf][3] + b4.w;
                uint2 np;
                np.x = packbf(o0, o1); np.y = packbf(o2, o3);
                *(uint2*)xp = np;
            }
        }
    } else {
        // final layer: out[b][c][p] = bf16 residual + mlp, f32 write (fuses transpose)
        #pragma unroll
        for (int tf = 0; tf < 2; tf++) {
            int row = tok0 + 16 * tf + l15;
            int b_ = row / PSPAT, p = row - b_ * PSPAT;
            float* ob = outp + (size_t)b_ * 128 * PSPAT + p;
            #pragma unroll
            for (int cg = 0; cg < 8; cg++) {
                int c0 = 16 * cg + 4 * lhi;
                f4ld_t b4 = *(const f4ld_t*)(b2p + c0);
                const unsigned short* xp = xbuf + (size_t)row * 128 + c0;
                uint2 oldp = *(const uint2*)xp;
                float o0 = bf2f((unsigned short)(oldp.x & 0xffff)) + acc2[cg][tf][0] + b4.x;
                float o1 = bf2f((unsigned short)(oldp.x >> 16))    + acc2[cg][tf][1] + b4.y;
                float o2 = bf2f((unsigned short)(oldp.y & 0xffff)) + acc2[cg][tf][2] + b4.z;
                float o3 = bf2f((unsigned short)(oldp.y >> 16))    + acc2[cg][tf][3] + b4.w;
                ob[(size_t)(c0 + 0) * PSPAT] = o0;
                ob[(size_t)(c0 + 1) * PSPAT] = o1;
                ob[(size_t)(c0 + 2) * PSPAT] = o2;
                ob[(size_t)(c0 + 3) * PSPAT] = o3;
            }
        }
    }
}

extern "C" void kernel_launch(void* const* d_in, const int* in_sizes, int n_in,
                              void* d_out, int out_size, void* d_ws, size_t ws_size,
                              hipStream_t stream) {
    const float* x_in   = (const float*)d_in[0];
    const float* ln1_g  = (const float*)d_in[1];
    const float* ln1_b  = (const float*)d_in[2];
    const float* qkv_w  = (const float*)d_in[3];
    const float* qkv_b  = (const float*)d_in[4];
    const float* rpb    = (const float*)d_in[5];
    const float* proj_w = (const float*)d_in[6];
    const float* proj_b = (const float*)d_in[7];
    const float* ln2_g  = (const float*)d_in[8];
    const float* ln2_b  = (const float*)d_in[9];
    const float* fc1_w  = (const float*)d_in[10];
    const float* fc1_b  = (const float*)d_in[11];
    const float* fc2_w  = (const float*)d_in[12];
    const float* fc2_b  = (const float*)d_in[13];
    float* out = (float*)d_out;

    char* ws = (char*)d_ws;
    unsigned short* xbufb = (unsigned short*)ws;                     //  51,380,224 B (bf16)
    unsigned short* qkbuf = (unsigned short*)(ws + 51380224);        // 102,760,448 B
    unsigned short* vTbuf = (unsigned short*)(ws + 154140672);       //  58,720,256 B
    unsigned short* wbase = (unsigned short*)(ws + 212860928);       //     786,432 B
    float* biasb = (float*)(ws + 212860928 + 786432);                //     401,408 B

    // single merged prep launch: transpose-in + all weight transposes + bias table
    k_prep_all<<<NTRB + 384 + 392, 256, 0, stream>>>(x_in, xbufb,
                                                     qkv_w, proj_w, fc1_w, fc2_w,
                                                     wbase, rpb, biasb);

    for (int layer = 0; layer < 2; layer++) {
        unsigned short* wqT = wbase + (size_t)layer * 196608;
        unsigned short* wpT = wqT + 49152;
        unsigned short* w1T = wpT + 16384;
        unsigned short* w2T = w1T + 65536;
        int shifted = layer & 1;

        k_qkv<<<TOK_TOTAL / 64, 256, 0, stream>>>(xbufb, ln1_g + layer * 128, ln1_b + layer * 128,
                                                  wqT, qkv_b + layer * 384, qkbuf, vTbuf, shifted);
        k_attn_proj<<<BNW, 256, 0, stream>>>(qkbuf, vTbuf, biasb + (size_t)layer * 4 * 112 * 112,
                                             wpT, proj_b + layer * 128, xbufb, shifted);
        k_mlp<<<TOK_TOTAL / 128, 256, 0, stream>>>(xbufb, ln2_g + layer * 128, ln2_b + layer * 128,
                                                   w1T, fc1_b + layer * 512, w2T, fc2_b + layer * 128,
                                                   xbufb, out, layer == 1);
    }
}